// Round 7
// baseline (371.867 us; speedup 1.0000x reference)
//
#include <hip/hip_runtime.h>
#include <cstdint>

#define DEVINL __device__ __forceinline__

typedef __attribute__((ext_vector_type(8))) short short8;       // 8 x bf16 (4 VGPRs)
typedef __attribute__((ext_vector_type(4))) short short4v;      // 4 x bf16 (2 VGPRs)
typedef __attribute__((ext_vector_type(4))) float floatx4;
typedef __attribute__((ext_vector_type(4))) unsigned short ushort4v;

// hardware packed cvt: D = {bf16(a), bf16(b)} (RNE) — gfx950 V_CVT_PK_BF16_F32
DEVINL uint32_t pkbf(float a, float b) {
  uint32_t d;
  asm("v_cvt_pk_bf16_f32 %0, %1, %2" : "=v"(d) : "v"(a), "v"(b));
  return d;
}
DEVINL unsigned short f2bf(float f) { return (unsigned short)pkbf(f, f); }
DEVINL float bf2f(unsigned short h) {
  union { uint32_t u; float f; } v; v.u = ((uint32_t)h) << 16;
  return v.f;
}

#if defined(__has_builtin) && __has_builtin(__builtin_amdgcn_exp2f)
#define EXP2(x) __builtin_amdgcn_exp2f(x)
#else
#define EXP2(x) exp2f(x)
#endif

// fast GELU (tanh form, exp2-based): max |err| ~3e-4 vs exact erf GELU.
DEVINL float fast_gelu(float v) {
  const float z = -2.30220795f * v * (1.0f + 0.044715f * v * v);
  return v * __builtin_amdgcn_rcpf(1.0f + EXP2(z));
}

typedef __attribute__((address_space(3))) unsigned char* lds_ptr_t;
typedef const __attribute__((address_space(1))) unsigned char* gbl_ptr_t;
// async global->LDS, 16B per lane; LDS dest = wave-uniform base + lane*16
DEVINL void load_lds_128(const void* g, void* l) {
  __builtin_amdgcn_global_load_lds((gbl_ptr_t)g, (lds_ptr_t)l, 16, 0, 0);
}

#define MFMA16(a, b, c) __builtin_amdgcn_mfma_f32_16x16x32_bf16((a), (b), (c), 0, 0, 0)

// 0.125 (1/sqrt(Dk)) * log2(e): folds attention scale AND base-2 softmax into Q
#define QSCALE2 0.18033688011112042f

// ---------------------------------------------------------------------------
// prep: blocks 0..4095 cast x->bf16; 4096..8191 four 1024^2 transposes;
// 8192..12287 w1; 12288..16383 w2; 16384 converts mask(int)->bf16 0/1.
__global__ __launch_bounds__(256) void prep_kernel(
    const float* __restrict__ x, unsigned short* __restrict__ XB,
    const float* __restrict__ wq, const float* __restrict__ wk,
    const float* __restrict__ wv, const float* __restrict__ wo,
    unsigned short* __restrict__ WQKV, unsigned short* __restrict__ WOT,
    const float* __restrict__ w1, unsigned short* __restrict__ W1T,
    const float* __restrict__ w2, unsigned short* __restrict__ W2T,
    const int* __restrict__ mask, unsigned short* __restrict__ MB) {
  const int bid = blockIdx.x;
  if (bid >= 16384) {  // mask -> bf16 0/1
    const int i0 = threadIdx.x * 16;
#pragma unroll
    for (int j = 0; j < 16; ++j) MB[i0 + j] = mask[i0 + j] ? 0x3F80 : 0;
    return;
  }
  if (bid < 4096) {  // cast x
    const int i = (bid * 256 + threadIdx.x) * 4;
    floatx4 v = *(const floatx4*)(x + i);
    union { uint32_t u[2]; ushort4v v4; } o;
    o.u[0] = pkbf(v[0], v[1]);
    o.u[1] = pkbf(v[2], v[3]);
    *(ushort4v*)(XB + i) = o.v4;
    return;
  }
  const float* in;
  unsigned short* out;
  int K, N, bx, by;
  if (bid < 8192) {
    const int b2 = bid - 4096, z = b2 >> 10;
    in = (z == 0) ? wq : (z == 1) ? wk : (z == 2) ? wv : wo;
    out = (z == 3) ? WOT : WQKV + (size_t)z * 1024 * 1024;
    K = 1024; N = 1024; bx = b2 & 31; by = (b2 >> 5) & 31;
  } else if (bid < 12288) {
    const int b3 = bid - 8192;
    in = w1; out = W1T; K = 1024; N = 4096; bx = b3 & 127; by = b3 >> 7;
  } else {
    const int b4 = bid - 12288;
    in = w2; out = W2T; K = 4096; N = 1024; bx = b4 & 31; by = b4 >> 5;
  }
  __shared__ float tile[32][33];
  const int n0 = bx * 32, k0 = by * 32;
  const int tx = threadIdx.x & 31, ty = threadIdx.x >> 5;  // 32 x 8
#pragma unroll
  for (int i = 0; i < 4; ++i)
    tile[ty + 8 * i][tx] = in[(size_t)(k0 + ty + 8 * i) * N + n0 + tx];
  __syncthreads();
#pragma unroll
  for (int i = 0; i < 4; ++i)
    out[(size_t)(n0 + ty + 8 * i) * K + k0 + tx] = f2bf(tile[tx][ty + 8 * i]);
}

// ---------------------------------------------------------------------------
// GEMM: C = A[M,K] @ BT[N,K]^T  (bf16 in, fp32 acc), BM=BN=128, BK=64, 256 thr.
// LDS A/B each stored as TWO stacked 32-K panels of 64-B rows.
// SK: split-K factor (blockIdx.z = slice; slice 0 -> C0, slice 1 -> C1).
// EPI: 2 = bias + fast GELU -> bf16
//      4 = bf16 partial store (split-K; bias added downstream in LN)
//      5 = fused QKV epilogue: region 0 -> Q*QSCALE2 (C0); 1 -> K (C1);
//          2 -> V * mask, per-head-transposed [bh][64][2048] (C2)
template <int EPI, int SK>
__global__ __launch_bounds__(256) void gemm_bt_kernel(
    const unsigned short* __restrict__ A, const unsigned short* __restrict__ BT,
    const float* __restrict__ bias, void* __restrict__ C0, void* __restrict__ C1,
    void* __restrict__ C2, int M, int N, int K, const int* __restrict__ msk) {
  __shared__ __align__(16) unsigned short As[128 * 64];   // 2 panels x 8KB
  __shared__ __align__(16) unsigned short Bs[128 * 64];
  const int tid = threadIdx.x;
  const int w = tid >> 6, l = tid & 63;
  const int lq = l >> 4, lr = l & 15;
  const int m0 = blockIdx.y * 128, n0 = blockIdx.x * 128;
  const int wm = (w >> 1) * 64, wn = (w & 1) * 64;
  const int r_a = l >> 2;            // row within 16-row chunk
  const int colb = (l & 3) * 8;      // col (8 bf16 = 16B)
  const int kslice = K / SK;
  const int kbeg = kslice * blockIdx.z;

  floatx4 acc[4][4];
  const floatx4 fz = {0.f, 0.f, 0.f, 0.f};
#pragma unroll
  for (int mt = 0; mt < 4; ++mt)
#pragma unroll
    for (int nt = 0; nt < 4; ++nt) acc[mt][nt] = fz;

  for (int k0 = kbeg; k0 < kbeg + kslice; k0 += 64) {
    __syncthreads();
#pragma unroll
    for (int p = 0; p < 2; ++p) {
#pragma unroll
      for (int i = 0; i < 2; ++i) {
        const int c = w * 2 + i;
        load_lds_128(A + (size_t)(m0 + c * 16 + r_a) * K + k0 + p * 32 + colb,
                     (char*)As + p * 8192 + c * 1024);
        load_lds_128(BT + (size_t)(n0 + c * 16 + r_a) * K + k0 + p * 32 + colb,
                     (char*)Bs + p * 8192 + c * 1024);
      }
    }
    __syncthreads();
#pragma unroll
    for (int p = 0; p < 2; ++p) {
      short8 af[4], bf[4];
#pragma unroll
      for (int mt = 0; mt < 4; ++mt)
        af[mt] = *(const short8*)((const char*)As + p * 8192 + (wm + mt * 16 + lr) * 64 + lq * 16);
#pragma unroll
      for (int nt = 0; nt < 4; ++nt)
        bf[nt] = *(const short8*)((const char*)Bs + p * 8192 + (wn + nt * 16 + lr) * 64 + lq * 16);
#pragma unroll
      for (int mt = 0; mt < 4; ++mt)
#pragma unroll
        for (int nt = 0; nt < 4; ++nt)
          acc[mt][nt] = MFMA16(af[mt], bf[nt], acc[mt][nt]);
    }
  }

  void* Cp = (SK > 1 && blockIdx.z) ? C1 : C0;
  const int region = (EPI == 5) ? (n0 >> 10) : 0;  // block-uniform (BN=128 | 1024)
  // epilogue: C row = quad*4+reg, col = lane&15
#pragma unroll
  for (int mt = 0; mt < 4; ++mt) {
    float fm[4] = {1.f, 1.f, 1.f, 1.f};
    if (EPI == 5 && region == 2) {  // V-row mask (mask index == global row m)
      const int4 m4 = *(const int4*)(msk + m0 + wm + mt * 16 + lq * 4);
      fm[0] = m4.x ? 1.f : 0.f; fm[1] = m4.y ? 1.f : 0.f;
      fm[2] = m4.z ? 1.f : 0.f; fm[3] = m4.w ? 1.f : 0.f;
    }
#pragma unroll
    for (int nt = 0; nt < 4; ++nt) {
      const int n = n0 + wn + nt * 16 + lr;
      float bval = 0.f;
      if (EPI == 2) bval = bias[n];
#pragma unroll
      for (int r = 0; r < 4; ++r) {
        const int m = m0 + wm + mt * 16 + lq * 4 + r;
        float v = acc[mt][nt][r];
        if (EPI == 4) {
          ((unsigned short*)Cp)[(size_t)m * N + n] = f2bf(v);
        } else if (EPI == 2) {
          ((unsigned short*)C0)[(size_t)m * N + n] = f2bf(fast_gelu(v + bval));
        } else {  // EPI == 5
          if (region == 0) {
            ((unsigned short*)C0)[(size_t)m * 1024 + n] = f2bf(v * QSCALE2);
          } else if (region == 1) {
            ((unsigned short*)C1)[(size_t)m * 1024 + (n - 1024)] = f2bf(v);
          } else {
            const int nn = n - 2048;
            const int bidx = m >> 11, s = m & 2047;
            const int hh = nn >> 6, d = nn & 63;
            ((unsigned short*)C2)[((size_t)((bidx * 16 + hh) * 64 + d)) * 2048 + s] =
                f2bf(v * fm[r]);
          }
        }
      }
    }
  }
}

// ---------------------------------------------------------------------------
// Flash attention: S=2048, Dk=64. Q PRE-SCALED by 0.125*log2e (exp2 domain).
// FIXED-SHIFT softmax (p = exp2(score), no running max) + TRANSPOSED-SCORE
// register pipeline: S^T = K·Q^T, so the S^T C/D fragment is directly a PV
// A-operand under key-permutation phi (matched by the V B-fragment reads).
// Mask pre-folded: V columns zeroed upstream; denominator accumulated by
// MFMA against a bf16 0/1 mask fragment (MB) -> inner loop is exp2+pack only
// (pack via hardware v_cvt_pk_bf16_f32). LDS 32 KB (Ks 16K + VTs 16K).
__global__ __launch_bounds__(256, 4) void flash_kernel(
    const unsigned short* __restrict__ Q, const unsigned short* __restrict__ Kg,
    const unsigned short* __restrict__ VT, const unsigned short* __restrict__ MB,
    unsigned short* __restrict__ ctx) {
  __shared__ __align__(16) unsigned short Ks[128 * 64];    // [key][d], swizzled
  __shared__ __align__(16) unsigned short VTs[64 * 128];   // [d][key], swizzled

  const int tid = threadIdx.x, w = tid >> 6, l = tid & 63;
  const int lq = l >> 4, lr = l & 15;
  const int bh = blockIdx.y, b = bh >> 4, h = bh & 15;
  const int q0 = blockIdx.x * 64;

  const unsigned short* Qp = Q + (size_t)(b * 2048 + q0) * 1024 + h * 64;
  const unsigned short* Kp = Kg + (size_t)(b * 2048) * 1024 + h * 64;
  const unsigned short* VTp = VT + (size_t)bh * 64 * 2048;
  const unsigned short* mbp = MB + b * 2048;

  {  // stage Q [64][64] once through Ks head (plain layout, consumed to regs)
    const int rq = l >> 3, cs = l & 7;
#pragma unroll
    for (int i = 0; i < 2; ++i) {
      const int c = w * 2 + i;
      load_lds_128(Qp + (size_t)(c * 8 + rq) * 1024 + cs * 8, (char*)Ks + c * 1024);
    }
  }
  __syncthreads();
  short8 qf[2];  // B-operand: lane holds Q[q0+w*16+lr][d = lq*8 + 0..7 (+32)]
  qf[0] = *(const short8*)((const char*)Ks + (w * 16 + lr) * 128 + lq * 16);
  qf[1] = *(const short8*)((const char*)Ks + (w * 16 + lr) * 128 + 64 + lq * 16);

  const floatx4 fz = {0.f, 0.f, 0.f, 0.f};
  floatx4 o[4] = {fz, fz, fz, fz};
  floatx4 l_acc = fz;

  const int krow = l >> 3, kslot = l & 7;   // Ks staging: 8 rows / 1KB chunk
  const int vrow = l >> 4, vslot = l & 15;  // VTs staging: 4 rows / 1KB chunk

  for (int kb = 0; kb < 2048; kb += 128) {
    __syncthreads();
#pragma unroll
    for (int i = 0; i < 4; ++i) {
      const int c4 = w * 4 + i;
      {  // Ks rows c4*8..+7; slot kslot holds logical chunk kslot^(row&7)
        const int row = c4 * 8 + krow;
        const int cc = kslot ^ (row & 7);
        load_lds_128(Kp + (size_t)(kb + row) * 1024 + cc * 8, (char*)Ks + c4 * 1024);
      }
      {  // VTs rows c4*4..+3; slot vslot holds logical chunk vslot^(row&15)
        const int row = c4 * 4 + vrow;
        const int cc = vslot ^ (row & 15);
        load_lds_128(VTp + (size_t)row * 2048 + kb + cc * 8, (char*)VTs + c4 * 1024);
      }
    }
    // mask fragments for the 4 PV windows (bf16 0/1; lr-independent -> bcast)
    short8 mf[4];
#pragma unroll
    for (int t = 0; t < 4; ++t) {
      const short4v ma = *(const short4v*)(mbp + kb + t * 32 + lq * 4);
      const short4v mb2 = *(const short4v*)(mbp + kb + t * 32 + 16 + lq * 4);
      mf[t] = short8{ma[0], ma[1], ma[2], ma[3], mb2[0], mb2[1], mb2[2], mb2[3]};
    }
    __syncthreads();

    // two halves of 64 keys each: 4 score-groups -> 2 PV windows
#pragma unroll
    for (int h2 = 0; h2 < 2; ++h2) {
      // S^T: D[m=key][n=q]; lane gets q=lr(col), key=g*16+lq*4+r(row)
      floatx4 s[4];
#pragma unroll
      for (int gg = 0; gg < 4; ++gg) {
        const int g = h2 * 4 + gg;
        const char* rowp = (const char*)Ks + (g * 16 + lr) * 128;
        short8 k0 = *(const short8*)(rowp + ((lq) ^ (lr & 7)) * 16);
        short8 k1 = *(const short8*)(rowp + ((4 + lq) ^ (lr & 7)) * 16);
        floatx4 t = MFMA16(k0, qf[0], fz);
        s[gg] = MFMA16(k1, qf[1], t);
      }
      // p = exp2(score), hw-packed to bf16 A-fragments (key-permuted)
      short8 pf[2];
#pragma unroll
      for (int tt = 0; tt < 2; ++tt) {
        const floatx4 sL = s[tt * 2], sH = s[tt * 2 + 1];
        union { uint32_t u[4]; short8 s8; } pk;
        pk.u[0] = pkbf(EXP2(sL[0]), EXP2(sL[1]));
        pk.u[1] = pkbf(EXP2(sL[2]), EXP2(sL[3]));
        pk.u[2] = pkbf(EXP2(sH[0]), EXP2(sH[1]));
        pk.u[3] = pkbf(EXP2(sH[2]), EXP2(sH[3]));
        pf[tt] = pk.s8;
      }
      // PV: windows t = h2*2 + tt over 32 keys each
#pragma unroll
      for (int tt = 0; tt < 2; ++tt) {
        const int t = h2 * 2 + tt;
        l_acc = MFMA16(pf[tt], mf[t], l_acc);
        const int kc0 = t * 4 + (lq >> 1);       // 16B chunk of low 16-key half
        const int off = (lq & 1) * 8;            // byte offset within chunk
#pragma unroll
        for (int nt = 0; nt < 4; ++nt) {
          const int d = nt * 16 + lr;
          const char* vrow_p = (const char*)VTs + d * 256;
          short4v va = *(const short4v*)(vrow_p + ((kc0 ^ (d & 15)) * 16) + off);
          short4v vb = *(const short4v*)(vrow_p + (((kc0 + 2) ^ (d & 15)) * 16) + off);
          short8 vf = {va[0], va[1], va[2], va[3], vb[0], vb[1], vb[2], vb[3]};
          o[nt] = MFMA16(pf[tt], vf, o[nt]);
        }
      }
    }
  }

  // epilogue: o C-layout: q = q0 + w*16 + lq*4 + r, d = nt*16 + lr
#pragma unroll
  for (int r = 0; r < 4; ++r) {
    const float inv = 1.0f / l_acc[r];
    const int q = q0 + w * 16 + lq * 4 + r;
#pragma unroll
    for (int nt = 0; nt < 4; ++nt)
      ctx[(size_t)(b * 2048 + q) * 1024 + h * 64 + nt * 16 + lr] = f2bf(o[nt][r] * inv);
  }
}

// ---------------------------------------------------------------------------
// fused residual + dual bf16-partial sum + bias + LayerNorm over rows of 1024.
// v = res + y0 + y1 + bias; out = LN(v)*gamma + beta.
template <int RESBF, int OUTBF>
__global__ __launch_bounds__(256) void ln2_kernel(
    const void* __restrict__ res, const unsigned short* __restrict__ y0,
    const unsigned short* __restrict__ y1, const float* __restrict__ bias,
    const float* __restrict__ gamma, const float* __restrict__ beta,
    void* __restrict__ outp) {
  const int row = blockIdx.x, t = threadIdx.x;
  const size_t base = (size_t)row * 1024 + t * 4;
  float v[4];
  if (RESBF) {
    ushort4v r4 = *(const ushort4v*)((const unsigned short*)res + base);
#pragma unroll
    for (int j = 0; j < 4; ++j) v[j] = bf2f(r4[j]);
  } else {
    floatx4 r4 = *(const floatx4*)((const float*)res + base);
#pragma unroll
    for (int j = 0; j < 4; ++j) v[j] = r4[j];
  }
  const ushort4v a4 = *(const ushort4v*)(y0 + base);
  const ushort4v b4v = *(const ushort4v*)(y1 + base);
  const floatx4 bi4 = *(const floatx4*)(bias + t * 4);
  float s = 0.f, ss = 0.f;
#pragma unroll
  for (int j = 0; j < 4; ++j) {
    v[j] += bf2f(a4[j]) + bf2f(b4v[j]) + bi4[j];
    s += v[j];
    ss += v[j] * v[j];
  }
#pragma unroll
  for (int off = 1; off < 64; off <<= 1) {
    s += __shfl_xor(s, off);
    ss += __shfl_xor(ss, off);
  }
  __shared__ float red[8];
  const int w = t >> 6;
  if ((t & 63) == 0) { red[w] = s; red[4 + w] = ss; }
  __syncthreads();
  s = red[0] + red[1] + red[2] + red[3];
  ss = red[4] + red[5] + red[6] + red[7];
  const float mean = s * (1.0f / 1024.0f);
  const float var = ss * (1.0f / 1024.0f) - mean * mean;
  const float rstd = rsqrtf(var + 1e-6f);
  const floatx4 g4 = *(const floatx4*)(gamma + t * 4);
  const floatx4 be4 = *(const floatx4*)(beta + t * 4);
  if (OUTBF) {
    union { uint32_t u[2]; ushort4v v4; } o;
    o.u[0] = pkbf((v[0] - mean) * rstd * g4[0] + be4[0],
                  (v[1] - mean) * rstd * g4[1] + be4[1]);
    o.u[1] = pkbf((v[2] - mean) * rstd * g4[2] + be4[2],
                  (v[3] - mean) * rstd * g4[3] + be4[3]);
    *(ushort4v*)((unsigned short*)outp + base) = o.v4;
  } else {
    floatx4 o;
#pragma unroll
    for (int j = 0; j < 4; ++j) o[j] = (v[j] - mean) * rstd * g4[j] + be4[j];
    *(floatx4*)((float*)outp + base) = o;
  }
}

// ---------------------------------------------------------------------------
extern "C" void kernel_launch(void* const* d_in, const int* in_sizes, int n_in,
                              void* d_out, int out_size, void* d_ws, size_t ws_size,
                              hipStream_t stream) {
  (void)in_sizes; (void)n_in; (void)out_size; (void)ws_size;
  const float* x    = (const float*)d_in[0];
  const int*   mask = (const int*)d_in[1];
  const float* wq   = (const float*)d_in[2];
  const float* wk   = (const float*)d_in[3];
  const float* wv   = (const float*)d_in[4];
  const float* wo   = (const float*)d_in[5];
  const float* wo_b = (const float*)d_in[6];
  const float* w1   = (const float*)d_in[7];
  const float* b1   = (const float*)d_in[8];
  const float* w2   = (const float*)d_in[9];
  const float* b2   = (const float*)d_in[10];
  const float* g1   = (const float*)d_in[11];
  const float* be1  = (const float*)d_in[12];
  const float* g2   = (const float*)d_in[13];
  const float* be2  = (const float*)d_in[14];
  float* out = (float*)d_out;

  char* ws = (char*)d_ws;
  const size_t MBy = 1024ull * 1024ull;
  // phase-aliased workspace (80 MB):
  unsigned short* WQKV = (unsigned short*)(ws + 0 * MBy);   // 6MB  (dead after QKV gemm)
  unsigned short* WOT  = (unsigned short*)(ws + 6 * MBy);   // 2MB  (dead after WO gemm)
  unsigned short* W1T  = (unsigned short*)(ws + 8 * MBy);   // 8MB  (dead after FF1)
  unsigned short* W2T  = (unsigned short*)(ws + 16 * MBy);  // 8MB  (dead after FF2)
  unsigned short* XB   = (unsigned short*)(ws + 24 * MBy);  // 8MB  (dead after QKV)
  unsigned short* Qb   = (unsigned short*)(ws + 32 * MBy);  // 8MB  (dead after flash)
  unsigned short* Kb   = (unsigned short*)(ws + 40 * MBy);  // 8MB  (dead after flash)
  unsigned short* VTb  = (unsigned short*)(ws + 48 * MBy);  // 8MB  (dead after flash)
  unsigned short* CTX  = (unsigned short*)(ws + 56 * MBy);  // 8MB  (dead after WO gemm)
  unsigned short* ATT0 = (unsigned short*)(ws + 32 * MBy);  // 8MB bf16, over Qb
  unsigned short* ATT1 = (unsigned short*)(ws + 40 * MBy);  // 8MB bf16, over Kb
  unsigned short* Hb   = (unsigned short*)(ws + 24 * MBy);  // 8MB  over XB
  unsigned short* G1   = (unsigned short*)(ws + 32 * MBy);  // 32MB over ATT0/ATT1/VTb/CTX
  unsigned short* FF20 = (unsigned short*)(ws + 64 * MBy);  // 8MB bf16
  unsigned short* FF21 = (unsigned short*)(ws + 72 * MBy);  // 8MB bf16
  unsigned short* MB   = (unsigned short*)(ws + 78 * MBy);  // 8KB bf16 mask (inside FF21
                                                            // region; FF21 written after flash)

  // 1. prep: cast x + all 6 weight transposes + bf16 mask in one launch
  prep_kernel<<<16385, 256, 0, stream>>>(x, XB, wq, wk, wv, wo, WQKV, WOT,
                                         w1, W1T, w2, W2T, mask, MB);
  // 2. fused QKV projection: N=3072 -> 768 blocks; Q pre-scaled, V masked
  gemm_bt_kernel<5, 1><<<dim3(24, 32), 256, 0, stream>>>(
      XB, WQKV, nullptr, Qb, Kb, VTb, 4096, 3072, 1024, mask);
  // 3. attention
  flash_kernel<<<dim3(32, 32), 256, 0, stream>>>(Qb, Kb, VTb, MB, CTX);
  // 4. output projection, split-K=2 bf16 partials (bias folded into LN1)
  gemm_bt_kernel<4, 2><<<dim3(8, 32, 2), 256, 0, stream>>>(
      CTX, WOT, nullptr, ATT0, ATT1, nullptr, 4096, 1024, 1024, nullptr);
  // 5. LN1: h = LN(x + att0 + att1 + wo_b) -> bf16
  ln2_kernel<0, 1><<<4096, 256, 0, stream>>>(x, ATT0, ATT1, wo_b, g1, be1, Hb);
  // 6. FF1 + bias + fast GELU -> bf16
  gemm_bt_kernel<2, 1><<<dim3(32, 32), 256, 0, stream>>>(
      Hb, W1T, b1, G1, nullptr, nullptr, 4096, 4096, 1024, nullptr);
  // 7. FF2, split-K=2 bf16 partials (bias folded into LN2)
  gemm_bt_kernel<4, 2><<<dim3(8, 32, 2), 256, 0, stream>>>(
      G1, W2T, nullptr, FF20, FF21, nullptr, 4096, 1024, 4096, nullptr);
  // 8. LN2: out = LN(h + ff0 + ff1 + b2) -> fp32
  ln2_kernel<1, 0><<<4096, 256, 0, stream>>>(Hb, FF20, FF21, b2, g2, be2, out);
}

// Round 8
// 369.508 us; speedup vs baseline: 1.0064x; 1.0064x over previous
//
#include <hip/hip_runtime.h>
#include <cstdint>

#define DEVINL __device__ __forceinline__

typedef __attribute__((ext_vector_type(8))) short short8;       // 8 x bf16 (4 VGPRs)
typedef __attribute__((ext_vector_type(4))) short short4v;      // 4 x bf16 (2 VGPRs)
typedef __attribute__((ext_vector_type(4))) float floatx4;
typedef __attribute__((ext_vector_type(4))) unsigned short ushort4v;

// hardware packed cvt: D = {bf16(a), bf16(b)} (RNE) — use ONLY for true pair
// packs (scalar use regressed R7: asm blocks CSE, +20 VGPR in GEMM epilogue).
DEVINL uint32_t pkbf(float a, float b) {
  uint32_t d;
  asm("v_cvt_pk_bf16_f32 %0, %1, %2" : "=v"(d) : "v"(a), "v"(b));
  return d;
}
// software RNE fp32->bf16 for scalar stores (compiler-schedulable)
DEVINL unsigned short f2bf(float f) {
  union { float f; uint32_t u; } v; v.f = f;
  return (unsigned short)((v.u + 0x7fffu + ((v.u >> 16) & 1u)) >> 16);
}
DEVINL float bf2f(unsigned short h) {
  union { uint32_t u; float f; } v; v.u = ((uint32_t)h) << 16;
  return v.f;
}

#if defined(__has_builtin) && __has_builtin(__builtin_amdgcn_exp2f)
#define EXP2(x) __builtin_amdgcn_exp2f(x)
#else
#define EXP2(x) exp2f(x)
#endif

// fast GELU (tanh form, exp2-based): max |err| ~3e-4 vs exact erf GELU.
DEVINL float fast_gelu(float v) {
  const float z = -2.30220795f * v * (1.0f + 0.044715f * v * v);
  return v * __builtin_amdgcn_rcpf(1.0f + EXP2(z));
}

typedef __attribute__((address_space(3))) unsigned char* lds_ptr_t;
typedef const __attribute__((address_space(1))) unsigned char* gbl_ptr_t;
// async global->LDS, 16B per lane; LDS dest = wave-uniform base + lane*16
DEVINL void load_lds_128(const void* g, void* l) {
  __builtin_amdgcn_global_load_lds((gbl_ptr_t)g, (lds_ptr_t)l, 16, 0, 0);
}

#define MFMA16(a, b, c) __builtin_amdgcn_mfma_f32_16x16x32_bf16((a), (b), (c), 0, 0, 0)

// 0.125 (1/sqrt(Dk)) * log2(e): folds attention scale AND base-2 softmax into Q
#define QSCALE2 0.18033688011112042f

// ---------------------------------------------------------------------------
// prep: blocks 0..4095 cast x->bf16; 4096..8191 four 1024^2 transposes;
// 8192..12287 w1; 12288..16383 w2; 16384 converts mask(int)->bf16 0/1.
__global__ __launch_bounds__(256) void prep_kernel(
    const float* __restrict__ x, unsigned short* __restrict__ XB,
    const float* __restrict__ wq, const float* __restrict__ wk,
    const float* __restrict__ wv, const float* __restrict__ wo,
    unsigned short* __restrict__ WQKV, unsigned short* __restrict__ WOT,
    const float* __restrict__ w1, unsigned short* __restrict__ W1T,
    const float* __restrict__ w2, unsigned short* __restrict__ W2T,
    const int* __restrict__ mask, unsigned short* __restrict__ MB) {
  const int bid = blockIdx.x;
  if (bid >= 16384) {  // mask -> bf16 0/1
    const int i0 = threadIdx.x * 16;
#pragma unroll
    for (int j = 0; j < 16; ++j) MB[i0 + j] = mask[i0 + j] ? 0x3F80 : 0;
    return;
  }
  if (bid < 4096) {  // cast x (pair-packed hw cvt)
    const int i = (bid * 256 + threadIdx.x) * 4;
    floatx4 v = *(const floatx4*)(x + i);
    union { uint32_t u[2]; ushort4v v4; } o;
    o.u[0] = pkbf(v[0], v[1]);
    o.u[1] = pkbf(v[2], v[3]);
    *(ushort4v*)(XB + i) = o.v4;
    return;
  }
  const float* in;
  unsigned short* out;
  int K, N, bx, by;
  if (bid < 8192) {
    const int b2 = bid - 4096, z = b2 >> 10;
    in = (z == 0) ? wq : (z == 1) ? wk : (z == 2) ? wv : wo;
    out = (z == 3) ? WOT : WQKV + (size_t)z * 1024 * 1024;
    K = 1024; N = 1024; bx = b2 & 31; by = (b2 >> 5) & 31;
  } else if (bid < 12288) {
    const int b3 = bid - 8192;
    in = w1; out = W1T; K = 1024; N = 4096; bx = b3 & 127; by = b3 >> 7;
  } else {
    const int b4 = bid - 12288;
    in = w2; out = W2T; K = 4096; N = 1024; bx = b4 & 31; by = b4 >> 5;
  }
  __shared__ float tile[32][33];
  const int n0 = bx * 32, k0 = by * 32;
  const int tx = threadIdx.x & 31, ty = threadIdx.x >> 5;  // 32 x 8
#pragma unroll
  for (int i = 0; i < 4; ++i)
    tile[ty + 8 * i][tx] = in[(size_t)(k0 + ty + 8 * i) * N + n0 + tx];
  __syncthreads();
#pragma unroll
  for (int i = 0; i < 4; ++i)
    out[(size_t)(n0 + ty + 8 * i) * K + k0 + tx] = f2bf(tile[tx][ty + 8 * i]);
}

// ---------------------------------------------------------------------------
// GEMM: C = A[M,K] @ BT[N,K]^T  (bf16 in, fp32 acc), BM=BN=128, BK=64, 256 thr.
// XCD-aware swizzle: xcd = lin&7 owns an N-strip of gridDim.x/8 column-blocks
// so each XCD's 4MB L2 holds only its B-slice (QKV: 0.75MB) instead of
// streaming all of B per row-group. Requires gridDim.x % 8 == 0 (all ours are).
// SK: split-K factor (blockIdx.z = slice; slice 0 -> C0, slice 1 -> C1).
// EPI: 2 = bias + fast GELU -> bf16
//      4 = bf16 partial store (split-K; bias added downstream in LN)
//      5 = fused QKV epilogue: region 0 -> Q*QSCALE2 (C0); 1 -> K (C1);
//          2 -> V * mask (16 packed bits, loaded in prologue), per-head-
//          transposed [bh][64][2048] (C2)
template <int EPI, int SK>
__global__ __launch_bounds__(256) void gemm_bt_kernel(
    const unsigned short* __restrict__ A, const unsigned short* __restrict__ BT,
    const float* __restrict__ bias, void* __restrict__ C0, void* __restrict__ C1,
    void* __restrict__ C2, int M, int N, int K, const int* __restrict__ msk) {
  __shared__ __align__(16) unsigned short As[128 * 64];   // 2 panels x 8KB
  __shared__ __align__(16) unsigned short Bs[128 * 64];
  const int tid = threadIdx.x;
  const int w = tid >> 6, l = tid & 63;
  const int lq = l >> 4, lr = l & 15;

  int bxs = blockIdx.x, bys = blockIdx.y;
  {  // XCD swizzle (perf-only heuristic; correctness independent of mapping)
    const int nblk = gridDim.x;
    const int lin = bys * nblk + bxs;
    const int nb8 = nblk >> 3;
    const int xcd = lin & 7, j = lin >> 3;
    bxs = xcd * nb8 + (j % nb8);
    bys = j / nb8;
  }
  const int m0 = bys * 128, n0 = bxs * 128;
  const int wm = (w >> 1) * 64, wn = (w & 1) * 64;
  const int r_a = l >> 2;            // row within 16-row chunk
  const int colb = (l & 3) * 8;      // col (8 bf16 = 16B)
  const int kslice = K / SK;
  const int kbeg = kslice * blockIdx.z;
  const int region = (EPI == 5) ? (n0 >> 10) : 0;  // block-uniform

  // V-row mask, 16 packed bits (loads overlap the K-loop staging)
  uint32_t mbits = 0xFFFFu;
  if (EPI == 5 && region == 2) {
    mbits = 0;
#pragma unroll
    for (int mt = 0; mt < 4; ++mt) {
      const int4 m4 = *(const int4*)(msk + m0 + wm + mt * 16 + lq * 4);
      mbits |= (m4.x ? 1u : 0u) << (mt * 4);
      mbits |= (m4.y ? 1u : 0u) << (mt * 4 + 1);
      mbits |= (m4.z ? 1u : 0u) << (mt * 4 + 2);
      mbits |= (m4.w ? 1u : 0u) << (mt * 4 + 3);
    }
  }

  floatx4 acc[4][4];
  const floatx4 fz = {0.f, 0.f, 0.f, 0.f};
#pragma unroll
  for (int mt = 0; mt < 4; ++mt)
#pragma unroll
    for (int nt = 0; nt < 4; ++nt) acc[mt][nt] = fz;

  for (int k0 = kbeg; k0 < kbeg + kslice; k0 += 64) {
    __syncthreads();
#pragma unroll
    for (int p = 0; p < 2; ++p) {
#pragma unroll
      for (int i = 0; i < 2; ++i) {
        const int c = w * 2 + i;
        load_lds_128(A + (size_t)(m0 + c * 16 + r_a) * K + k0 + p * 32 + colb,
                     (char*)As + p * 8192 + c * 1024);
        load_lds_128(BT + (size_t)(n0 + c * 16 + r_a) * K + k0 + p * 32 + colb,
                     (char*)Bs + p * 8192 + c * 1024);
      }
    }
    __syncthreads();
#pragma unroll
    for (int p = 0; p < 2; ++p) {
      short8 af[4], bf[4];
#pragma unroll
      for (int mt = 0; mt < 4; ++mt)
        af[mt] = *(const short8*)((const char*)As + p * 8192 + (wm + mt * 16 + lr) * 64 + lq * 16);
#pragma unroll
      for (int nt = 0; nt < 4; ++nt)
        bf[nt] = *(const short8*)((const char*)Bs + p * 8192 + (wn + nt * 16 + lr) * 64 + lq * 16);
#pragma unroll
      for (int mt = 0; mt < 4; ++mt)
#pragma unroll
        for (int nt = 0; nt < 4; ++nt)
          acc[mt][nt] = MFMA16(af[mt], bf[nt], acc[mt][nt]);
    }
  }

  void* Cp = (SK > 1 && blockIdx.z) ? C1 : C0;
  // epilogue: C row = quad*4+reg, col = lane&15
#pragma unroll
  for (int mt = 0; mt < 4; ++mt) {
#pragma unroll
    for (int nt = 0; nt < 4; ++nt) {
      const int n = n0 + wn + nt * 16 + lr;
      float bval = 0.f;
      if (EPI == 2) bval = bias[n];
#pragma unroll
      for (int r = 0; r < 4; ++r) {
        const int m = m0 + wm + mt * 16 + lq * 4 + r;
        float v = acc[mt][nt][r];
        if (EPI == 4) {
          ((unsigned short*)Cp)[(size_t)m * N + n] = f2bf(v);
        } else if (EPI == 2) {
          ((unsigned short*)C0)[(size_t)m * N + n] = f2bf(fast_gelu(v + bval));
        } else {  // EPI == 5
          if (region == 0) {
            ((unsigned short*)C0)[(size_t)m * 1024 + n] = f2bf(v * QSCALE2);
          } else if (region == 1) {
            ((unsigned short*)C1)[(size_t)m * 1024 + (n - 1024)] = f2bf(v);
          } else {
            const int nn = n - 2048;
            const int bidx = m >> 11, s = m & 2047;
            const int hh = nn >> 6, d = nn & 63;
            const float vv = ((mbits >> (mt * 4 + r)) & 1u) ? v : 0.f;
            ((unsigned short*)C2)[((size_t)((bidx * 16 + hh) * 64 + d)) * 2048 + s] = f2bf(vv);
          }
        }
      }
    }
  }
}

// ---------------------------------------------------------------------------
// Flash attention: S=2048, Dk=64. Q PRE-SCALED by 0.125*log2e (exp2 domain).
// FIXED-SHIFT softmax (p = exp2(score), no running max) + TRANSPOSED-SCORE
// register pipeline: S^T = K·Q^T, so the S^T C/D fragment is directly a PV
// A-operand under key-permutation phi (matched by the V B-fragment reads).
// Mask pre-folded: V columns zeroed upstream; denominator accumulated by
// MFMA against a bf16 0/1 mask fragment (MB) -> inner loop is exp2+pack only
// (pack via hardware v_cvt_pk_bf16_f32). LDS 32 KB (Ks 16K + VTs 16K).
__global__ __launch_bounds__(256, 4) void flash_kernel(
    const unsigned short* __restrict__ Q, const unsigned short* __restrict__ Kg,
    const unsigned short* __restrict__ VT, const unsigned short* __restrict__ MB,
    unsigned short* __restrict__ ctx) {
  __shared__ __align__(16) unsigned short Ks[128 * 64];    // [key][d], swizzled
  __shared__ __align__(16) unsigned short VTs[64 * 128];   // [d][key], swizzled

  const int tid = threadIdx.x, w = tid >> 6, l = tid & 63;
  const int lq = l >> 4, lr = l & 15;
  const int bh = blockIdx.y, b = bh >> 4, h = bh & 15;
  const int q0 = blockIdx.x * 64;

  const unsigned short* Qp = Q + (size_t)(b * 2048 + q0) * 1024 + h * 64;
  const unsigned short* Kp = Kg + (size_t)(b * 2048) * 1024 + h * 64;
  const unsigned short* VTp = VT + (size_t)bh * 64 * 2048;
  const unsigned short* mbp = MB + b * 2048;

  {  // stage Q [64][64] once through Ks head (plain layout, consumed to regs)
    const int rq = l >> 3, cs = l & 7;
#pragma unroll
    for (int i = 0; i < 2; ++i) {
      const int c = w * 2 + i;
      load_lds_128(Qp + (size_t)(c * 8 + rq) * 1024 + cs * 8, (char*)Ks + c * 1024);
    }
  }
  __syncthreads();
  short8 qf[2];  // B-operand: lane holds Q[q0+w*16+lr][d = lq*8 + 0..7 (+32)]
  qf[0] = *(const short8*)((const char*)Ks + (w * 16 + lr) * 128 + lq * 16);
  qf[1] = *(const short8*)((const char*)Ks + (w * 16 + lr) * 128 + 64 + lq * 16);

  const floatx4 fz = {0.f, 0.f, 0.f, 0.f};
  floatx4 o[4] = {fz, fz, fz, fz};
  floatx4 l_acc = fz;

  const int krow = l >> 3, kslot = l & 7;   // Ks staging: 8 rows / 1KB chunk
  const int vrow = l >> 4, vslot = l & 15;  // VTs staging: 4 rows / 1KB chunk

  for (int kb = 0; kb < 2048; kb += 128) {
    __syncthreads();
#pragma unroll
    for (int i = 0; i < 4; ++i) {
      const int c4 = w * 4 + i;
      {  // Ks rows c4*8..+7; slot kslot holds logical chunk kslot^(row&7)
        const int row = c4 * 8 + krow;
        const int cc = kslot ^ (row & 7);
        load_lds_128(Kp + (size_t)(kb + row) * 1024 + cc * 8, (char*)Ks + c4 * 1024);
      }
      {  // VTs rows c4*4..+3; slot vslot holds logical chunk vslot^(row&15)
        const int row = c4 * 4 + vrow;
        const int cc = vslot ^ (row & 15);
        load_lds_128(VTp + (size_t)row * 2048 + kb + cc * 8, (char*)VTs + c4 * 1024);
      }
    }
    // mask fragments for the 4 PV windows (bf16 0/1; lr-independent -> bcast)
    short8 mf[4];
#pragma unroll
    for (int t = 0; t < 4; ++t) {
      const short4v ma = *(const short4v*)(mbp + kb + t * 32 + lq * 4);
      const short4v mb2 = *(const short4v*)(mbp + kb + t * 32 + 16 + lq * 4);
      mf[t] = short8{ma[0], ma[1], ma[2], ma[3], mb2[0], mb2[1], mb2[2], mb2[3]};
    }
    __syncthreads();

    // two halves of 64 keys each: 4 score-groups -> 2 PV windows
#pragma unroll
    for (int h2 = 0; h2 < 2; ++h2) {
      // S^T: D[m=key][n=q]; lane gets q=lr(col), key=g*16+lq*4+r(row)
      floatx4 s[4];
#pragma unroll
      for (int gg = 0; gg < 4; ++gg) {
        const int g = h2 * 4 + gg;
        const char* rowp = (const char*)Ks + (g * 16 + lr) * 128;
        short8 k0 = *(const short8*)(rowp + ((lq) ^ (lr & 7)) * 16);
        short8 k1 = *(const short8*)(rowp + ((4 + lq) ^ (lr & 7)) * 16);
        floatx4 t = MFMA16(k0, qf[0], fz);
        s[gg] = MFMA16(k1, qf[1], t);
      }
      // p = exp2(score), hw-packed to bf16 A-fragments (key-permuted)
      short8 pf[2];
#pragma unroll
      for (int tt = 0; tt < 2; ++tt) {
        const floatx4 sL = s[tt * 2], sH = s[tt * 2 + 1];
        union { uint32_t u[4]; short8 s8; } pk;
        pk.u[0] = pkbf(EXP2(sL[0]), EXP2(sL[1]));
        pk.u[1] = pkbf(EXP2(sL[2]), EXP2(sL[3]));
        pk.u[2] = pkbf(EXP2(sH[0]), EXP2(sH[1]));
        pk.u[3] = pkbf(EXP2(sH[2]), EXP2(sH[3]));
        pf[tt] = pk.s8;
      }
      // PV: windows t = h2*2 + tt over 32 keys each
#pragma unroll
      for (int tt = 0; tt < 2; ++tt) {
        const int t = h2 * 2 + tt;
        l_acc = MFMA16(pf[tt], mf[t], l_acc);
        const int kc0 = t * 4 + (lq >> 1);       // 16B chunk of low 16-key half
        const int off = (lq & 1) * 8;            // byte offset within chunk
#pragma unroll
        for (int nt = 0; nt < 4; ++nt) {
          const int d = nt * 16 + lr;
          const char* vrow_p = (const char*)VTs + d * 256;
          short4v va = *(const short4v*)(vrow_p + ((kc0 ^ (d & 15)) * 16) + off);
          short4v vb = *(const short4v*)(vrow_p + (((kc0 + 2) ^ (d & 15)) * 16) + off);
          short8 vf = {va[0], va[1], va[2], va[3], vb[0], vb[1], vb[2], vb[3]};
          o[nt] = MFMA16(pf[tt], vf, o[nt]);
        }
      }
    }
  }

  // epilogue: o C-layout: q = q0 + w*16 + lq*4 + r, d = nt*16 + lr
#pragma unroll
  for (int r = 0; r < 4; ++r) {
    const float inv = 1.0f / l_acc[r];
    const int q = q0 + w * 16 + lq * 4 + r;
#pragma unroll
    for (int nt = 0; nt < 4; ++nt)
      ctx[(size_t)(b * 2048 + q) * 1024 + h * 64 + nt * 16 + lr] = f2bf(o[nt][r] * inv);
  }
}

// ---------------------------------------------------------------------------
// fused residual + dual bf16-partial sum + bias + LayerNorm over rows of 1024.
// v = res + y0 + y1 + bias; out = LN(v)*gamma + beta.
template <int RESBF, int OUTBF>
__global__ __launch_bounds__(256) void ln2_kernel(
    const void* __restrict__ res, const unsigned short* __restrict__ y0,
    const unsigned short* __restrict__ y1, const float* __restrict__ bias,
    const float* __restrict__ gamma, const float* __restrict__ beta,
    void* __restrict__ outp) {
  const int row = blockIdx.x, t = threadIdx.x;
  const size_t base = (size_t)row * 1024 + t * 4;
  float v[4];
  if (RESBF) {
    ushort4v r4 = *(const ushort4v*)((const unsigned short*)res + base);
#pragma unroll
    for (int j = 0; j < 4; ++j) v[j] = bf2f(r4[j]);
  } else {
    floatx4 r4 = *(const floatx4*)((const float*)res + base);
#pragma unroll
    for (int j = 0; j < 4; ++j) v[j] = r4[j];
  }
  const ushort4v a4 = *(const ushort4v*)(y0 + base);
  const ushort4v b4v = *(const ushort4v*)(y1 + base);
  const floatx4 bi4 = *(const floatx4*)(bias + t * 4);
  float s = 0.f, ss = 0.f;
#pragma unroll
  for (int j = 0; j < 4; ++j) {
    v[j] += bf2f(a4[j]) + bf2f(b4v[j]) + bi4[j];
    s += v[j];
    ss += v[j] * v[j];
  }
#pragma unroll
  for (int off = 1; off < 64; off <<= 1) {
    s += __shfl_xor(s, off);
    ss += __shfl_xor(ss, off);
  }
  __shared__ float red[8];
  const int w = t >> 6;
  if ((t & 63) == 0) { red[w] = s; red[4 + w] = ss; }
  __syncthreads();
  s = red[0] + red[1] + red[2] + red[3];
  ss = red[4] + red[5] + red[6] + red[7];
  const float mean = s * (1.0f / 1024.0f);
  const float var = ss * (1.0f / 1024.0f) - mean * mean;
  const float rstd = rsqrtf(var + 1e-6f);
  const floatx4 g4 = *(const floatx4*)(gamma + t * 4);
  const floatx4 be4 = *(const floatx4*)(beta + t * 4);
  if (OUTBF) {
    union { uint32_t u[2]; ushort4v v4; } o;
    o.u[0] = pkbf((v[0] - mean) * rstd * g4[0] + be4[0],
                  (v[1] - mean) * rstd * g4[1] + be4[1]);
    o.u[1] = pkbf((v[2] - mean) * rstd * g4[2] + be4[2],
                  (v[3] - mean) * rstd * g4[3] + be4[3]);
    *(ushort4v*)((unsigned short*)outp + base) = o.v4;
  } else {
    floatx4 o;
#pragma unroll
    for (int j = 0; j < 4; ++j) o[j] = (v[j] - mean) * rstd * g4[j] + be4[j];
    *(floatx4*)((float*)outp + base) = o;
  }
}

// ---------------------------------------------------------------------------
extern "C" void kernel_launch(void* const* d_in, const int* in_sizes, int n_in,
                              void* d_out, int out_size, void* d_ws, size_t ws_size,
                              hipStream_t stream) {
  (void)in_sizes; (void)n_in; (void)out_size; (void)ws_size;
  const float* x    = (const float*)d_in[0];
  const int*   mask = (const int*)d_in[1];
  const float* wq   = (const float*)d_in[2];
  const float* wk   = (const float*)d_in[3];
  const float* wv   = (const float*)d_in[4];
  const float* wo   = (const float*)d_in[5];
  const float* wo_b = (const float*)d_in[6];
  const float* w1   = (const float*)d_in[7];
  const float* b1   = (const float*)d_in[8];
  const float* w2   = (const float*)d_in[9];
  const float* b2   = (const float*)d_in[10];
  const float* g1   = (const float*)d_in[11];
  const float* be1  = (const float*)d_in[12];
  const float* g2   = (const float*)d_in[13];
  const float* be2  = (const float*)d_in[14];
  float* out = (float*)d_out;

  char* ws = (char*)d_ws;
  const size_t MBy = 1024ull * 1024ull;
  // phase-aliased workspace (80 MB):
  unsigned short* WQKV = (unsigned short*)(ws + 0 * MBy);   // 6MB  (dead after QKV gemm)
  unsigned short* WOT  = (unsigned short*)(ws + 6 * MBy);   // 2MB  (dead after WO gemm)
  unsigned short* W1T  = (unsigned short*)(ws + 8 * MBy);   // 8MB  (dead after FF1)
  unsigned short* W2T  = (unsigned short*)(ws + 16 * MBy);  // 8MB  (dead after FF2)
  unsigned short* XB   = (unsigned short*)(ws + 24 * MBy);  // 8MB  (dead after QKV)
  unsigned short* Qb   = (unsigned short*)(ws + 32 * MBy);  // 8MB  (dead after flash)
  unsigned short* Kb   = (unsigned short*)(ws + 40 * MBy);  // 8MB  (dead after flash)
  unsigned short* VTb  = (unsigned short*)(ws + 48 * MBy);  // 8MB  (dead after flash)
  unsigned short* CTX  = (unsigned short*)(ws + 56 * MBy);  // 8MB  (dead after WO gemm)
  unsigned short* ATT0 = (unsigned short*)(ws + 32 * MBy);  // 8MB bf16, over Qb
  unsigned short* ATT1 = (unsigned short*)(ws + 40 * MBy);  // 8MB bf16, over Kb
  unsigned short* Hb   = (unsigned short*)(ws + 24 * MBy);  // 8MB  over XB
  unsigned short* G1   = (unsigned short*)(ws + 32 * MBy);  // 32MB over ATT0/ATT1/VTb/CTX
  unsigned short* FF20 = (unsigned short*)(ws + 64 * MBy);  // 8MB bf16
  unsigned short* FF21 = (unsigned short*)(ws + 72 * MBy);  // 8MB bf16
  unsigned short* MB   = (unsigned short*)(ws + 78 * MBy);  // 8KB bf16 mask (inside FF21
                                                            // region; FF21 written after flash)

  // 1. prep: cast x + all 6 weight transposes + bf16 mask in one launch
  prep_kernel<<<16385, 256, 0, stream>>>(x, XB, wq, wk, wv, wo, WQKV, WOT,
                                         w1, W1T, w2, W2T, mask, MB);
  // 2. fused QKV projection: N=3072 -> 768 blocks; Q pre-scaled, V masked
  gemm_bt_kernel<5, 1><<<dim3(24, 32), 256, 0, stream>>>(
      XB, WQKV, nullptr, Qb, Kb, VTb, 4096, 3072, 1024, mask);
  // 3. attention
  flash_kernel<<<dim3(32, 32), 256, 0, stream>>>(Qb, Kb, VTb, MB, CTX);
  // 4. output projection, split-K=2 bf16 partials (bias folded into LN1)
  gemm_bt_kernel<4, 2><<<dim3(8, 32, 2), 256, 0, stream>>>(
      CTX, WOT, nullptr, ATT0, ATT1, nullptr, 4096, 1024, 1024, nullptr);
  // 5. LN1: h = LN(x + att0 + att1 + wo_b) -> bf16
  ln2_kernel<0, 1><<<4096, 256, 0, stream>>>(x, ATT0, ATT1, wo_b, g1, be1, Hb);
  // 6. FF1 + bias + fast GELU -> bf16
  gemm_bt_kernel<2, 1><<<dim3(32, 32), 256, 0, stream>>>(
      Hb, W1T, b1, G1, nullptr, nullptr, 4096, 4096, 1024, nullptr);
  // 7. FF2, split-K=2 bf16 partials (bias folded into LN2)
  gemm_bt_kernel<4, 2><<<dim3(8, 32, 2), 256, 0, stream>>>(
      G1, W2T, nullptr, FF20, FF21, nullptr, 4096, 1024, 4096, nullptr);
  // 8. LN2: out = LN(h + ff0 + ff1 + b2) -> fp32
  ln2_kernel<1, 0><<<4096, 256, 0, stream>>>(Hb, FF20, FF21, b2, g2, be2, out);
}

// Round 9
// 358.720 us; speedup vs baseline: 1.0366x; 1.0301x over previous
//
#include <hip/hip_runtime.h>
#include <cstdint>

#define DEVINL __device__ __forceinline__

typedef __attribute__((ext_vector_type(8))) short short8;       // 8 x bf16 (4 VGPRs)
typedef __attribute__((ext_vector_type(4))) short short4v;      // 4 x bf16 (2 VGPRs)
typedef __attribute__((ext_vector_type(4))) float floatx4;
typedef __attribute__((ext_vector_type(4))) unsigned short ushort4v;

// hardware packed cvt: D = {bf16(a), bf16(b)} (RNE) — use ONLY for true pair
// packs (scalar use regressed R7: asm blocks CSE, +20 VGPR in GEMM epilogue).
DEVINL uint32_t pkbf(float a, float b) {
  uint32_t d;
  asm("v_cvt_pk_bf16_f32 %0, %1, %2" : "=v"(d) : "v"(a), "v"(b));
  return d;
}
// software RNE fp32->bf16 for scalar stores (compiler-schedulable)
DEVINL unsigned short f2bf(float f) {
  union { float f; uint32_t u; } v; v.f = f;
  return (unsigned short)((v.u + 0x7fffu + ((v.u >> 16) & 1u)) >> 16);
}
DEVINL float bf2f(unsigned short h) {
  union { uint32_t u; float f; } v; v.u = ((uint32_t)h) << 16;
  return v.f;
}

#if defined(__has_builtin) && __has_builtin(__builtin_amdgcn_exp2f)
#define EXP2(x) __builtin_amdgcn_exp2f(x)
#else
#define EXP2(x) exp2f(x)
#endif

// fast GELU (tanh form, exp2-based): max |err| ~3e-4 vs exact erf GELU.
DEVINL float fast_gelu(float v) {
  const float z = -2.30220795f * v * (1.0f + 0.044715f * v * v);
  return v * __builtin_amdgcn_rcpf(1.0f + EXP2(z));
}

typedef __attribute__((address_space(3))) unsigned char* lds_ptr_t;
typedef const __attribute__((address_space(1))) unsigned char* gbl_ptr_t;
// async global->LDS, 16B per lane; LDS dest = wave-uniform base + lane*16
DEVINL void load_lds_128(const void* g, void* l) {
  __builtin_amdgcn_global_load_lds((gbl_ptr_t)g, (lds_ptr_t)l, 16, 0, 0);
}

#define MFMA16(a, b, c) __builtin_amdgcn_mfma_f32_16x16x32_bf16((a), (b), (c), 0, 0, 0)

// 0.125 (1/sqrt(Dk)) * log2(e): folds attention scale AND base-2 softmax into Q
#define QSCALE2 0.18033688011112042f

// ---------------------------------------------------------------------------
// prep: blocks 0..4095 cast x->bf16; 4096..8191 four 1024^2 transposes;
// 8192..12287 w1; 12288..16383 w2; 16384 converts mask(int)->bf16 0/1.
__global__ __launch_bounds__(256) void prep_kernel(
    const float* __restrict__ x, unsigned short* __restrict__ XB,
    const float* __restrict__ wq, const float* __restrict__ wk,
    const float* __restrict__ wv, const float* __restrict__ wo,
    unsigned short* __restrict__ WQKV, unsigned short* __restrict__ WOT,
    const float* __restrict__ w1, unsigned short* __restrict__ W1T,
    const float* __restrict__ w2, unsigned short* __restrict__ W2T,
    const int* __restrict__ mask, unsigned short* __restrict__ MB) {
  const int bid = blockIdx.x;
  if (bid >= 16384) {  // mask -> bf16 0/1
    const int i0 = threadIdx.x * 16;
#pragma unroll
    for (int j = 0; j < 16; ++j) MB[i0 + j] = mask[i0 + j] ? 0x3F80 : 0;
    return;
  }
  if (bid < 4096) {  // cast x (pair-packed hw cvt)
    const int i = (bid * 256 + threadIdx.x) * 4;
    floatx4 v = *(const floatx4*)(x + i);
    union { uint32_t u[2]; ushort4v v4; } o;
    o.u[0] = pkbf(v[0], v[1]);
    o.u[1] = pkbf(v[2], v[3]);
    *(ushort4v*)(XB + i) = o.v4;
    return;
  }
  const float* in;
  unsigned short* out;
  int K, N, bx, by;
  if (bid < 8192) {
    const int b2 = bid - 4096, z = b2 >> 10;
    in = (z == 0) ? wq : (z == 1) ? wk : (z == 2) ? wv : wo;
    out = (z == 3) ? WOT : WQKV + (size_t)z * 1024 * 1024;
    K = 1024; N = 1024; bx = b2 & 31; by = (b2 >> 5) & 31;
  } else if (bid < 12288) {
    const int b3 = bid - 8192;
    in = w1; out = W1T; K = 1024; N = 4096; bx = b3 & 127; by = b3 >> 7;
  } else {
    const int b4 = bid - 12288;
    in = w2; out = W2T; K = 4096; N = 1024; bx = b4 & 31; by = b4 >> 5;
  }
  __shared__ float tile[32][33];
  const int n0 = bx * 32, k0 = by * 32;
  const int tx = threadIdx.x & 31, ty = threadIdx.x >> 5;  // 32 x 8
#pragma unroll
  for (int i = 0; i < 4; ++i)
    tile[ty + 8 * i][tx] = in[(size_t)(k0 + ty + 8 * i) * N + n0 + tx];
  __syncthreads();
#pragma unroll
  for (int i = 0; i < 4; ++i)
    out[(size_t)(n0 + ty + 8 * i) * K + k0 + tx] = f2bf(tile[tx][ty + 8 * i]);
}

// ---------------------------------------------------------------------------
// GEMM: C = A[M,K] @ BT[N,K]^T  (bf16 in, fp32 acc), BM=BN=128, BK=64, 256 thr.
// Natural block mapping (R8's XCD strip-swizzle destroyed A row-panel L2
// sharing — reverted).
// SK: split-K factor (blockIdx.z = slice; slice 0 -> C0, slice 1 -> C1).
// EPI: 2 = bias + fast GELU -> bf16
//      4 = bf16 partial store (split-K; bias added downstream in LN)
//      5 = fused QKV epilogue: region 0 -> Q*QSCALE2 (C0); 1 -> K (C1);
//          2 -> V * mask, per-head-transposed [bh][64][2048] with keys
//          PERMUTED within each 32-group (p = (u&3)|(bit4<<2)|((u>>2&3)<<3))
//          so flash PV B-fragments are single b128 reads (C2)
template <int EPI, int SK>
__global__ __launch_bounds__(256) void gemm_bt_kernel(
    const unsigned short* __restrict__ A, const unsigned short* __restrict__ BT,
    const float* __restrict__ bias, void* __restrict__ C0, void* __restrict__ C1,
    void* __restrict__ C2, int M, int N, int K, const int* __restrict__ msk) {
  __shared__ __align__(16) unsigned short As[128 * 64];   // 2 panels x 8KB
  __shared__ __align__(16) unsigned short Bs[128 * 64];
  const int tid = threadIdx.x;
  const int w = tid >> 6, l = tid & 63;
  const int lq = l >> 4, lr = l & 15;
  const int m0 = blockIdx.y * 128, n0 = blockIdx.x * 128;
  const int wm = (w >> 1) * 64, wn = (w & 1) * 64;
  const int r_a = l >> 2;            // row within 16-row chunk
  const int colb = (l & 3) * 8;      // col (8 bf16 = 16B)
  const int kslice = K / SK;
  const int kbeg = kslice * blockIdx.z;
  const int region = (EPI == 5) ? (n0 >> 10) : 0;  // block-uniform

  // V-row mask, 16 packed bits (loads overlap the K-loop staging)
  uint32_t mbits = 0xFFFFu;
  if (EPI == 5 && region == 2) {
    mbits = 0;
#pragma unroll
    for (int mt = 0; mt < 4; ++mt) {
      const int4 m4 = *(const int4*)(msk + m0 + wm + mt * 16 + lq * 4);
      mbits |= (m4.x ? 1u : 0u) << (mt * 4);
      mbits |= (m4.y ? 1u : 0u) << (mt * 4 + 1);
      mbits |= (m4.z ? 1u : 0u) << (mt * 4 + 2);
      mbits |= (m4.w ? 1u : 0u) << (mt * 4 + 3);
    }
  }

  floatx4 acc[4][4];
  const floatx4 fz = {0.f, 0.f, 0.f, 0.f};
#pragma unroll
  for (int mt = 0; mt < 4; ++mt)
#pragma unroll
    for (int nt = 0; nt < 4; ++nt) acc[mt][nt] = fz;

  for (int k0 = kbeg; k0 < kbeg + kslice; k0 += 64) {
    __syncthreads();
#pragma unroll
    for (int p = 0; p < 2; ++p) {
#pragma unroll
      for (int i = 0; i < 2; ++i) {
        const int c = w * 2 + i;
        load_lds_128(A + (size_t)(m0 + c * 16 + r_a) * K + k0 + p * 32 + colb,
                     (char*)As + p * 8192 + c * 1024);
        load_lds_128(BT + (size_t)(n0 + c * 16 + r_a) * K + k0 + p * 32 + colb,
                     (char*)Bs + p * 8192 + c * 1024);
      }
    }
    __syncthreads();
#pragma unroll
    for (int p = 0; p < 2; ++p) {
      short8 af[4], bf[4];
#pragma unroll
      for (int mt = 0; mt < 4; ++mt)
        af[mt] = *(const short8*)((const char*)As + p * 8192 + (wm + mt * 16 + lr) * 64 + lq * 16);
#pragma unroll
      for (int nt = 0; nt < 4; ++nt)
        bf[nt] = *(const short8*)((const char*)Bs + p * 8192 + (wn + nt * 16 + lr) * 64 + lq * 16);
#pragma unroll
      for (int mt = 0; mt < 4; ++mt)
#pragma unroll
        for (int nt = 0; nt < 4; ++nt)
          acc[mt][nt] = MFMA16(af[mt], bf[nt], acc[mt][nt]);
    }
  }

  void* Cp = (SK > 1 && blockIdx.z) ? C1 : C0;
  // epilogue: C row = quad*4+reg, col = lane&15
#pragma unroll
  for (int mt = 0; mt < 4; ++mt) {
#pragma unroll
    for (int nt = 0; nt < 4; ++nt) {
      const int n = n0 + wn + nt * 16 + lr;
      float bval = 0.f;
      if (EPI == 2) bval = bias[n];
#pragma unroll
      for (int r = 0; r < 4; ++r) {
        const int m = m0 + wm + mt * 16 + lq * 4 + r;
        float v = acc[mt][nt][r];
        if (EPI == 4) {
          ((unsigned short*)Cp)[(size_t)m * N + n] = f2bf(v);
        } else if (EPI == 2) {
          ((unsigned short*)C0)[(size_t)m * N + n] = f2bf(fast_gelu(v + bval));
        } else {  // EPI == 5
          if (region == 0) {
            ((unsigned short*)C0)[(size_t)m * 1024 + n] = f2bf(v * QSCALE2);
          } else if (region == 1) {
            ((unsigned short*)C1)[(size_t)m * 1024 + (n - 1024)] = f2bf(v);
          } else {
            const int nn = n - 2048;
            const int bidx = m >> 11, s = m & 2047;
            // key permutation within 32-group: p = (u&3)|(bit4<<2)|((u>>2&3)<<3)
            const int u = s & 31;
            const int sp = (s & ~31) | (u & 3) | (((u >> 4) & 1) << 2) | (((u >> 2) & 3) << 3);
            const int hh = nn >> 6, d = nn & 63;
            const float vv = ((mbits >> (mt * 4 + r)) & 1u) ? v : 0.f;
            ((unsigned short*)C2)[((size_t)((bidx * 16 + hh) * 64 + d)) * 2048 + sp] = f2bf(vv);
          }
        }
      }
    }
  }
}

// ---------------------------------------------------------------------------
// Flash attention: S=2048, Dk=64. Q PRE-SCALED by 0.125*log2e (exp2 domain).
// FIXED-SHIFT softmax (p = exp2(score), no running max) + TRANSPOSED-SCORE
// register pipeline: S^T = K·Q^T, so the S^T C/D fragment is directly a PV
// A-operand under key-permutation phi. V is stored PRE-PERMUTED (QKV
// epilogue) so phi runs 8 consecutive stored keys -> V B-fragment is ONE
// ds_read_b128 (was 2x b64 scatter, 8.5e6 bank-conflict cycles in R6-R8).
// Mask pre-folded: V columns zeroed upstream; denominator via MFMA against a
// bf16 0/1 mask fragment (MB enumerated in phi order already).
// LDS 32 KB (Ks 16K + VTs 16K). grid (S/64, B*H); 256 thr.
__global__ __launch_bounds__(256, 4) void flash_kernel(
    const unsigned short* __restrict__ Q, const unsigned short* __restrict__ Kg,
    const unsigned short* __restrict__ VT, const unsigned short* __restrict__ MB,
    unsigned short* __restrict__ ctx) {
  __shared__ __align__(16) unsigned short Ks[128 * 64];    // [key][d], swizzled
  __shared__ __align__(16) unsigned short VTs[64 * 128];   // [d][key'], swizzled

  const int tid = threadIdx.x, w = tid >> 6, l = tid & 63;
  const int lq = l >> 4, lr = l & 15;
  const int bh = blockIdx.y, b = bh >> 4, h = bh & 15;
  const int q0 = blockIdx.x * 64;

  const unsigned short* Qp = Q + (size_t)(b * 2048 + q0) * 1024 + h * 64;
  const unsigned short* Kp = Kg + (size_t)(b * 2048) * 1024 + h * 64;
  const unsigned short* VTp = VT + (size_t)bh * 64 * 2048;
  const unsigned short* mbp = MB + b * 2048;

  {  // stage Q [64][64] once through Ks head (plain layout, consumed to regs)
    const int rq = l >> 3, cs = l & 7;
#pragma unroll
    for (int i = 0; i < 2; ++i) {
      const int c = w * 2 + i;
      load_lds_128(Qp + (size_t)(c * 8 + rq) * 1024 + cs * 8, (char*)Ks + c * 1024);
    }
  }
  __syncthreads();
  short8 qf[2];  // B-operand: lane holds Q[q0+w*16+lr][d = lq*8 + 0..7 (+32)]
  qf[0] = *(const short8*)((const char*)Ks + (w * 16 + lr) * 128 + lq * 16);
  qf[1] = *(const short8*)((const char*)Ks + (w * 16 + lr) * 128 + 64 + lq * 16);

  const floatx4 fz = {0.f, 0.f, 0.f, 0.f};
  floatx4 o[4] = {fz, fz, fz, fz};
  floatx4 l_acc = fz;

  const int krow = l >> 3, kslot = l & 7;   // Ks staging: 8 rows / 1KB chunk
  const int vrow = l >> 4, vslot = l & 15;  // VTs staging: 4 rows / 1KB chunk

  for (int kb = 0; kb < 2048; kb += 128) {
    __syncthreads();
#pragma unroll
    for (int i = 0; i < 4; ++i) {
      const int c4 = w * 4 + i;
      {  // Ks rows c4*8..+7; slot kslot holds logical chunk kslot^(row&7)
        const int row = c4 * 8 + krow;
        const int cc = kslot ^ (row & 7);
        load_lds_128(Kp + (size_t)(kb + row) * 1024 + cc * 8, (char*)Ks + c4 * 1024);
      }
      {  // VTs rows c4*4..+3; slot vslot holds logical chunk vslot^(row&15)
        const int row = c4 * 4 + vrow;
        const int cc = vslot ^ (row & 15);
        load_lds_128(VTp + (size_t)row * 2048 + kb + cc * 8, (char*)VTs + c4 * 1024);
      }
    }
    // mask fragments for the 4 PV windows (already in phi key order)
    short8 mf[4];
#pragma unroll
    for (int t = 0; t < 4; ++t) {
      const short4v ma = *(const short4v*)(mbp + kb + t * 32 + lq * 4);
      const short4v mb2 = *(const short4v*)(mbp + kb + t * 32 + 16 + lq * 4);
      mf[t] = short8{ma[0], ma[1], ma[2], ma[3], mb2[0], mb2[1], mb2[2], mb2[3]};
    }
    __syncthreads();

    // two halves of 64 keys each: 4 score-groups -> 2 PV windows
#pragma unroll
    for (int h2 = 0; h2 < 2; ++h2) {
      // S^T: D[m=key][n=q]; lane gets q=lr(col), key=g*16+lq*4+r(row)
      floatx4 s[4];
#pragma unroll
      for (int gg = 0; gg < 4; ++gg) {
        const int g = h2 * 4 + gg;
        const char* rowp = (const char*)Ks + (g * 16 + lr) * 128;
        short8 k0 = *(const short8*)(rowp + ((lq) ^ (lr & 7)) * 16);
        short8 k1 = *(const short8*)(rowp + ((4 + lq) ^ (lr & 7)) * 16);
        floatx4 t = MFMA16(k0, qf[0], fz);
        s[gg] = MFMA16(k1, qf[1], t);
      }
      // p = exp2(score), hw-packed to bf16 A-fragments (phi key order)
      short8 pf[2];
#pragma unroll
      for (int tt = 0; tt < 2; ++tt) {
        const floatx4 sL = s[tt * 2], sH = s[tt * 2 + 1];
        union { uint32_t u[4]; short8 s8; } pk;
        pk.u[0] = pkbf(EXP2(sL[0]), EXP2(sL[1]));
        pk.u[1] = pkbf(EXP2(sL[2]), EXP2(sL[3]));
        pk.u[2] = pkbf(EXP2(sH[0]), EXP2(sH[1]));
        pk.u[3] = pkbf(EXP2(sH[2]), EXP2(sH[3]));
        pf[tt] = pk.s8;
      }
      // PV: windows t = h2*2 + tt over 32 keys each; V fragment = one b128
#pragma unroll
      for (int tt = 0; tt < 2; ++tt) {
        const int t = h2 * 2 + tt;
        l_acc = MFMA16(pf[tt], mf[t], l_acc);
#pragma unroll
        for (int nt = 0; nt < 4; ++nt) {
          const int d = nt * 16 + lr;
          short8 vf = *(const short8*)((const char*)VTs + d * 256 +
                                       (((t * 4 + lq) ^ (d & 15)) * 16));
          o[nt] = MFMA16(pf[tt], vf, o[nt]);
        }
      }
    }
  }

  // epilogue: o C-layout: q = q0 + w*16 + lq*4 + r, d = nt*16 + lr
#pragma unroll
  for (int r = 0; r < 4; ++r) {
    const float inv = 1.0f / l_acc[r];
    const int q = q0 + w * 16 + lq * 4 + r;
#pragma unroll
    for (int nt = 0; nt < 4; ++nt)
      ctx[(size_t)(b * 2048 + q) * 1024 + h * 64 + nt * 16 + lr] = f2bf(o[nt][r] * inv);
  }
}

// ---------------------------------------------------------------------------
// fused residual + dual bf16-partial sum + bias + LayerNorm over rows of 1024.
// v = res + y0 + y1 + bias; out = LN(v)*gamma + beta.
template <int RESBF, int OUTBF>
__global__ __launch_bounds__(256) void ln2_kernel(
    const void* __restrict__ res, const unsigned short* __restrict__ y0,
    const unsigned short* __restrict__ y1, const float* __restrict__ bias,
    const float* __restrict__ gamma, const float* __restrict__ beta,
    void* __restrict__ outp) {
  const int row = blockIdx.x, t = threadIdx.x;
  const size_t base = (size_t)row * 1024 + t * 4;
  float v[4];
  if (RESBF) {
    ushort4v r4 = *(const ushort4v*)((const unsigned short*)res + base);
#pragma unroll
    for (int j = 0; j < 4; ++j) v[j] = bf2f(r4[j]);
  } else {
    floatx4 r4 = *(const floatx4*)((const float*)res + base);
#pragma unroll
    for (int j = 0; j < 4; ++j) v[j] = r4[j];
  }
  const ushort4v a4 = *(const ushort4v*)(y0 + base);
  const ushort4v b4v = *(const ushort4v*)(y1 + base);
  const floatx4 bi4 = *(const floatx4*)(bias + t * 4);
  float s = 0.f, ss = 0.f;
#pragma unroll
  for (int j = 0; j < 4; ++j) {
    v[j] += bf2f(a4[j]) + bf2f(b4v[j]) + bi4[j];
    s += v[j];
    ss += v[j] * v[j];
  }
#pragma unroll
  for (int off = 1; off < 64; off <<= 1) {
    s += __shfl_xor(s, off);
    ss += __shfl_xor(ss, off);
  }
  __shared__ float red[8];
  const int w = t >> 6;
  if ((t & 63) == 0) { red[w] = s; red[4 + w] = ss; }
  __syncthreads();
  s = red[0] + red[1] + red[2] + red[3];
  ss = red[4] + red[5] + red[6] + red[7];
  const float mean = s * (1.0f / 1024.0f);
  const float var = ss * (1.0f / 1024.0f) - mean * mean;
  const float rstd = rsqrtf(var + 1e-6f);
  const floatx4 g4 = *(const floatx4*)(gamma + t * 4);
  const floatx4 be4 = *(const floatx4*)(beta + t * 4);
  if (OUTBF) {
    union { uint32_t u[2]; ushort4v v4; } o;
    o.u[0] = pkbf((v[0] - mean) * rstd * g4[0] + be4[0],
                  (v[1] - mean) * rstd * g4[1] + be4[1]);
    o.u[1] = pkbf((v[2] - mean) * rstd * g4[2] + be4[2],
                  (v[3] - mean) * rstd * g4[3] + be4[3]);
    *(ushort4v*)((unsigned short*)outp + base) = o.v4;
  } else {
    floatx4 o;
#pragma unroll
    for (int j = 0; j < 4; ++j) o[j] = (v[j] - mean) * rstd * g4[j] + be4[j];
    *(floatx4*)((float*)outp + base) = o;
  }
}

// ---------------------------------------------------------------------------
extern "C" void kernel_launch(void* const* d_in, const int* in_sizes, int n_in,
                              void* d_out, int out_size, void* d_ws, size_t ws_size,
                              hipStream_t stream) {
  (void)in_sizes; (void)n_in; (void)out_size; (void)ws_size;
  const float* x    = (const float*)d_in[0];
  const int*   mask = (const int*)d_in[1];
  const float* wq   = (const float*)d_in[2];
  const float* wk   = (const float*)d_in[3];
  const float* wv   = (const float*)d_in[4];
  const float* wo   = (const float*)d_in[5];
  const float* wo_b = (const float*)d_in[6];
  const float* w1   = (const float*)d_in[7];
  const float* b1   = (const float*)d_in[8];
  const float* w2   = (const float*)d_in[9];
  const float* b2   = (const float*)d_in[10];
  const float* g1   = (const float*)d_in[11];
  const float* be1  = (const float*)d_in[12];
  const float* g2   = (const float*)d_in[13];
  const float* be2  = (const float*)d_in[14];
  float* out = (float*)d_out;

  char* ws = (char*)d_ws;
  const size_t MBy = 1024ull * 1024ull;
  // phase-aliased workspace (80 MB):
  unsigned short* WQKV = (unsigned short*)(ws + 0 * MBy);   // 6MB  (dead after QKV gemm)
  unsigned short* WOT  = (unsigned short*)(ws + 6 * MBy);   // 2MB  (dead after WO gemm)
  unsigned short* W1T  = (unsigned short*)(ws + 8 * MBy);   // 8MB  (dead after FF1)
  unsigned short* W2T  = (unsigned short*)(ws + 16 * MBy);  // 8MB  (dead after FF2)
  unsigned short* XB   = (unsigned short*)(ws + 24 * MBy);  // 8MB  (dead after QKV)
  unsigned short* Qb   = (unsigned short*)(ws + 32 * MBy);  // 8MB  (dead after flash)
  unsigned short* Kb   = (unsigned short*)(ws + 40 * MBy);  // 8MB  (dead after flash)
  unsigned short* VTb  = (unsigned short*)(ws + 48 * MBy);  // 8MB  (dead after flash)
  unsigned short* CTX  = (unsigned short*)(ws + 56 * MBy);  // 8MB  (dead after WO gemm)
  unsigned short* ATT0 = (unsigned short*)(ws + 32 * MBy);  // 8MB bf16, over Qb
  unsigned short* ATT1 = (unsigned short*)(ws + 40 * MBy);  // 8MB bf16, over Kb
  unsigned short* Hb   = (unsigned short*)(ws + 24 * MBy);  // 8MB  over XB
  unsigned short* G1   = (unsigned short*)(ws + 32 * MBy);  // 32MB over ATT0/ATT1/VTb/CTX
  unsigned short* FF20 = (unsigned short*)(ws + 64 * MBy);  // 8MB bf16
  unsigned short* FF21 = (unsigned short*)(ws + 72 * MBy);  // 8MB bf16
  unsigned short* MB   = (unsigned short*)(ws + 78 * MBy);  // 8KB bf16 mask (inside FF21
                                                            // region; FF21 written after flash)

  // 1. prep: cast x + all 6 weight transposes + bf16 mask in one launch
  prep_kernel<<<16385, 256, 0, stream>>>(x, XB, wq, wk, wv, wo, WQKV, WOT,
                                         w1, W1T, w2, W2T, mask, MB);
  // 2. fused QKV projection: N=3072 -> 768 blocks; Q pre-scaled, V masked+permuted
  gemm_bt_kernel<5, 1><<<dim3(24, 32), 256, 0, stream>>>(
      XB, WQKV, nullptr, Qb, Kb, VTb, 4096, 3072, 1024, mask);
  // 3. attention
  flash_kernel<<<dim3(32, 32), 256, 0, stream>>>(Qb, Kb, VTb, MB, CTX);
  // 4. output projection, split-K=2 bf16 partials (bias folded into LN1)
  gemm_bt_kernel<4, 2><<<dim3(8, 32, 2), 256, 0, stream>>>(
      CTX, WOT, nullptr, ATT0, ATT1, nullptr, 4096, 1024, 1024, nullptr);
  // 5. LN1: h = LN(x + att0 + att1 + wo_b) -> bf16
  ln2_kernel<0, 1><<<4096, 256, 0, stream>>>(x, ATT0, ATT1, wo_b, g1, be1, Hb);
  // 6. FF1 + bias + fast GELU -> bf16
  gemm_bt_kernel<2, 1><<<dim3(32, 32), 256, 0, stream>>>(
      Hb, W1T, b1, G1, nullptr, nullptr, 4096, 4096, 1024, nullptr);
  // 7. FF2, split-K=2 bf16 partials (bias folded into LN2)
  gemm_bt_kernel<4, 2><<<dim3(8, 32, 2), 256, 0, stream>>>(
      G1, W2T, nullptr, FF20, FF21, nullptr, 4096, 1024, 4096, nullptr);
  // 8. LN2: out = LN(h + ff0 + ff1 + b2) -> fp32
  ln2_kernel<1, 0><<<4096, 256, 0, stream>>>(Hb, FF20, FF21, b2, g2, be2, out);
}

// Round 10
// 356.806 us; speedup vs baseline: 1.0422x; 1.0054x over previous
//
#include <hip/hip_runtime.h>
#include <cstdint>

#define DEVINL __device__ __forceinline__

typedef __attribute__((ext_vector_type(8))) short short8;       // 8 x bf16 (4 VGPRs)
typedef __attribute__((ext_vector_type(4))) short short4v;      // 4 x bf16 (2 VGPRs)
typedef __attribute__((ext_vector_type(4))) float floatx4;
typedef __attribute__((ext_vector_type(16))) float floatx16;
typedef __attribute__((ext_vector_type(4))) unsigned short ushort4v;

// hardware packed cvt: D = {bf16(a), bf16(b)} (RNE) — use ONLY for true pair
// packs (scalar use regressed R7: asm blocks CSE, +20 VGPR in GEMM epilogue).
DEVINL uint32_t pkbf(float a, float b) {
  uint32_t d;
  asm("v_cvt_pk_bf16_f32 %0, %1, %2" : "=v"(d) : "v"(a), "v"(b));
  return d;
}
// software RNE fp32->bf16 for scalar stores (compiler-schedulable)
DEVINL unsigned short f2bf(float f) {
  union { float f; uint32_t u; } v; v.f = f;
  return (unsigned short)((v.u + 0x7fffu + ((v.u >> 16) & 1u)) >> 16);
}
DEVINL float bf2f(unsigned short h) {
  union { uint32_t u; float f; } v; v.u = ((uint32_t)h) << 16;
  return v.f;
}

#if defined(__has_builtin) && __has_builtin(__builtin_amdgcn_exp2f)
#define EXP2(x) __builtin_amdgcn_exp2f(x)
#else
#define EXP2(x) exp2f(x)
#endif

// fast GELU (tanh form, exp2-based): max |err| ~3e-4 vs exact erf GELU.
DEVINL float fast_gelu(float v) {
  const float z = -2.30220795f * v * (1.0f + 0.044715f * v * v);
  return v * __builtin_amdgcn_rcpf(1.0f + EXP2(z));
}

typedef __attribute__((address_space(3))) unsigned char* lds_ptr_t;
typedef const __attribute__((address_space(1))) unsigned char* gbl_ptr_t;
// async global->LDS, 16B per lane; LDS dest = wave-uniform base + lane*16
DEVINL void load_lds_128(const void* g, void* l) {
  __builtin_amdgcn_global_load_lds((gbl_ptr_t)g, (lds_ptr_t)l, 16, 0, 0);
}

#define MFMA16(a, b, c) __builtin_amdgcn_mfma_f32_16x16x32_bf16((a), (b), (c), 0, 0, 0)
#define MFMA32(a, b, c) __builtin_amdgcn_mfma_f32_32x32x16_bf16((a), (b), (c), 0, 0, 0)

// 0.125 (1/sqrt(Dk)) * log2(e): folds attention scale AND base-2 softmax into Q
#define QSCALE2 0.18033688011112042f

// ---------------------------------------------------------------------------
// prep: blocks 0..4095 cast x->bf16; 4096..8191 four 1024^2 transposes;
// 8192..12287 w1; 12288..16383 w2; 16384 converts mask(int)->bf16 0/1.
__global__ __launch_bounds__(256) void prep_kernel(
    const float* __restrict__ x, unsigned short* __restrict__ XB,
    const float* __restrict__ wq, const float* __restrict__ wk,
    const float* __restrict__ wv, const float* __restrict__ wo,
    unsigned short* __restrict__ WQKV, unsigned short* __restrict__ WOT,
    const float* __restrict__ w1, unsigned short* __restrict__ W1T,
    const float* __restrict__ w2, unsigned short* __restrict__ W2T,
    const int* __restrict__ mask, unsigned short* __restrict__ MB) {
  const int bid = blockIdx.x;
  if (bid >= 16384) {  // mask -> bf16 0/1
    const int i0 = threadIdx.x * 16;
#pragma unroll
    for (int j = 0; j < 16; ++j) MB[i0 + j] = mask[i0 + j] ? 0x3F80 : 0;
    return;
  }
  if (bid < 4096) {  // cast x (pair-packed hw cvt)
    const int i = (bid * 256 + threadIdx.x) * 4;
    floatx4 v = *(const floatx4*)(x + i);
    union { uint32_t u[2]; ushort4v v4; } o;
    o.u[0] = pkbf(v[0], v[1]);
    o.u[1] = pkbf(v[2], v[3]);
    *(ushort4v*)(XB + i) = o.v4;
    return;
  }
  const float* in;
  unsigned short* out;
  int K, N, bx, by;
  if (bid < 8192) {
    const int b2 = bid - 4096, z = b2 >> 10;
    in = (z == 0) ? wq : (z == 1) ? wk : (z == 2) ? wv : wo;
    out = (z == 3) ? WOT : WQKV + (size_t)z * 1024 * 1024;
    K = 1024; N = 1024; bx = b2 & 31; by = (b2 >> 5) & 31;
  } else if (bid < 12288) {
    const int b3 = bid - 8192;
    in = w1; out = W1T; K = 1024; N = 4096; bx = b3 & 127; by = b3 >> 7;
  } else {
    const int b4 = bid - 12288;
    in = w2; out = W2T; K = 4096; N = 1024; bx = b4 & 31; by = b4 >> 5;
  }
  __shared__ float tile[32][33];
  const int n0 = bx * 32, k0 = by * 32;
  const int tx = threadIdx.x & 31, ty = threadIdx.x >> 5;  // 32 x 8
#pragma unroll
  for (int i = 0; i < 4; ++i)
    tile[ty + 8 * i][tx] = in[(size_t)(k0 + ty + 8 * i) * N + n0 + tx];
  __syncthreads();
#pragma unroll
  for (int i = 0; i < 4; ++i)
    out[(size_t)(n0 + ty + 8 * i) * K + k0 + tx] = f2bf(tile[tx][ty + 8 * i]);
}

// ---------------------------------------------------------------------------
// GEMM: C = A[M,K] @ BT[N,K]^T (bf16 in, fp32 acc), BM=BN=128, BK=64, 256 thr.
// 32x32x16 MFMA (measured-faster shape; half the MFMA instr count of
// 16x16x32 for the same FLOPs). Wave tile 64x64 = 2x2 of 32x32.
// A-frag: A[m=lane&31][k=(lane>>5)*8+j]; B-frag: B^T[n=lane&31][k=...].
// LDS rows are 64B (32 K-elems) with 16B chunks XOR-swizzled by (row&3)
// (applied on the GLOBAL source during staging) so the 32-row fragment read
// hits all 32 banks evenly (unswizzled would be 4-way conflicted).
// C/D: col=lane&31, row=(reg&3)+8*(reg>>2)+4*(lane>>5)  [verified m74/m101].
// SK: split-K factor (blockIdx.z = slice; slice 0 -> C0, slice 1 -> C1).
// EPI: 2 = bias + fast GELU -> bf16
//      4 = bf16 partial store (split-K; bias added downstream in LN)
//      5 = fused QKV epilogue: region 0 -> Q*QSCALE2 (C0); 1 -> K (C1);
//          2 -> V * mask, per-head-transposed [bh][64][2048] with keys
//          permuted within 32-groups (flash phi order) (C2)
template <int EPI, int SK>
__global__ __launch_bounds__(256) void gemm_bt_kernel(
    const unsigned short* __restrict__ A, const unsigned short* __restrict__ BT,
    const float* __restrict__ bias, void* __restrict__ C0, void* __restrict__ C1,
    void* __restrict__ C2, int M, int N, int K, const int* __restrict__ msk) {
  __shared__ __align__(16) unsigned short As[128 * 64];   // 2 panels x 8KB
  __shared__ __align__(16) unsigned short Bs[128 * 64];
  const int tid = threadIdx.x;
  const int w = tid >> 6, l = tid & 63;
  const int m0 = blockIdx.y * 128, n0 = blockIdx.x * 128;
  const int wm = (w >> 1) * 64, wn = (w & 1) * 64;
  const int ml = l & 31;             // fragment m/n index
  const int hb = l >> 5;             // k-half selector
  const int r_c = l >> 2;            // staging: row within 16-row chunk
  const int csl = l & 3;             // staging: phys 16B chunk slot
  const int cgl = (csl ^ (r_c & 3)) * 8;  // swizzled global col (elems)
  const int kslice = K / SK;
  const int kbeg = kslice * blockIdx.z;
  const int region = (EPI == 5) ? (n0 >> 10) : 0;  // block-uniform

  // V-row mask bits (EPI=5 region 2): bit reg of mb32[mt] = mask row
  // m0+wm+mt*32+4*hb + (reg&3)+8*(reg>>2)
  uint32_t mb32[2] = {0xFFFFu, 0xFFFFu};
  if (EPI == 5 && region == 2) {
    mb32[0] = mb32[1] = 0;
#pragma unroll
    for (int mt = 0; mt < 2; ++mt)
#pragma unroll
      for (int g = 0; g < 4; ++g) {
        const int4 m4 = *(const int4*)(msk + m0 + wm + mt * 32 + 4 * hb + 8 * g);
        mb32[mt] |= (m4.x ? 1u : 0u) << (g * 4);
        mb32[mt] |= (m4.y ? 1u : 0u) << (g * 4 + 1);
        mb32[mt] |= (m4.z ? 1u : 0u) << (g * 4 + 2);
        mb32[mt] |= (m4.w ? 1u : 0u) << (g * 4 + 3);
      }
  }

  floatx16 acc[2][2];
#pragma unroll
  for (int mt = 0; mt < 2; ++mt)
#pragma unroll
    for (int nt = 0; nt < 2; ++nt)
#pragma unroll
      for (int r = 0; r < 16; ++r) acc[mt][nt][r] = 0.f;

  for (int k0 = kbeg; k0 < kbeg + kslice; k0 += 64) {
    __syncthreads();
#pragma unroll
    for (int p = 0; p < 2; ++p) {
#pragma unroll
      for (int i = 0; i < 2; ++i) {
        const int c = w * 2 + i;
        load_lds_128(A + (size_t)(m0 + c * 16 + r_c) * K + k0 + p * 32 + cgl,
                     (char*)As + p * 8192 + c * 1024);
        load_lds_128(BT + (size_t)(n0 + c * 16 + r_c) * K + k0 + p * 32 + cgl,
                     (char*)Bs + p * 8192 + c * 1024);
      }
    }
    __syncthreads();
#pragma unroll
    for (int p = 0; p < 2; ++p) {
#pragma unroll
      for (int ks = 0; ks < 2; ++ks) {
        short8 af[2], bf[2];
        const int lc = ks * 2 + hb;  // logical 16B chunk
#pragma unroll
        for (int mt = 0; mt < 2; ++mt) {
          const int row = wm + mt * 32 + ml;
          af[mt] = *(const short8*)((const char*)As + p * 8192 + row * 64 +
                                    ((lc ^ (row & 3)) * 16));
        }
#pragma unroll
        for (int nt = 0; nt < 2; ++nt) {
          const int row = wn + nt * 32 + ml;
          bf[nt] = *(const short8*)((const char*)Bs + p * 8192 + row * 64 +
                                    ((lc ^ (row & 3)) * 16));
        }
#pragma unroll
        for (int mt = 0; mt < 2; ++mt)
#pragma unroll
          for (int nt = 0; nt < 2; ++nt)
            acc[mt][nt] = MFMA32(af[mt], bf[nt], acc[mt][nt]);
      }
    }
  }

  void* Cp = (SK > 1 && blockIdx.z) ? C1 : C0;
  // epilogue: m = wm+mt*32+4*hb+(reg&3)+8*(reg>>2), n = wn+nt*32+ml
#pragma unroll
  for (int mt = 0; mt < 2; ++mt) {
#pragma unroll
    for (int nt = 0; nt < 2; ++nt) {
      const int n = n0 + wn + nt * 32 + ml;
      float bval = 0.f;
      if (EPI == 2) bval = bias[n];
#pragma unroll
      for (int reg = 0; reg < 16; ++reg) {
        const int m = m0 + wm + mt * 32 + 4 * hb + (reg & 3) + 8 * (reg >> 2);
        float v = acc[mt][nt][reg];
        if (EPI == 4) {
          ((unsigned short*)Cp)[(size_t)m * N + n] = f2bf(v);
        } else if (EPI == 2) {
          ((unsigned short*)C0)[(size_t)m * N + n] = f2bf(fast_gelu(v + bval));
        } else {  // EPI == 5
          if (region == 0) {
            ((unsigned short*)C0)[(size_t)m * 1024 + n] = f2bf(v * QSCALE2);
          } else if (region == 1) {
            ((unsigned short*)C1)[(size_t)m * 1024 + (n - 1024)] = f2bf(v);
          } else {
            const int nn = n - 2048;
            const int bidx = m >> 11, s = m & 2047;
            // key permutation within 32-group: p = (u&3)|(bit4<<2)|((u>>2&3)<<3)
            const int u = s & 31;
            const int sp = (s & ~31) | (u & 3) | (((u >> 4) & 1) << 2) | (((u >> 2) & 3) << 3);
            const int hh = nn >> 6, d = nn & 63;
            const float vv = ((mb32[mt] >> reg) & 1u) ? v : 0.f;
            ((unsigned short*)C2)[((size_t)((bidx * 16 + hh) * 64 + d)) * 2048 + sp] = f2bf(vv);
          }
        }
      }
    }
  }
}

// ---------------------------------------------------------------------------
// Flash attention: S=2048, Dk=64. Q PRE-SCALED by 0.125*log2e (exp2 domain).
// FIXED-SHIFT softmax (p = exp2(score)) + TRANSPOSED-SCORE register pipeline
// (S^T = K·Q^T -> C/D fragment is directly a PV A-operand under phi; V
// stored pre-permuted so V B-fragment is one ds_read_b128).
// XCD HEAD-GROUPING: 1D grid, xcd = lin&7 owns 4 whole (b,h) heads -> per-XCD
// K/V footprint 2MB fits the 4MB L2 (linear dispatch streamed all 32 heads
// through every XCD: 70MB HBM fetch). Perf-only heuristic, any mapping is
// correct. LDS 32 KB (Ks 16K + VTs 16K). 256 thr, wave w -> 16 q rows.
__global__ __launch_bounds__(256, 4) void flash_kernel(
    const unsigned short* __restrict__ Q, const unsigned short* __restrict__ Kg,
    const unsigned short* __restrict__ VT, const unsigned short* __restrict__ MB,
    unsigned short* __restrict__ ctx) {
  __shared__ __align__(16) unsigned short Ks[128 * 64];    // [key][d], swizzled
  __shared__ __align__(16) unsigned short VTs[64 * 128];   // [d][key'], swizzled

  const int tid = threadIdx.x, w = tid >> 6, l = tid & 63;
  const int lq = l >> 4, lr = l & 15;
  const int lin = blockIdx.x;
  const int xcd = lin & 7, slot = lin >> 3;
  const int bh = xcd * 4 + (slot >> 5);    // 4 heads per XCD
  const int b = bh >> 4, h = bh & 15;
  const int q0 = (slot & 31) * 64;

  const unsigned short* Qp = Q + (size_t)(b * 2048 + q0) * 1024 + h * 64;
  const unsigned short* Kp = Kg + (size_t)(b * 2048) * 1024 + h * 64;
  const unsigned short* VTp = VT + (size_t)bh * 64 * 2048;
  const unsigned short* mbp = MB + b * 2048;

  {  // stage Q [64][64] once through Ks head (plain layout, consumed to regs)
    const int rq = l >> 3, cs = l & 7;
#pragma unroll
    for (int i = 0; i < 2; ++i) {
      const int c = w * 2 + i;
      load_lds_128(Qp + (size_t)(c * 8 + rq) * 1024 + cs * 8, (char*)Ks + c * 1024);
    }
  }
  __syncthreads();
  short8 qf[2];  // B-operand: lane holds Q[q0+w*16+lr][d = lq*8 + 0..7 (+32)]
  qf[0] = *(const short8*)((const char*)Ks + (w * 16 + lr) * 128 + lq * 16);
  qf[1] = *(const short8*)((const char*)Ks + (w * 16 + lr) * 128 + 64 + lq * 16);

  const floatx4 fz = {0.f, 0.f, 0.f, 0.f};
  floatx4 o[4] = {fz, fz, fz, fz};
  floatx4 l_acc = fz;

  const int krow = l >> 3, kslot = l & 7;   // Ks staging: 8 rows / 1KB chunk
  const int vrow = l >> 4, vslot = l & 15;  // VTs staging: 4 rows / 1KB chunk

  for (int kb = 0; kb < 2048; kb += 128) {
    __syncthreads();
#pragma unroll
    for (int i = 0; i < 4; ++i) {
      const int c4 = w * 4 + i;
      {  // Ks rows c4*8..+7; slot kslot holds logical chunk kslot^(row&7)
        const int row = c4 * 8 + krow;
        const int cc = kslot ^ (row & 7);
        load_lds_128(Kp + (size_t)(kb + row) * 1024 + cc * 8, (char*)Ks + c4 * 1024);
      }
      {  // VTs rows c4*4..+3; slot vslot holds logical chunk vslot^(row&15)
        const int row = c4 * 4 + vrow;
        const int cc = vslot ^ (row & 15);
        load_lds_128(VTp + (size_t)row * 2048 + kb + cc * 8, (char*)VTs + c4 * 1024);
      }
    }
    // mask fragments for the 4 PV windows (already in phi key order)
    short8 mf[4];
#pragma unroll
    for (int t = 0; t < 4; ++t) {
      const short4v ma = *(const short4v*)(mbp + kb + t * 32 + lq * 4);
      const short4v mb2 = *(const short4v*)(mbp + kb + t * 32 + 16 + lq * 4);
      mf[t] = short8{ma[0], ma[1], ma[2], ma[3], mb2[0], mb2[1], mb2[2], mb2[3]};
    }
    __syncthreads();

    // two halves of 64 keys each: 4 score-groups -> 2 PV windows
#pragma unroll
    for (int h2 = 0; h2 < 2; ++h2) {
      // S^T: D[m=key][n=q]; lane gets q=lr(col), key=g*16+lq*4+r(row)
      floatx4 s[4];
#pragma unroll
      for (int gg = 0; gg < 4; ++gg) {
        const int g = h2 * 4 + gg;
        const char* rowp = (const char*)Ks + (g * 16 + lr) * 128;
        short8 k0 = *(const short8*)(rowp + ((lq) ^ (lr & 7)) * 16);
        short8 k1 = *(const short8*)(rowp + ((4 + lq) ^ (lr & 7)) * 16);
        floatx4 t = MFMA16(k0, qf[0], fz);
        s[gg] = MFMA16(k1, qf[1], t);
      }
      // p = exp2(score), hw-packed to bf16 A-fragments (phi key order)
      short8 pf[2];
#pragma unroll
      for (int tt = 0; tt < 2; ++tt) {
        const floatx4 sL = s[tt * 2], sH = s[tt * 2 + 1];
        union { uint32_t u[4]; short8 s8; } pk;
        pk.u[0] = pkbf(EXP2(sL[0]), EXP2(sL[1]));
        pk.u[1] = pkbf(EXP2(sL[2]), EXP2(sL[3]));
        pk.u[2] = pkbf(EXP2(sH[0]), EXP2(sH[1]));
        pk.u[3] = pkbf(EXP2(sH[2]), EXP2(sH[3]));
        pf[tt] = pk.s8;
      }
      // PV: windows t = h2*2 + tt over 32 keys each; V fragment = one b128
#pragma unroll
      for (int tt = 0; tt < 2; ++tt) {
        const int t = h2 * 2 + tt;
        l_acc = MFMA16(pf[tt], mf[t], l_acc);
#pragma unroll
        for (int nt = 0; nt < 4; ++nt) {
          const int d = nt * 16 + lr;
          short8 vf = *(const short8*)((const char*)VTs + d * 256 +
                                       (((t * 4 + lq) ^ (d & 15)) * 16));
          o[nt] = MFMA16(pf[tt], vf, o[nt]);
        }
      }
    }
  }

  // epilogue: o C-layout: q = q0 + w*16 + lq*4 + r, d = nt*16 + lr
#pragma unroll
  for (int r = 0; r < 4; ++r) {
    const float inv = 1.0f / l_acc[r];
    const int q = q0 + w * 16 + lq * 4 + r;
#pragma unroll
    for (int nt = 0; nt < 4; ++nt)
      ctx[(size_t)(b * 2048 + q) * 1024 + h * 64 + nt * 16 + lr] = f2bf(o[nt][r] * inv);
  }
}

// ---------------------------------------------------------------------------
// fused residual + dual bf16-partial sum + bias + LayerNorm over rows of 1024.
// v = res + y0 + y1 + bias; out = LN(v)*gamma + beta.
template <int RESBF, int OUTBF>
__global__ __launch_bounds__(256) void ln2_kernel(
    const void* __restrict__ res, const unsigned short* __restrict__ y0,
    const unsigned short* __restrict__ y1, const float* __restrict__ bias,
    const float* __restrict__ gamma, const float* __restrict__ beta,
    void* __restrict__ outp) {
  const int row = blockIdx.x, t = threadIdx.x;
  const size_t base = (size_t)row * 1024 + t * 4;
  float v[4];
  if (RESBF) {
    ushort4v r4 = *(const ushort4v*)((const unsigned short*)res + base);
#pragma unroll
    for (int j = 0; j < 4; ++j) v[j] = bf2f(r4[j]);
  } else {
    floatx4 r4 = *(const floatx4*)((const float*)res + base);
#pragma unroll
    for (int j = 0; j < 4; ++j) v[j] = r4[j];
  }
  const ushort4v a4 = *(const ushort4v*)(y0 + base);
  const ushort4v b4v = *(const ushort4v*)(y1 + base);
  const floatx4 bi4 = *(const floatx4*)(bias + t * 4);
  float s = 0.f, ss = 0.f;
#pragma unroll
  for (int j = 0; j < 4; ++j) {
    v[j] += bf2f(a4[j]) + bf2f(b4v[j]) + bi4[j];
    s += v[j];
    ss += v[j] * v[j];
  }
#pragma unroll
  for (int off = 1; off < 64; off <<= 1) {
    s += __shfl_xor(s, off);
    ss += __shfl_xor(ss, off);
  }
  __shared__ float red[8];
  const int w = t >> 6;
  if ((t & 63) == 0) { red[w] = s; red[4 + w] = ss; }
  __syncthreads();
  s = red[0] + red[1] + red[2] + red[3];
  ss = red[4] + red[5] + red[6] + red[7];
  const float mean = s * (1.0f / 1024.0f);
  const float var = ss * (1.0f / 1024.0f) - mean * mean;
  const float rstd = rsqrtf(var + 1e-6f);
  const floatx4 g4 = *(const floatx4*)(gamma + t * 4);
  const floatx4 be4 = *(const floatx4*)(beta + t * 4);
  if (OUTBF) {
    union { uint32_t u[2]; ushort4v v4; } o;
    o.u[0] = pkbf((v[0] - mean) * rstd * g4[0] + be4[0],
                  (v[1] - mean) * rstd * g4[1] + be4[1]);
    o.u[1] = pkbf((v[2] - mean) * rstd * g4[2] + be4[2],
                  (v[3] - mean) * rstd * g4[3] + be4[3]);
    *(ushort4v*)((unsigned short*)outp + base) = o.v4;
  } else {
    floatx4 o;
#pragma unroll
    for (int j = 0; j < 4; ++j) o[j] = (v[j] - mean) * rstd * g4[j] + be4[j];
    *(floatx4*)((float*)outp + base) = o;
  }
}

// ---------------------------------------------------------------------------
extern "C" void kernel_launch(void* const* d_in, const int* in_sizes, int n_in,
                              void* d_out, int out_size, void* d_ws, size_t ws_size,
                              hipStream_t stream) {
  (void)in_sizes; (void)n_in; (void)out_size; (void)ws_size;
  const float* x    = (const float*)d_in[0];
  const int*   mask = (const int*)d_in[1];
  const float* wq   = (const float*)d_in[2];
  const float* wk   = (const float*)d_in[3];
  const float* wv   = (const float*)d_in[4];
  const float* wo   = (const float*)d_in[5];
  const float* wo_b = (const float*)d_in[6];
  const float* w1   = (const float*)d_in[7];
  const float* b1   = (const float*)d_in[8];
  const float* w2   = (const float*)d_in[9];
  const float* b2   = (const float*)d_in[10];
  const float* g1   = (const float*)d_in[11];
  const float* be1  = (const float*)d_in[12];
  const float* g2   = (const float*)d_in[13];
  const float* be2  = (const float*)d_in[14];
  float* out = (float*)d_out;

  char* ws = (char*)d_ws;
  const size_t MBy = 1024ull * 1024ull;
  // phase-aliased workspace (80 MB):
  unsigned short* WQKV = (unsigned short*)(ws + 0 * MBy);   // 6MB  (dead after QKV gemm)
  unsigned short* WOT  = (unsigned short*)(ws + 6 * MBy);   // 2MB  (dead after WO gemm)
  unsigned short* W1T  = (unsigned short*)(ws + 8 * MBy);   // 8MB  (dead after FF1)
  unsigned short* W2T  = (unsigned short*)(ws + 16 * MBy);  // 8MB  (dead after FF2)
  unsigned short* XB   = (unsigned short*)(ws + 24 * MBy);  // 8MB  (dead after QKV)
  unsigned short* Qb   = (unsigned short*)(ws + 32 * MBy);  // 8MB  (dead after flash)
  unsigned short* Kb   = (unsigned short*)(ws + 40 * MBy);  // 8MB  (dead after flash)
  unsigned short* VTb  = (unsigned short*)(ws + 48 * MBy);  // 8MB  (dead after flash)
  unsigned short* CTX  = (unsigned short*)(ws + 56 * MBy);  // 8MB  (dead after WO gemm)
  unsigned short* ATT0 = (unsigned short*)(ws + 32 * MBy);  // 8MB bf16, over Qb
  unsigned short* ATT1 = (unsigned short*)(ws + 40 * MBy);  // 8MB bf16, over Kb
  unsigned short* Hb   = (unsigned short*)(ws + 24 * MBy);  // 8MB  over XB
  unsigned short* G1   = (unsigned short*)(ws + 32 * MBy);  // 32MB over ATT0/ATT1/VTb/CTX
  unsigned short* FF20 = (unsigned short*)(ws + 64 * MBy);  // 8MB bf16
  unsigned short* FF21 = (unsigned short*)(ws + 72 * MBy);  // 8MB bf16
  unsigned short* MB   = (unsigned short*)(ws + 78 * MBy);  // 8KB bf16 mask (inside FF21
                                                            // region; FF21 written after flash)

  // 1. prep: cast x + all 6 weight transposes + bf16 mask in one launch
  prep_kernel<<<16385, 256, 0, stream>>>(x, XB, wq, wk, wv, wo, WQKV, WOT,
                                         w1, W1T, w2, W2T, mask, MB);
  // 2. fused QKV projection: N=3072 -> 768 blocks; Q pre-scaled, V masked+permuted
  gemm_bt_kernel<5, 1><<<dim3(24, 32), 256, 0, stream>>>(
      XB, WQKV, nullptr, Qb, Kb, VTb, 4096, 3072, 1024, mask);
  // 3. attention (1D grid, XCD head-grouped)
  flash_kernel<<<1024, 256, 0, stream>>>(Qb, Kb, VTb, MB, CTX);
  // 4. output projection, split-K=2 bf16 partials (bias folded into LN1)
  gemm_bt_kernel<4, 2><<<dim3(8, 32, 2), 256, 0, stream>>>(
      CTX, WOT, nullptr, ATT0, ATT1, nullptr, 4096, 1024, 1024, nullptr);
  // 5. LN1: h = LN(x + att0 + att1 + wo_b) -> bf16
  ln2_kernel<0, 1><<<4096, 256, 0, stream>>>(x, ATT0, ATT1, wo_b, g1, be1, Hb);
  // 6. FF1 + bias + fast GELU -> bf16
  gemm_bt_kernel<2, 1><<<dim3(32, 32), 256, 0, stream>>>(
      Hb, W1T, b1, G1, nullptr, nullptr, 4096, 4096, 1024, nullptr);
  // 7. FF2, split-K=2 bf16 partials (bias folded into LN2)
  gemm_bt_kernel<4, 2><<<dim3(8, 32, 2), 256, 0, stream>>>(
      G1, W2T, nullptr, FF20, FF21, nullptr, 4096, 1024, 4096, nullptr);
  // 8. LN2: out = LN(h + ff0 + ff1 + b2) -> fp32
  ln2_kernel<1, 0><<<4096, 256, 0, stream>>>(Hb, FF20, FF21, b2, g2, be2, out);
}

// Round 11
// 341.091 us; speedup vs baseline: 1.0902x; 1.0461x over previous
//
#include <hip/hip_runtime.h>
#include <cstdint>

#define DEVINL __device__ __forceinline__

typedef __attribute__((ext_vector_type(8))) short short8;       // 8 x bf16 (4 VGPRs)
typedef __attribute__((ext_vector_type(4))) short short4v;      // 4 x bf16 (2 VGPRs)
typedef __attribute__((ext_vector_type(4))) float floatx4;
typedef __attribute__((ext_vector_type(4))) unsigned short ushort4v;

// hardware packed cvt: D = {bf16(a), bf16(b)} (RNE) — use ONLY for true pair
// packs (scalar use regressed R7: asm blocks CSE, +20 VGPR in GEMM epilogue).
DEVINL uint32_t pkbf(float a, float b) {
  uint32_t d;
  asm("v_cvt_pk_bf16_f32 %0, %1, %2" : "=v"(d) : "v"(a), "v"(b));
  return d;
}
// software RNE fp32->bf16 for scalar stores (compiler-schedulable)
DEVINL unsigned short f2bf(float f) {
  union { float f; uint32_t u; } v; v.f = f;
  return (unsigned short)((v.u + 0x7fffu + ((v.u >> 16) & 1u)) >> 16);
}
DEVINL float bf2f(unsigned short h) {
  union { uint32_t u; float f; } v; v.u = ((uint32_t)h) << 16;
  return v.f;
}

#if defined(__has_builtin) && __has_builtin(__builtin_amdgcn_exp2f)
#define EXP2(x) __builtin_amdgcn_exp2f(x)
#else
#define EXP2(x) exp2f(x)
#endif

// fast GELU (tanh form, exp2-based): max |err| ~3e-4 vs exact erf GELU.
DEVINL float fast_gelu(float v) {
  const float z = -2.30220795f * v * (1.0f + 0.044715f * v * v);
  return v * __builtin_amdgcn_rcpf(1.0f + EXP2(z));
}

typedef __attribute__((address_space(3))) unsigned char* lds_ptr_t;
typedef const __attribute__((address_space(1))) unsigned char* gbl_ptr_t;
// async global->LDS, 16B per lane; LDS dest = wave-uniform base + lane*16
DEVINL void load_lds_128(const void* g, void* l) {
  __builtin_amdgcn_global_load_lds((gbl_ptr_t)g, (lds_ptr_t)l, 16, 0, 0);
}

#define MFMA16(a, b, c) __builtin_amdgcn_mfma_f32_16x16x32_bf16((a), (b), (c), 0, 0, 0)

// 0.125 (1/sqrt(Dk)) * log2(e): folds attention scale AND base-2 softmax into Q
#define QSCALE2 0.18033688011112042f

// ---------------------------------------------------------------------------
// prep: blocks 0..4095 cast x->bf16; 4096..8191 four 1024^2 transposes;
// 8192..12287 w1; 12288..16383 w2; 16384 converts mask(int)->bf16 0/1.
__global__ __launch_bounds__(256) void prep_kernel(
    const float* __restrict__ x, unsigned short* __restrict__ XB,
    const float* __restrict__ wq, const float* __restrict__ wk,
    const float* __restrict__ wv, const float* __restrict__ wo,
    unsigned short* __restrict__ WQKV, unsigned short* __restrict__ WOT,
    const float* __restrict__ w1, unsigned short* __restrict__ W1T,
    const float* __restrict__ w2, unsigned short* __restrict__ W2T,
    const int* __restrict__ mask, unsigned short* __restrict__ MB) {
  const int bid = blockIdx.x;
  if (bid >= 16384) {  // mask -> bf16 0/1
    const int i0 = threadIdx.x * 16;
#pragma unroll
    for (int j = 0; j < 16; ++j) MB[i0 + j] = mask[i0 + j] ? 0x3F80 : 0;
    return;
  }
  if (bid < 4096) {  // cast x (pair-packed hw cvt)
    const int i = (bid * 256 + threadIdx.x) * 4;
    floatx4 v = *(const floatx4*)(x + i);
    union { uint32_t u[2]; ushort4v v4; } o;
    o.u[0] = pkbf(v[0], v[1]);
    o.u[1] = pkbf(v[2], v[3]);
    *(ushort4v*)(XB + i) = o.v4;
    return;
  }
  const float* in;
  unsigned short* out;
  int K, N, bx, by;
  if (bid < 8192) {
    const int b2 = bid - 4096, z = b2 >> 10;
    in = (z == 0) ? wq : (z == 1) ? wk : (z == 2) ? wv : wo;
    out = (z == 3) ? WOT : WQKV + (size_t)z * 1024 * 1024;
    K = 1024; N = 1024; bx = b2 & 31; by = (b2 >> 5) & 31;
  } else if (bid < 12288) {
    const int b3 = bid - 8192;
    in = w1; out = W1T; K = 1024; N = 4096; bx = b3 & 127; by = b3 >> 7;
  } else {
    const int b4 = bid - 12288;
    in = w2; out = W2T; K = 4096; N = 1024; bx = b4 & 31; by = b4 >> 5;
  }
  __shared__ float tile[32][33];
  const int n0 = bx * 32, k0 = by * 32;
  const int tx = threadIdx.x & 31, ty = threadIdx.x >> 5;  // 32 x 8
#pragma unroll
  for (int i = 0; i < 4; ++i)
    tile[ty + 8 * i][tx] = in[(size_t)(k0 + ty + 8 * i) * N + n0 + tx];
  __syncthreads();
#pragma unroll
  for (int i = 0; i < 4; ++i)
    out[(size_t)(n0 + ty + 8 * i) * K + k0 + tx] = f2bf(tile[tx][ty + 8 * i]);
}

// ---------------------------------------------------------------------------
// GEMM: C = A[M,K] @ BT[N,K]^T (bf16 in, fp32 acc), BM=BN=128, BK=64, 256 thr.
// 16x16x32 MFMA, 4x4 acc/wave (R9-verified best: FF1 57.2us, 4.2e6 LDS
// conflicts; the 32x32 variant with 64B rows was LDS-serialized — R10).
// LDS A/B each stored as TWO stacked 32-K panels of 64-B rows.
// Natural block mapping (R8's XCD strip-swizzle destroyed A-panel L2 reuse).
// SK: split-K factor (blockIdx.z = slice; slice 0 -> C0, slice 1 -> C1).
// EPI: 2 = bias + fast GELU -> bf16
//      4 = bf16 partial store (split-K; bias added downstream in LN)
//      5 = fused QKV epilogue: region 0 -> Q*QSCALE2 (C0); 1 -> K (C1);
//          2 -> V * mask, per-head-transposed [bh][64][2048] with keys
//          permuted within 32-groups (flash phi order) (C2)
template <int EPI, int SK>
__global__ __launch_bounds__(256) void gemm_bt_kernel(
    const unsigned short* __restrict__ A, const unsigned short* __restrict__ BT,
    const float* __restrict__ bias, void* __restrict__ C0, void* __restrict__ C1,
    void* __restrict__ C2, int M, int N, int K, const int* __restrict__ msk) {
  __shared__ __align__(16) unsigned short As[128 * 64];   // 2 panels x 8KB
  __shared__ __align__(16) unsigned short Bs[128 * 64];
  const int tid = threadIdx.x;
  const int w = tid >> 6, l = tid & 63;
  const int lq = l >> 4, lr = l & 15;
  const int m0 = blockIdx.y * 128, n0 = blockIdx.x * 128;
  const int wm = (w >> 1) * 64, wn = (w & 1) * 64;
  const int r_a = l >> 2;            // row within 16-row chunk
  const int colb = (l & 3) * 8;      // col (8 bf16 = 16B)
  const int kslice = K / SK;
  const int kbeg = kslice * blockIdx.z;
  const int region = (EPI == 5) ? (n0 >> 10) : 0;  // block-uniform

  // V-row mask, 16 packed bits (loads overlap the K-loop staging)
  uint32_t mbits = 0xFFFFu;
  if (EPI == 5 && region == 2) {
    mbits = 0;
#pragma unroll
    for (int mt = 0; mt < 4; ++mt) {
      const int4 m4 = *(const int4*)(msk + m0 + wm + mt * 16 + lq * 4);
      mbits |= (m4.x ? 1u : 0u) << (mt * 4);
      mbits |= (m4.y ? 1u : 0u) << (mt * 4 + 1);
      mbits |= (m4.z ? 1u : 0u) << (mt * 4 + 2);
      mbits |= (m4.w ? 1u : 0u) << (mt * 4 + 3);
    }
  }

  floatx4 acc[4][4];
  const floatx4 fz = {0.f, 0.f, 0.f, 0.f};
#pragma unroll
  for (int mt = 0; mt < 4; ++mt)
#pragma unroll
    for (int nt = 0; nt < 4; ++nt) acc[mt][nt] = fz;

  for (int k0 = kbeg; k0 < kbeg + kslice; k0 += 64) {
    __syncthreads();
#pragma unroll
    for (int p = 0; p < 2; ++p) {
#pragma unroll
      for (int i = 0; i < 2; ++i) {
        const int c = w * 2 + i;
        load_lds_128(A + (size_t)(m0 + c * 16 + r_a) * K + k0 + p * 32 + colb,
                     (char*)As + p * 8192 + c * 1024);
        load_lds_128(BT + (size_t)(n0 + c * 16 + r_a) * K + k0 + p * 32 + colb,
                     (char*)Bs + p * 8192 + c * 1024);
      }
    }
    __syncthreads();
#pragma unroll
    for (int p = 0; p < 2; ++p) {
      short8 af[4], bf[4];
#pragma unroll
      for (int mt = 0; mt < 4; ++mt)
        af[mt] = *(const short8*)((const char*)As + p * 8192 + (wm + mt * 16 + lr) * 64 + lq * 16);
#pragma unroll
      for (int nt = 0; nt < 4; ++nt)
        bf[nt] = *(const short8*)((const char*)Bs + p * 8192 + (wn + nt * 16 + lr) * 64 + lq * 16);
#pragma unroll
      for (int mt = 0; mt < 4; ++mt)
#pragma unroll
        for (int nt = 0; nt < 4; ++nt)
          acc[mt][nt] = MFMA16(af[mt], bf[nt], acc[mt][nt]);
    }
  }

  void* Cp = (SK > 1 && blockIdx.z) ? C1 : C0;
  // epilogue: C row = quad*4+reg, col = lane&15
#pragma unroll
  for (int mt = 0; mt < 4; ++mt) {
#pragma unroll
    for (int nt = 0; nt < 4; ++nt) {
      const int n = n0 + wn + nt * 16 + lr;
      float bval = 0.f;
      if (EPI == 2) bval = bias[n];
#pragma unroll
      for (int r = 0; r < 4; ++r) {
        const int m = m0 + wm + mt * 16 + lq * 4 + r;
        float v = acc[mt][nt][r];
        if (EPI == 4) {
          ((unsigned short*)Cp)[(size_t)m * N + n] = f2bf(v);
        } else if (EPI == 2) {
          ((unsigned short*)C0)[(size_t)m * N + n] = f2bf(fast_gelu(v + bval));
        } else {  // EPI == 5
          if (region == 0) {
            ((unsigned short*)C0)[(size_t)m * 1024 + n] = f2bf(v * QSCALE2);
          } else if (region == 1) {
            ((unsigned short*)C1)[(size_t)m * 1024 + (n - 1024)] = f2bf(v);
          } else {
            const int nn = n - 2048;
            const int bidx = m >> 11, s = m & 2047;
            // key permutation within 32-group: p = (u&3)|(bit4<<2)|((u>>2&3)<<3)
            const int u = s & 31;
            const int sp = (s & ~31) | (u & 3) | (((u >> 4) & 1) << 2) | (((u >> 2) & 3) << 3);
            const int hh = nn >> 6, d = nn & 63;
            const float vv = ((mbits >> (mt * 4 + r)) & 1u) ? v : 0.f;
            ((unsigned short*)C2)[((size_t)((bidx * 16 + hh) * 64 + d)) * 2048 + sp] = f2bf(vv);
          }
        }
      }
    }
  }
}

// ---------------------------------------------------------------------------
// Flash attention: S=2048, Dk=64. Q PRE-SCALED by 0.125*log2e (exp2 domain).
// FIXED-SHIFT softmax (p = exp2(score)) + TRANSPOSED-SCORE register pipeline
// (S^T = K·Q^T -> C/D fragment is directly a PV A-operand under phi; V
// stored pre-permuted so V B-fragment is one ds_read_b128).
// XCD HEAD-GROUPING (R10-verified): 1D grid, xcd = lin&7 owns 4 whole (b,h)
// heads -> per-XCD K/V footprint 2MB fits the 4MB L2. Perf-only heuristic.
// LDS 32 KB (Ks 16K + VTs 16K). 256 thr, wave w -> 16 q rows.
__global__ __launch_bounds__(256, 4) void flash_kernel(
    const unsigned short* __restrict__ Q, const unsigned short* __restrict__ Kg,
    const unsigned short* __restrict__ VT, const unsigned short* __restrict__ MB,
    unsigned short* __restrict__ ctx) {
  __shared__ __align__(16) unsigned short Ks[128 * 64];    // [key][d], swizzled
  __shared__ __align__(16) unsigned short VTs[64 * 128];   // [d][key'], swizzled

  const int tid = threadIdx.x, w = tid >> 6, l = tid & 63;
  const int lq = l >> 4, lr = l & 15;
  const int lin = blockIdx.x;
  const int xcd = lin & 7, slot = lin >> 3;
  const int bh = xcd * 4 + (slot >> 5);    // 4 heads per XCD
  const int b = bh >> 4, h = bh & 15;
  const int q0 = (slot & 31) * 64;

  const unsigned short* Qp = Q + (size_t)(b * 2048 + q0) * 1024 + h * 64;
  const unsigned short* Kp = Kg + (size_t)(b * 2048) * 1024 + h * 64;
  const unsigned short* VTp = VT + (size_t)bh * 64 * 2048;
  const unsigned short* mbp = MB + b * 2048;

  {  // stage Q [64][64] once through Ks head (plain layout, consumed to regs)
    const int rq = l >> 3, cs = l & 7;
#pragma unroll
    for (int i = 0; i < 2; ++i) {
      const int c = w * 2 + i;
      load_lds_128(Qp + (size_t)(c * 8 + rq) * 1024 + cs * 8, (char*)Ks + c * 1024);
    }
  }
  __syncthreads();
  short8 qf[2];  // B-operand: lane holds Q[q0+w*16+lr][d = lq*8 + 0..7 (+32)]
  qf[0] = *(const short8*)((const char*)Ks + (w * 16 + lr) * 128 + lq * 16);
  qf[1] = *(const short8*)((const char*)Ks + (w * 16 + lr) * 128 + 64 + lq * 16);

  const floatx4 fz = {0.f, 0.f, 0.f, 0.f};
  floatx4 o[4] = {fz, fz, fz, fz};
  floatx4 l_acc = fz;

  const int krow = l >> 3, kslot = l & 7;   // Ks staging: 8 rows / 1KB chunk
  const int vrow = l >> 4, vslot = l & 15;  // VTs staging: 4 rows / 1KB chunk

  for (int kb = 0; kb < 2048; kb += 128) {
    __syncthreads();
#pragma unroll
    for (int i = 0; i < 4; ++i) {
      const int c4 = w * 4 + i;
      {  // Ks rows c4*8..+7; slot kslot holds logical chunk kslot^(row&7)
        const int row = c4 * 8 + krow;
        const int cc = kslot ^ (row & 7);
        load_lds_128(Kp + (size_t)(kb + row) * 1024 + cc * 8, (char*)Ks + c4 * 1024);
      }
      {  // VTs rows c4*4..+3; slot vslot holds logical chunk vslot^(row&15)
        const int row = c4 * 4 + vrow;
        const int cc = vslot ^ (row & 15);
        load_lds_128(VTp + (size_t)row * 2048 + kb + cc * 8, (char*)VTs + c4 * 1024);
      }
    }
    // mask fragments for the 4 PV windows (already in phi key order)
    short8 mf[4];
#pragma unroll
    for (int t = 0; t < 4; ++t) {
      const short4v ma = *(const short4v*)(mbp + kb + t * 32 + lq * 4);
      const short4v mb2 = *(const short4v*)(mbp + kb + t * 32 + 16 + lq * 4);
      mf[t] = short8{ma[0], ma[1], ma[2], ma[3], mb2[0], mb2[1], mb2[2], mb2[3]};
    }
    __syncthreads();

    // two halves of 64 keys each: 4 score-groups -> 2 PV windows
#pragma unroll
    for (int h2 = 0; h2 < 2; ++h2) {
      // S^T: D[m=key][n=q]; lane gets q=lr(col), key=g*16+lq*4+r(row)
      floatx4 s[4];
#pragma unroll
      for (int gg = 0; gg < 4; ++gg) {
        const int g = h2 * 4 + gg;
        const char* rowp = (const char*)Ks + (g * 16 + lr) * 128;
        short8 k0 = *(const short8*)(rowp + ((lq) ^ (lr & 7)) * 16);
        short8 k1 = *(const short8*)(rowp + ((4 + lq) ^ (lr & 7)) * 16);
        floatx4 t = MFMA16(k0, qf[0], fz);
        s[gg] = MFMA16(k1, qf[1], t);
      }
      // p = exp2(score), hw-packed to bf16 A-fragments (phi key order)
      short8 pf[2];
#pragma unroll
      for (int tt = 0; tt < 2; ++tt) {
        const floatx4 sL = s[tt * 2], sH = s[tt * 2 + 1];
        union { uint32_t u[4]; short8 s8; } pk;
        pk.u[0] = pkbf(EXP2(sL[0]), EXP2(sL[1]));
        pk.u[1] = pkbf(EXP2(sL[2]), EXP2(sL[3]));
        pk.u[2] = pkbf(EXP2(sH[0]), EXP2(sH[1]));
        pk.u[3] = pkbf(EXP2(sH[2]), EXP2(sH[3]));
        pf[tt] = pk.s8;
      }
      // PV: windows t = h2*2 + tt over 32 keys each; V fragment = one b128
#pragma unroll
      for (int tt = 0; tt < 2; ++tt) {
        const int t = h2 * 2 + tt;
        l_acc = MFMA16(pf[tt], mf[t], l_acc);
#pragma unroll
        for (int nt = 0; nt < 4; ++nt) {
          const int d = nt * 16 + lr;
          short8 vf = *(const short8*)((const char*)VTs + d * 256 +
                                       (((t * 4 + lq) ^ (d & 15)) * 16));
          o[nt] = MFMA16(pf[tt], vf, o[nt]);
        }
      }
    }
  }

  // epilogue: o C-layout: q = q0 + w*16 + lq*4 + r, d = nt*16 + lr
#pragma unroll
  for (int r = 0; r < 4; ++r) {
    const float inv = 1.0f / l_acc[r];
    const int q = q0 + w * 16 + lq * 4 + r;
#pragma unroll
    for (int nt = 0; nt < 4; ++nt)
      ctx[(size_t)(b * 2048 + q) * 1024 + h * 64 + nt * 16 + lr] = f2bf(o[nt][r] * inv);
  }
}

// ---------------------------------------------------------------------------
// fused residual + dual bf16-partial sum + bias + LayerNorm over rows of 1024.
// v = res + y0 + y1 + bias; out = LN(v)*gamma + beta.
template <int RESBF, int OUTBF>
__global__ __launch_bounds__(256) void ln2_kernel(
    const void* __restrict__ res, const unsigned short* __restrict__ y0,
    const unsigned short* __restrict__ y1, const float* __restrict__ bias,
    const float* __restrict__ gamma, const float* __restrict__ beta,
    void* __restrict__ outp) {
  const int row = blockIdx.x, t = threadIdx.x;
  const size_t base = (size_t)row * 1024 + t * 4;
  float v[4];
  if (RESBF) {
    ushort4v r4 = *(const ushort4v*)((const unsigned short*)res + base);
#pragma unroll
    for (int j = 0; j < 4; ++j) v[j] = bf2f(r4[j]);
  } else {
    floatx4 r4 = *(const floatx4*)((const float*)res + base);
#pragma unroll
    for (int j = 0; j < 4; ++j) v[j] = r4[j];
  }
  const ushort4v a4 = *(const ushort4v*)(y0 + base);
  const ushort4v b4v = *(const ushort4v*)(y1 + base);
  const floatx4 bi4 = *(const floatx4*)(bias + t * 4);
  float s = 0.f, ss = 0.f;
#pragma unroll
  for (int j = 0; j < 4; ++j) {
    v[j] += bf2f(a4[j]) + bf2f(b4v[j]) + bi4[j];
    s += v[j];
    ss += v[j] * v[j];
  }
#pragma unroll
  for (int off = 1; off < 64; off <<= 1) {
    s += __shfl_xor(s, off);
    ss += __shfl_xor(ss, off);
  }
  __shared__ float red[8];
  const int w = t >> 6;
  if ((t & 63) == 0) { red[w] = s; red[4 + w] = ss; }
  __syncthreads();
  s = red[0] + red[1] + red[2] + red[3];
  ss = red[4] + red[5] + red[6] + red[7];
  const float mean = s * (1.0f / 1024.0f);
  const float var = ss * (1.0f / 1024.0f) - mean * mean;
  const float rstd = rsqrtf(var + 1e-6f);
  const floatx4 g4 = *(const floatx4*)(gamma + t * 4);
  const floatx4 be4 = *(const floatx4*)(beta + t * 4);
  if (OUTBF) {
    union { uint32_t u[2]; ushort4v v4; } o;
    o.u[0] = pkbf((v[0] - mean) * rstd * g4[0] + be4[0],
                  (v[1] - mean) * rstd * g4[1] + be4[1]);
    o.u[1] = pkbf((v[2] - mean) * rstd * g4[2] + be4[2],
                  (v[3] - mean) * rstd * g4[3] + be4[3]);
    *(ushort4v*)((unsigned short*)outp + base) = o.v4;
  } else {
    floatx4 o;
#pragma unroll
    for (int j = 0; j < 4; ++j) o[j] = (v[j] - mean) * rstd * g4[j] + be4[j];
    *(floatx4*)((float*)outp + base) = o;
  }
}

// ---------------------------------------------------------------------------
extern "C" void kernel_launch(void* const* d_in, const int* in_sizes, int n_in,
                              void* d_out, int out_size, void* d_ws, size_t ws_size,
                              hipStream_t stream) {
  (void)in_sizes; (void)n_in; (void)out_size; (void)ws_size;
  const float* x    = (const float*)d_in[0];
  const int*   mask = (const int*)d_in[1];
  const float* wq   = (const float*)d_in[2];
  const float* wk   = (const float*)d_in[3];
  const float* wv   = (const float*)d_in[4];
  const float* wo   = (const float*)d_in[5];
  const float* wo_b = (const float*)d_in[6];
  const float* w1   = (const float*)d_in[7];
  const float* b1   = (const float*)d_in[8];
  const float* w2   = (const float*)d_in[9];
  const float* b2   = (const float*)d_in[10];
  const float* g1   = (const float*)d_in[11];
  const float* be1  = (const float*)d_in[12];
  const float* g2   = (const float*)d_in[13];
  const float* be2  = (const float*)d_in[14];
  float* out = (float*)d_out;

  char* ws = (char*)d_ws;
  const size_t MBy = 1024ull * 1024ull;
  // phase-aliased workspace (80 MB):
  unsigned short* WQKV = (unsigned short*)(ws + 0 * MBy);   // 6MB  (dead after QKV gemm)
  unsigned short* WOT  = (unsigned short*)(ws + 6 * MBy);   // 2MB  (dead after WO gemm)
  unsigned short* W1T  = (unsigned short*)(ws + 8 * MBy);   // 8MB  (dead after FF1)
  unsigned short* W2T  = (unsigned short*)(ws + 16 * MBy);  // 8MB  (dead after FF2)
  unsigned short* XB   = (unsigned short*)(ws + 24 * MBy);  // 8MB  (dead after QKV)
  unsigned short* Qb   = (unsigned short*)(ws + 32 * MBy);  // 8MB  (dead after flash)
  unsigned short* Kb   = (unsigned short*)(ws + 40 * MBy);  // 8MB  (dead after flash)
  unsigned short* VTb  = (unsigned short*)(ws + 48 * MBy);  // 8MB  (dead after flash)
  unsigned short* CTX  = (unsigned short*)(ws + 56 * MBy);  // 8MB  (dead after WO gemm)
  unsigned short* ATT0 = (unsigned short*)(ws + 32 * MBy);  // 8MB bf16, over Qb
  unsigned short* ATT1 = (unsigned short*)(ws + 40 * MBy);  // 8MB bf16, over Kb
  unsigned short* Hb   = (unsigned short*)(ws + 24 * MBy);  // 8MB  over XB
  unsigned short* G1   = (unsigned short*)(ws + 32 * MBy);  // 32MB over ATT0/ATT1/VTb/CTX
  unsigned short* FF20 = (unsigned short*)(ws + 64 * MBy);  // 8MB bf16
  unsigned short* FF21 = (unsigned short*)(ws + 72 * MBy);  // 8MB bf16
  unsigned short* MB   = (unsigned short*)(ws + 78 * MBy);  // 8KB bf16 mask (inside FF21
                                                            // region; FF21 written after flash)

  // 1. prep: cast x + all 6 weight transposes + bf16 mask in one launch
  prep_kernel<<<16385, 256, 0, stream>>>(x, XB, wq, wk, wv, wo, WQKV, WOT,
                                         w1, W1T, w2, W2T, mask, MB);
  // 2. fused QKV projection: N=3072 -> 768 blocks; Q pre-scaled, V masked+permuted
  gemm_bt_kernel<5, 1><<<dim3(24, 32), 256, 0, stream>>>(
      XB, WQKV, nullptr, Qb, Kb, VTb, 4096, 3072, 1024, mask);
  // 3. attention (1D grid, XCD head-grouped)
  flash_kernel<<<1024, 256, 0, stream>>>(Qb, Kb, VTb, MB, CTX);
  // 4. output projection, split-K=2 bf16 partials (bias folded into LN1)
  gemm_bt_kernel<4, 2><<<dim3(8, 32, 2), 256, 0, stream>>>(
      CTX, WOT, nullptr, ATT0, ATT1, nullptr, 4096, 1024, 1024, nullptr);
  // 5. LN1: h = LN(x + att0 + att1 + wo_b) -> bf16
  ln2_kernel<0, 1><<<4096, 256, 0, stream>>>(x, ATT0, ATT1, wo_b, g1, be1, Hb);
  // 6. FF1 + bias + fast GELU -> bf16
  gemm_bt_kernel<2, 1><<<dim3(32, 32), 256, 0, stream>>>(
      Hb, W1T, b1, G1, nullptr, nullptr, 4096, 4096, 1024, nullptr);
  // 7. FF2, split-K=2 bf16 partials (bias folded into LN2)
  gemm_bt_kernel<4, 2><<<dim3(8, 32, 2), 256, 0, stream>>>(
      G1, W2T, nullptr, FF20, FF21, nullptr, 4096, 1024, 4096, nullptr);
  // 8. LN2: out = LN(h + ff0 + ff1 + b2) -> fp32
  ln2_kernel<1, 0><<<4096, 256, 0, stream>>>(Hb, FF20, FF21, b2, g2, be2, out);
}

// Round 12
// 329.370 us; speedup vs baseline: 1.1290x; 1.0356x over previous
//
#include <hip/hip_runtime.h>
#include <cstdint>

#define DEVINL __device__ __forceinline__

typedef __attribute__((ext_vector_type(8))) short short8;       // 8 x bf16 (4 VGPRs)
typedef __attribute__((ext_vector_type(4))) short short4v;      // 4 x bf16 (2 VGPRs)
typedef __attribute__((ext_vector_type(4))) float floatx4;
typedef __attribute__((ext_vector_type(4))) unsigned short ushort4v;

// hardware packed cvt: D = {bf16(a), bf16(b)} (RNE) — use ONLY for true pair
// packs (scalar use regressed R7: asm blocks CSE, +20 VGPR in GEMM epilogue).
DEVINL uint32_t pkbf(float a, float b) {
  uint32_t d;
  asm("v_cvt_pk_bf16_f32 %0, %1, %2" : "=v"(d) : "v"(a), "v"(b));
  return d;
}
// software RNE fp32->bf16 for scalar stores (compiler-schedulable)
DEVINL unsigned short f2bf(float f) {
  union { float f; uint32_t u; } v; v.f = f;
  return (unsigned short)((v.u + 0x7fffu + ((v.u >> 16) & 1u)) >> 16);
}
DEVINL float bf2f(unsigned short h) {
  union { uint32_t u; float f; } v; v.u = ((uint32_t)h) << 16;
  return v.f;
}

#if defined(__has_builtin) && __has_builtin(__builtin_amdgcn_exp2f)
#define EXP2(x) __builtin_amdgcn_exp2f(x)
#else
#define EXP2(x) exp2f(x)
#endif

// fast GELU (tanh form, exp2-based): max |err| ~3e-4 vs exact erf GELU.
DEVINL float fast_gelu(float v) {
  const float z = -2.30220795f * v * (1.0f + 0.044715f * v * v);
  return v * __builtin_amdgcn_rcpf(1.0f + EXP2(z));
}

typedef __attribute__((address_space(3))) unsigned char* lds_ptr_t;
typedef const __attribute__((address_space(1))) unsigned char* gbl_ptr_t;
// async global->LDS, 16B per lane; LDS dest = wave-uniform base + lane*16
DEVINL void load_lds_128(const void* g, void* l) {
  __builtin_amdgcn_global_load_lds((gbl_ptr_t)g, (lds_ptr_t)l, 16, 0, 0);
}

#define MFMA16(a, b, c) __builtin_amdgcn_mfma_f32_16x16x32_bf16((a), (b), (c), 0, 0, 0)

// 0.125 (1/sqrt(Dk)) * log2(e): folds attention scale AND base-2 softmax into Q
#define QSCALE2 0.18033688011112042f

// ---------------------------------------------------------------------------
// prep: blocks 0..4095 cast x->bf16; 4096..8191 four 1024^2 transposes;
// 8192..12287 w1; 12288..16383 w2; 16384 converts mask(int)->bf16 0/1.
__global__ __launch_bounds__(256) void prep_kernel(
    const float* __restrict__ x, unsigned short* __restrict__ XB,
    const float* __restrict__ wq, const float* __restrict__ wk,
    const float* __restrict__ wv, const float* __restrict__ wo,
    unsigned short* __restrict__ WQKV, unsigned short* __restrict__ WOT,
    const float* __restrict__ w1, unsigned short* __restrict__ W1T,
    const float* __restrict__ w2, unsigned short* __restrict__ W2T,
    const int* __restrict__ mask, unsigned short* __restrict__ MB) {
  const int bid = blockIdx.x;
  if (bid >= 16384) {  // mask -> bf16 0/1
    const int i0 = threadIdx.x * 16;
#pragma unroll
    for (int j = 0; j < 16; ++j) MB[i0 + j] = mask[i0 + j] ? 0x3F80 : 0;
    return;
  }
  if (bid < 4096) {  // cast x (pair-packed hw cvt)
    const int i = (bid * 256 + threadIdx.x) * 4;
    floatx4 v = *(const floatx4*)(x + i);
    union { uint32_t u[2]; ushort4v v4; } o;
    o.u[0] = pkbf(v[0], v[1]);
    o.u[1] = pkbf(v[2], v[3]);
    *(ushort4v*)(XB + i) = o.v4;
    return;
  }
  const float* in;
  unsigned short* out;
  int K, N, bx, by;
  if (bid < 8192) {
    const int b2 = bid - 4096, z = b2 >> 10;
    in = (z == 0) ? wq : (z == 1) ? wk : (z == 2) ? wv : wo;
    out = (z == 3) ? WOT : WQKV + (size_t)z * 1024 * 1024;
    K = 1024; N = 1024; bx = b2 & 31; by = (b2 >> 5) & 31;
  } else if (bid < 12288) {
    const int b3 = bid - 8192;
    in = w1; out = W1T; K = 1024; N = 4096; bx = b3 & 127; by = b3 >> 7;
  } else {
    const int b4 = bid - 12288;
    in = w2; out = W2T; K = 4096; N = 1024; bx = b4 & 31; by = b4 >> 5;
  }
  __shared__ float tile[32][33];
  const int n0 = bx * 32, k0 = by * 32;
  const int tx = threadIdx.x & 31, ty = threadIdx.x >> 5;  // 32 x 8
#pragma unroll
  for (int i = 0; i < 4; ++i)
    tile[ty + 8 * i][tx] = in[(size_t)(k0 + ty + 8 * i) * N + n0 + tx];
  __syncthreads();
#pragma unroll
  for (int i = 0; i < 4; ++i)
    out[(size_t)(n0 + ty + 8 * i) * K + k0 + tx] = f2bf(tile[tx][ty + 8 * i]);
}

// ---------------------------------------------------------------------------
// GEMM: C = A[M,K] @ BT[N,K]^T (bf16 in, fp32 acc), BM=BN=128, BK=64, 256 thr.
// 16x16x32 MFMA, 4x4 acc/wave (R9-verified best).
// __launch_bounds__(256,3): force allocator <=170 regs/wave (true demand
// ~156 = 92 VGPR + 64 AGPR) -> 3 blocks/CU instead of 2 (R11 showed 18%
// occupancy = allocator rounded past 170; both pipes idle, latency-bound).
// LDS A/B each stored as TWO stacked 32-K panels of 64-B rows.
// Natural block mapping (R8's XCD strip-swizzle destroyed A-panel L2 reuse).
// SK: split-K factor (blockIdx.z = slice; slice 0 -> C0, slice 1 -> C1).
// EPI: 2 = bias + fast GELU -> bf16
//      4 = bf16 partial store (split-K; bias added downstream in LN)
//      5 = fused QKV epilogue: region 0 -> Q*QSCALE2 (C0); 1 -> K (C1);
//          2 -> V * mask, per-head-transposed [bh][64][2048] with keys
//          permuted within 32-groups (flash phi order) (C2)
template <int EPI, int SK>
__global__ __launch_bounds__(256, 3) void gemm_bt_kernel(
    const unsigned short* __restrict__ A, const unsigned short* __restrict__ BT,
    const float* __restrict__ bias, void* __restrict__ C0, void* __restrict__ C1,
    void* __restrict__ C2, int M, int N, int K, const int* __restrict__ msk) {
  __shared__ __align__(16) unsigned short As[128 * 64];   // 2 panels x 8KB
  __shared__ __align__(16) unsigned short Bs[128 * 64];
  const int tid = threadIdx.x;
  const int w = tid >> 6, l = tid & 63;
  const int lq = l >> 4, lr = l & 15;
  const int m0 = blockIdx.y * 128, n0 = blockIdx.x * 128;
  const int wm = (w >> 1) * 64, wn = (w & 1) * 64;
  const int r_a = l >> 2;            // row within 16-row chunk
  const int colb = (l & 3) * 8;      // col (8 bf16 = 16B)
  const int kslice = K / SK;
  const int kbeg = kslice * blockIdx.z;
  const int region = (EPI == 5) ? (n0 >> 10) : 0;  // block-uniform

  // V-row mask, 16 packed bits (loads overlap the K-loop staging)
  uint32_t mbits = 0xFFFFu;
  if (EPI == 5 && region == 2) {
    mbits = 0;
#pragma unroll
    for (int mt = 0; mt < 4; ++mt) {
      const int4 m4 = *(const int4*)(msk + m0 + wm + mt * 16 + lq * 4);
      mbits |= (m4.x ? 1u : 0u) << (mt * 4);
      mbits |= (m4.y ? 1u : 0u) << (mt * 4 + 1);
      mbits |= (m4.z ? 1u : 0u) << (mt * 4 + 2);
      mbits |= (m4.w ? 1u : 0u) << (mt * 4 + 3);
    }
  }

  floatx4 acc[4][4];
  const floatx4 fz = {0.f, 0.f, 0.f, 0.f};
#pragma unroll
  for (int mt = 0; mt < 4; ++mt)
#pragma unroll
    for (int nt = 0; nt < 4; ++nt) acc[mt][nt] = fz;

  for (int k0 = kbeg; k0 < kbeg + kslice; k0 += 64) {
    __syncthreads();
#pragma unroll
    for (int p = 0; p < 2; ++p) {
#pragma unroll
      for (int i = 0; i < 2; ++i) {
        const int c = w * 2 + i;
        load_lds_128(A + (size_t)(m0 + c * 16 + r_a) * K + k0 + p * 32 + colb,
                     (char*)As + p * 8192 + c * 1024);
        load_lds_128(BT + (size_t)(n0 + c * 16 + r_a) * K + k0 + p * 32 + colb,
                     (char*)Bs + p * 8192 + c * 1024);
      }
    }
    __syncthreads();
#pragma unroll
    for (int p = 0; p < 2; ++p) {
      short8 af[4], bf[4];
#pragma unroll
      for (int mt = 0; mt < 4; ++mt)
        af[mt] = *(const short8*)((const char*)As + p * 8192 + (wm + mt * 16 + lr) * 64 + lq * 16);
#pragma unroll
      for (int nt = 0; nt < 4; ++nt)
        bf[nt] = *(const short8*)((const char*)Bs + p * 8192 + (wn + nt * 16 + lr) * 64 + lq * 16);
#pragma unroll
      for (int mt = 0; mt < 4; ++mt)
#pragma unroll
        for (int nt = 0; nt < 4; ++nt)
          acc[mt][nt] = MFMA16(af[mt], bf[nt], acc[mt][nt]);
    }
  }

  void* Cp = (SK > 1 && blockIdx.z) ? C1 : C0;
  // epilogue: C row = quad*4+reg, col = lane&15
#pragma unroll
  for (int mt = 0; mt < 4; ++mt) {
#pragma unroll
    for (int nt = 0; nt < 4; ++nt) {
      const int n = n0 + wn + nt * 16 + lr;
      float bval = 0.f;
      if (EPI == 2) bval = bias[n];
#pragma unroll
      for (int r = 0; r < 4; ++r) {
        const int m = m0 + wm + mt * 16 + lq * 4 + r;
        float v = acc[mt][nt][r];
        if (EPI == 4) {
          ((unsigned short*)Cp)[(size_t)m * N + n] = f2bf(v);
        } else if (EPI == 2) {
          ((unsigned short*)C0)[(size_t)m * N + n] = f2bf(fast_gelu(v + bval));
        } else {  // EPI == 5
          if (region == 0) {
            ((unsigned short*)C0)[(size_t)m * 1024 + n] = f2bf(v * QSCALE2);
          } else if (region == 1) {
            ((unsigned short*)C1)[(size_t)m * 1024 + (n - 1024)] = f2bf(v);
          } else {
            const int nn = n - 2048;
            const int bidx = m >> 11, s = m & 2047;
            // key permutation within 32-group: p = (u&3)|(bit4<<2)|((u>>2&3)<<3)
            const int u = s & 31;
            const int sp = (s & ~31) | (u & 3) | (((u >> 4) & 1) << 2) | (((u >> 2) & 3) << 3);
            const int hh = nn >> 6, d = nn & 63;
            const float vv = ((mbits >> (mt * 4 + r)) & 1u) ? v : 0.f;
            ((unsigned short*)C2)[((size_t)((bidx * 16 + hh) * 64 + d)) * 2048 + sp] = f2bf(vv);
          }
        }
      }
    }
  }
}

// ---------------------------------------------------------------------------
// Flash attention: S=2048, Dk=64. Q PRE-SCALED by 0.125*log2e (exp2 domain).
// FIXED-SHIFT softmax (p = exp2(score)) + TRANSPOSED-SCORE register pipeline
// (S^T = K·Q^T -> C/D fragment is directly a PV A-operand under phi; V
// stored pre-permuted so V B-fragment is one ds_read_b128).
// XCD HEAD-GROUPING (R10-verified): 1D grid, xcd = lin&7 owns 4 whole (b,h)
// heads -> per-XCD K/V footprint 2MB fits the 4MB L2. Perf-only heuristic.
// LDS 32 KB (Ks 16K + VTs 16K). 256 thr, wave w -> 16 q rows.
__global__ __launch_bounds__(256, 4) void flash_kernel(
    const unsigned short* __restrict__ Q, const unsigned short* __restrict__ Kg,
    const unsigned short* __restrict__ VT, const unsigned short* __restrict__ MB,
    unsigned short* __restrict__ ctx) {
  __shared__ __align__(16) unsigned short Ks[128 * 64];    // [key][d], swizzled
  __shared__ __align__(16) unsigned short VTs[64 * 128];   // [d][key'], swizzled

  const int tid = threadIdx.x, w = tid >> 6, l = tid & 63;
  const int lq = l >> 4, lr = l & 15;
  const int lin = blockIdx.x;
  const int xcd = lin & 7, slot = lin >> 3;
  const int bh = xcd * 4 + (slot >> 5);    // 4 heads per XCD
  const int b = bh >> 4, h = bh & 15;
  const int q0 = (slot & 31) * 64;

  const unsigned short* Qp = Q + (size_t)(b * 2048 + q0) * 1024 + h * 64;
  const unsigned short* Kp = Kg + (size_t)(b * 2048) * 1024 + h * 64;
  const unsigned short* VTp = VT + (size_t)bh * 64 * 2048;
  const unsigned short* mbp = MB + b * 2048;

  {  // stage Q [64][64] once through Ks head (plain layout, consumed to regs)
    const int rq = l >> 3, cs = l & 7;
#pragma unroll
    for (int i = 0; i < 2; ++i) {
      const int c = w * 2 + i;
      load_lds_128(Qp + (size_t)(c * 8 + rq) * 1024 + cs * 8, (char*)Ks + c * 1024);
    }
  }
  __syncthreads();
  short8 qf[2];  // B-operand: lane holds Q[q0+w*16+lr][d = lq*8 + 0..7 (+32)]
  qf[0] = *(const short8*)((const char*)Ks + (w * 16 + lr) * 128 + lq * 16);
  qf[1] = *(const short8*)((const char*)Ks + (w * 16 + lr) * 128 + 64 + lq * 16);

  const floatx4 fz = {0.f, 0.f, 0.f, 0.f};
  floatx4 o[4] = {fz, fz, fz, fz};
  floatx4 l_acc = fz;

  const int krow = l >> 3, kslot = l & 7;   // Ks staging: 8 rows / 1KB chunk
  const int vrow = l >> 4, vslot = l & 15;  // VTs staging: 4 rows / 1KB chunk

  for (int kb = 0; kb < 2048; kb += 128) {
    __syncthreads();
#pragma unroll
    for (int i = 0; i < 4; ++i) {
      const int c4 = w * 4 + i;
      {  // Ks rows c4*8..+7; slot kslot holds logical chunk kslot^(row&7)
        const int row = c4 * 8 + krow;
        const int cc = kslot ^ (row & 7);
        load_lds_128(Kp + (size_t)(kb + row) * 1024 + cc * 8, (char*)Ks + c4 * 1024);
      }
      {  // VTs rows c4*4..+3; slot vslot holds logical chunk vslot^(row&15)
        const int row = c4 * 4 + vrow;
        const int cc = vslot ^ (row & 15);
        load_lds_128(VTp + (size_t)row * 2048 + kb + cc * 8, (char*)VTs + c4 * 1024);
      }
    }
    // mask fragments for the 4 PV windows (already in phi key order)
    short8 mf[4];
#pragma unroll
    for (int t = 0; t < 4; ++t) {
      const short4v ma = *(const short4v*)(mbp + kb + t * 32 + lq * 4);
      const short4v mb2 = *(const short4v*)(mbp + kb + t * 32 + 16 + lq * 4);
      mf[t] = short8{ma[0], ma[1], ma[2], ma[3], mb2[0], mb2[1], mb2[2], mb2[3]};
    }
    __syncthreads();

    // two halves of 64 keys each: 4 score-groups -> 2 PV windows
#pragma unroll
    for (int h2 = 0; h2 < 2; ++h2) {
      // S^T: D[m=key][n=q]; lane gets q=lr(col), key=g*16+lq*4+r(row)
      floatx4 s[4];
#pragma unroll
      for (int gg = 0; gg < 4; ++gg) {
        const int g = h2 * 4 + gg;
        const char* rowp = (const char*)Ks + (g * 16 + lr) * 128;
        short8 k0 = *(const short8*)(rowp + ((lq) ^ (lr & 7)) * 16);
        short8 k1 = *(const short8*)(rowp + ((4 + lq) ^ (lr & 7)) * 16);
        floatx4 t = MFMA16(k0, qf[0], fz);
        s[gg] = MFMA16(k1, qf[1], t);
      }
      // p = exp2(score), hw-packed to bf16 A-fragments (phi key order)
      short8 pf[2];
#pragma unroll
      for (int tt = 0; tt < 2; ++tt) {
        const floatx4 sL = s[tt * 2], sH = s[tt * 2 + 1];
        union { uint32_t u[4]; short8 s8; } pk;
        pk.u[0] = pkbf(EXP2(sL[0]), EXP2(sL[1]));
        pk.u[1] = pkbf(EXP2(sL[2]), EXP2(sL[3]));
        pk.u[2] = pkbf(EXP2(sH[0]), EXP2(sH[1]));
        pk.u[3] = pkbf(EXP2(sH[2]), EXP2(sH[3]));
        pf[tt] = pk.s8;
      }
      // PV: windows t = h2*2 + tt over 32 keys each; V fragment = one b128
#pragma unroll
      for (int tt = 0; tt < 2; ++tt) {
        const int t = h2 * 2 + tt;
        l_acc = MFMA16(pf[tt], mf[t], l_acc);
#pragma unroll
        for (int nt = 0; nt < 4; ++nt) {
          const int d = nt * 16 + lr;
          short8 vf = *(const short8*)((const char*)VTs + d * 256 +
                                       (((t * 4 + lq) ^ (d & 15)) * 16));
          o[nt] = MFMA16(pf[tt], vf, o[nt]);
        }
      }
    }
  }

  // epilogue: o C-layout: q = q0 + w*16 + lq*4 + r, d = nt*16 + lr
#pragma unroll
  for (int r = 0; r < 4; ++r) {
    const float inv = 1.0f / l_acc[r];
    const int q = q0 + w * 16 + lq * 4 + r;
#pragma unroll
    for (int nt = 0; nt < 4; ++nt)
      ctx[(size_t)(b * 2048 + q) * 1024 + h * 64 + nt * 16 + lr] = f2bf(o[nt][r] * inv);
  }
}

// ---------------------------------------------------------------------------
// fused residual + dual bf16-partial sum + bias + LayerNorm over rows of 1024.
// v = res + y0 + y1 + bias; out = LN(v)*gamma + beta.
template <int RESBF, int OUTBF>
__global__ __launch_bounds__(256) void ln2_kernel(
    const void* __restrict__ res, const unsigned short* __restrict__ y0,
    const unsigned short* __restrict__ y1, const float* __restrict__ bias,
    const float* __restrict__ gamma, const float* __restrict__ beta,
    void* __restrict__ outp) {
  const int row = blockIdx.x, t = threadIdx.x;
  const size_t base = (size_t)row * 1024 + t * 4;
  float v[4];
  if (RESBF) {
    ushort4v r4 = *(const ushort4v*)((const unsigned short*)res + base);
#pragma unroll
    for (int j = 0; j < 4; ++j) v[j] = bf2f(r4[j]);
  } else {
    floatx4 r4 = *(const floatx4*)((const float*)res + base);
#pragma unroll
    for (int j = 0; j < 4; ++j) v[j] = r4[j];
  }
  const ushort4v a4 = *(const ushort4v*)(y0 + base);
  const ushort4v b4v = *(const ushort4v*)(y1 + base);
  const floatx4 bi4 = *(const floatx4*)(bias + t * 4);
  float s = 0.f, ss = 0.f;
#pragma unroll
  for (int j = 0; j < 4; ++j) {
    v[j] += bf2f(a4[j]) + bf2f(b4v[j]) + bi4[j];
    s += v[j];
    ss += v[j] * v[j];
  }
#pragma unroll
  for (int off = 1; off < 64; off <<= 1) {
    s += __shfl_xor(s, off);
    ss += __shfl_xor(ss, off);
  }
  __shared__ float red[8];
  const int w = t >> 6;
  if ((t & 63) == 0) { red[w] = s; red[4 + w] = ss; }
  __syncthreads();
  s = red[0] + red[1] + red[2] + red[3];
  ss = red[4] + red[5] + red[6] + red[7];
  const float mean = s * (1.0f / 1024.0f);
  const float var = ss * (1.0f / 1024.0f) - mean * mean;
  const float rstd = rsqrtf(var + 1e-6f);
  const floatx4 g4 = *(const floatx4*)(gamma + t * 4);
  const floatx4 be4 = *(const floatx4*)(beta + t * 4);
  if (OUTBF) {
    union { uint32_t u[2]; ushort4v v4; } o;
    o.u[0] = pkbf((v[0] - mean) * rstd * g4[0] + be4[0],
                  (v[1] - mean) * rstd * g4[1] + be4[1]);
    o.u[1] = pkbf((v[2] - mean) * rstd * g4[2] + be4[2],
                  (v[3] - mean) * rstd * g4[3] + be4[3]);
    *(ushort4v*)((unsigned short*)outp + base) = o.v4;
  } else {
    floatx4 o;
#pragma unroll
    for (int j = 0; j < 4; ++j) o[j] = (v[j] - mean) * rstd * g4[j] + be4[j];
    *(floatx4*)((float*)outp + base) = o;
  }
}

// ---------------------------------------------------------------------------
extern "C" void kernel_launch(void* const* d_in, const int* in_sizes, int n_in,
                              void* d_out, int out_size, void* d_ws, size_t ws_size,
                              hipStream_t stream) {
  (void)in_sizes; (void)n_in; (void)out_size; (void)ws_size;
  const float* x    = (const float*)d_in[0];
  const int*   mask = (const int*)d_in[1];
  const float* wq   = (const float*)d_in[2];
  const float* wk   = (const float*)d_in[3];
  const float* wv   = (const float*)d_in[4];
  const float* wo   = (const float*)d_in[5];
  const float* wo_b = (const float*)d_in[6];
  const float* w1   = (const float*)d_in[7];
  const float* b1   = (const float*)d_in[8];
  const float* w2   = (const float*)d_in[9];
  const float* b2   = (const float*)d_in[10];
  const float* g1   = (const float*)d_in[11];
  const float* be1  = (const float*)d_in[12];
  const float* g2   = (const float*)d_in[13];
  const float* be2  = (const float*)d_in[14];
  float* out = (float*)d_out;

  char* ws = (char*)d_ws;
  const size_t MBy = 1024ull * 1024ull;
  // phase-aliased workspace (80 MB):
  unsigned short* WQKV = (unsigned short*)(ws + 0 * MBy);   // 6MB  (dead after QKV gemm)
  unsigned short* WOT  = (unsigned short*)(ws + 6 * MBy);   // 2MB  (dead after WO gemm)
  unsigned short* W1T  = (unsigned short*)(ws + 8 * MBy);   // 8MB  (dead after FF1)
  unsigned short* W2T  = (unsigned short*)(ws + 16 * MBy);  // 8MB  (dead after FF2)
  unsigned short* XB   = (unsigned short*)(ws + 24 * MBy);  // 8MB  (dead after QKV)
  unsigned short* Qb   = (unsigned short*)(ws + 32 * MBy);  // 8MB  (dead after flash)
  unsigned short* Kb   = (unsigned short*)(ws + 40 * MBy);  // 8MB  (dead after flash)
  unsigned short* VTb  = (unsigned short*)(ws + 48 * MBy);  // 8MB  (dead after flash)
  unsigned short* CTX  = (unsigned short*)(ws + 56 * MBy);  // 8MB  (dead after WO gemm)
  unsigned short* ATT0 = (unsigned short*)(ws + 32 * MBy);  // 8MB bf16, over Qb
  unsigned short* ATT1 = (unsigned short*)(ws + 40 * MBy);  // 8MB bf16, over Kb
  unsigned short* Hb   = (unsigned short*)(ws + 24 * MBy);  // 8MB  over XB
  unsigned short* G1   = (unsigned short*)(ws + 32 * MBy);  // 32MB over ATT0/ATT1/VTb/CTX
  unsigned short* FF20 = (unsigned short*)(ws + 64 * MBy);  // 8MB bf16
  unsigned short* FF21 = (unsigned short*)(ws + 72 * MBy);  // 8MB bf16
  unsigned short* MB   = (unsigned short*)(ws + 78 * MBy);  // 8KB bf16 mask (inside FF21
                                                            // region; FF21 written after flash)

  // 1. prep: cast x + all 6 weight transposes + bf16 mask in one launch
  prep_kernel<<<16385, 256, 0, stream>>>(x, XB, wq, wk, wv, wo, WQKV, WOT,
                                         w1, W1T, w2, W2T, mask, MB);
  // 2. fused QKV projection: N=3072 -> 768 blocks; Q pre-scaled, V masked+permuted
  gemm_bt_kernel<5, 1><<<dim3(24, 32), 256, 0, stream>>>(
      XB, WQKV, nullptr, Qb, Kb, VTb, 4096, 3072, 1024, mask);
  // 3. attention (1D grid, XCD head-grouped)
  flash_kernel<<<1024, 256, 0, stream>>>(Qb, Kb, VTb, MB, CTX);
  // 4. output projection, split-K=2 bf16 partials (bias folded into LN1)
  gemm_bt_kernel<4, 2><<<dim3(8, 32, 2), 256, 0, stream>>>(
      CTX, WOT, nullptr, ATT0, ATT1, nullptr, 4096, 1024, 1024, nullptr);
  // 5. LN1: h = LN(x + att0 + att1 + wo_b) -> bf16
  ln2_kernel<0, 1><<<4096, 256, 0, stream>>>(x, ATT0, ATT1, wo_b, g1, be1, Hb);
  // 6. FF1 + bias + fast GELU -> bf16
  gemm_bt_kernel<2, 1><<<dim3(32, 32), 256, 0, stream>>>(
      Hb, W1T, b1, G1, nullptr, nullptr, 4096, 4096, 1024, nullptr);
  // 7. FF2, split-K=2 bf16 partials (bias folded into LN2)
  gemm_bt_kernel<4, 2><<<dim3(8, 32, 2), 256, 0, stream>>>(
      G1, W2T, nullptr, FF20, FF21, nullptr, 4096, 1024, 4096, nullptr);
  // 8. LN2: out = LN(h + ff0 + ff1 + b2) -> fp32
  ln2_kernel<1, 0><<<4096, 256, 0, stream>>>(Hb, FF20, FF21, b2, g2, be2, out);
}

// Round 13
// 329.211 us; speedup vs baseline: 1.1296x; 1.0005x over previous
//
#include <hip/hip_runtime.h>
#include <cstdint>

#define DEVINL __device__ __forceinline__

typedef __attribute__((ext_vector_type(8))) short short8;       // 8 x bf16 (4 VGPRs)
typedef __attribute__((ext_vector_type(4))) short short4v;      // 4 x bf16 (2 VGPRs)
typedef __attribute__((ext_vector_type(4))) float floatx4;
typedef __attribute__((ext_vector_type(4))) unsigned short ushort4v;

// hardware packed cvt: D = {bf16(a), bf16(b)} (RNE) — use ONLY for true pair
// packs (scalar use regressed R7: asm blocks CSE, +20 VGPR in GEMM epilogue).
DEVINL uint32_t pkbf(float a, float b) {
  uint32_t d;
  asm("v_cvt_pk_bf16_f32 %0, %1, %2" : "=v"(d) : "v"(a), "v"(b));
  return d;
}
// software RNE fp32->bf16 for scalar stores (compiler-schedulable)
DEVINL unsigned short f2bf(float f) {
  union { float f; uint32_t u; } v; v.f = f;
  return (unsigned short)((v.u + 0x7fffu + ((v.u >> 16) & 1u)) >> 16);
}
DEVINL float bf2f(unsigned short h) {
  union { uint32_t u; float f; } v; v.u = ((uint32_t)h) << 16;
  return v.f;
}

#if defined(__has_builtin) && __has_builtin(__builtin_amdgcn_exp2f)
#define EXP2(x) __builtin_amdgcn_exp2f(x)
#else
#define EXP2(x) exp2f(x)
#endif

// fast GELU (tanh form, exp2-based): max |err| ~3e-4 vs exact erf GELU.
DEVINL float fast_gelu(float v) {
  const float z = -2.30220795f * v * (1.0f + 0.044715f * v * v);
  return v * __builtin_amdgcn_rcpf(1.0f + EXP2(z));
}

typedef __attribute__((address_space(3))) unsigned char* lds_ptr_t;
typedef const __attribute__((address_space(1))) unsigned char* gbl_ptr_t;
// async global->LDS, 16B per lane; LDS dest = wave-uniform base + lane*16
DEVINL void load_lds_128(const void* g, void* l) {
  __builtin_amdgcn_global_load_lds((gbl_ptr_t)g, (lds_ptr_t)l, 16, 0, 0);
}

#define MFMA16(a, b, c) __builtin_amdgcn_mfma_f32_16x16x32_bf16((a), (b), (c), 0, 0, 0)

// 0.125 (1/sqrt(Dk)) * log2(e): folds attention scale AND base-2 softmax into Q
#define QSCALE2 0.18033688011112042f

// ---------------------------------------------------------------------------
// prep: blocks 0..4095 cast x->bf16; 4096..8191 four 1024^2 transposes;
// 8192..12287 w1; 12288..16383 w2; 16384 converts mask(int)->bf16 0/1.
__global__ __launch_bounds__(256) void prep_kernel(
    const float* __restrict__ x, unsigned short* __restrict__ XB,
    const float* __restrict__ wq, const float* __restrict__ wk,
    const float* __restrict__ wv, const float* __restrict__ wo,
    unsigned short* __restrict__ WQKV, unsigned short* __restrict__ WOT,
    const float* __restrict__ w1, unsigned short* __restrict__ W1T,
    const float* __restrict__ w2, unsigned short* __restrict__ W2T,
    const int* __restrict__ mask, unsigned short* __restrict__ MB) {
  const int bid = blockIdx.x;
  if (bid >= 16384) {  // mask -> bf16 0/1
    const int i0 = threadIdx.x * 16;
#pragma unroll
    for (int j = 0; j < 16; ++j) MB[i0 + j] = mask[i0 + j] ? 0x3F80 : 0;
    return;
  }
  if (bid < 4096) {  // cast x (pair-packed hw cvt)
    const int i = (bid * 256 + threadIdx.x) * 4;
    floatx4 v = *(const floatx4*)(x + i);
    union { uint32_t u[2]; ushort4v v4; } o;
    o.u[0] = pkbf(v[0], v[1]);
    o.u[1] = pkbf(v[2], v[3]);
    *(ushort4v*)(XB + i) = o.v4;
    return;
  }
  const float* in;
  unsigned short* out;
  int K, N, bx, by;
  if (bid < 8192) {
    const int b2 = bid - 4096, z = b2 >> 10;
    in = (z == 0) ? wq : (z == 1) ? wk : (z == 2) ? wv : wo;
    out = (z == 3) ? WOT : WQKV + (size_t)z * 1024 * 1024;
    K = 1024; N = 1024; bx = b2 & 31; by = (b2 >> 5) & 31;
  } else if (bid < 12288) {
    const int b3 = bid - 8192;
    in = w1; out = W1T; K = 1024; N = 4096; bx = b3 & 127; by = b3 >> 7;
  } else {
    const int b4 = bid - 12288;
    in = w2; out = W2T; K = 4096; N = 1024; bx = b4 & 31; by = b4 >> 5;
  }
  __shared__ float tile[32][33];
  const int n0 = bx * 32, k0 = by * 32;
  const int tx = threadIdx.x & 31, ty = threadIdx.x >> 5;  // 32 x 8
#pragma unroll
  for (int i = 0; i < 4; ++i)
    tile[ty + 8 * i][tx] = in[(size_t)(k0 + ty + 8 * i) * N + n0 + tx];
  __syncthreads();
#pragma unroll
  for (int i = 0; i < 4; ++i)
    out[(size_t)(n0 + ty + 8 * i) * K + k0 + tx] = f2bf(tile[tx][ty + 8 * i]);
}

// ---------------------------------------------------------------------------
// GEMM: C = A[M,K] @ BT[N,K]^T (bf16 in, fp32 acc), BM=BN=128, BK=64, 256 thr.
// 16x16x32 MFMA, 4x4 acc/wave; __launch_bounds__(256,3) caps regs at 170
// (true demand ~156) -> 3 blocks/CU (R12-verified: 341->329us).
// LDS A/B each stored as TWO stacked 32-K panels of 64-B rows.
// Natural block mapping. SK: split-K (blockIdx.z; slice0->C0, slice1->C1).
// EPI: 2 = bias + fast GELU -> bf16
//      4 = bf16 partial store (split-K; bias added downstream in LN)
//      5 = fused QKV epilogue: region 0 -> Q*QSCALE2 (C0); 1 -> K (C1);
//          2 -> V * mask, per-head-transposed [bh][64][2048] with keys
//          permuted within 32-groups (flash phi order) (C2)
template <int EPI, int SK>
__global__ __launch_bounds__(256, 3) void gemm_bt_kernel(
    const unsigned short* __restrict__ A, const unsigned short* __restrict__ BT,
    const float* __restrict__ bias, void* __restrict__ C0, void* __restrict__ C1,
    void* __restrict__ C2, int M, int N, int K, const int* __restrict__ msk) {
  __shared__ __align__(16) unsigned short As[128 * 64];   // 2 panels x 8KB
  __shared__ __align__(16) unsigned short Bs[128 * 64];
  const int tid = threadIdx.x;
  const int w = tid >> 6, l = tid & 63;
  const int lq = l >> 4, lr = l & 15;
  const int m0 = blockIdx.y * 128, n0 = blockIdx.x * 128;
  const int wm = (w >> 1) * 64, wn = (w & 1) * 64;
  const int r_a = l >> 2;            // row within 16-row chunk
  const int colb = (l & 3) * 8;      // col (8 bf16 = 16B)
  const int kslice = K / SK;
  const int kbeg = kslice * blockIdx.z;
  const int region = (EPI == 5) ? (n0 >> 10) : 0;  // block-uniform

  // V-row mask, 16 packed bits (loads overlap the K-loop staging)
  uint32_t mbits = 0xFFFFu;
  if (EPI == 5 && region == 2) {
    mbits = 0;
#pragma unroll
    for (int mt = 0; mt < 4; ++mt) {
      const int4 m4 = *(const int4*)(msk + m0 + wm + mt * 16 + lq * 4);
      mbits |= (m4.x ? 1u : 0u) << (mt * 4);
      mbits |= (m4.y ? 1u : 0u) << (mt * 4 + 1);
      mbits |= (m4.z ? 1u : 0u) << (mt * 4 + 2);
      mbits |= (m4.w ? 1u : 0u) << (mt * 4 + 3);
    }
  }

  floatx4 acc[4][4];
  const floatx4 fz = {0.f, 0.f, 0.f, 0.f};
#pragma unroll
  for (int mt = 0; mt < 4; ++mt)
#pragma unroll
    for (int nt = 0; nt < 4; ++nt) acc[mt][nt] = fz;

  for (int k0 = kbeg; k0 < kbeg + kslice; k0 += 64) {
    __syncthreads();
#pragma unroll
    for (int p = 0; p < 2; ++p) {
#pragma unroll
      for (int i = 0; i < 2; ++i) {
        const int c = w * 2 + i;
        load_lds_128(A + (size_t)(m0 + c * 16 + r_a) * K + k0 + p * 32 + colb,
                     (char*)As + p * 8192 + c * 1024);
        load_lds_128(BT + (size_t)(n0 + c * 16 + r_a) * K + k0 + p * 32 + colb,
                     (char*)Bs + p * 8192 + c * 1024);
      }
    }
    __syncthreads();
#pragma unroll
    for (int p = 0; p < 2; ++p) {
      short8 af[4], bf[4];
#pragma unroll
      for (int mt = 0; mt < 4; ++mt)
        af[mt] = *(const short8*)((const char*)As + p * 8192 + (wm + mt * 16 + lr) * 64 + lq * 16);
#pragma unroll
      for (int nt = 0; nt < 4; ++nt)
        bf[nt] = *(const short8*)((const char*)Bs + p * 8192 + (wn + nt * 16 + lr) * 64 + lq * 16);
#pragma unroll
      for (int mt = 0; mt < 4; ++mt)
#pragma unroll
        for (int nt = 0; nt < 4; ++nt)
          acc[mt][nt] = MFMA16(af[mt], bf[nt], acc[mt][nt]);
    }
  }

  void* Cp = (SK > 1 && blockIdx.z) ? C1 : C0;
  // epilogue: C row = quad*4+reg, col = lane&15
#pragma unroll
  for (int mt = 0; mt < 4; ++mt) {
#pragma unroll
    for (int nt = 0; nt < 4; ++nt) {
      const int n = n0 + wn + nt * 16 + lr;
      float bval = 0.f;
      if (EPI == 2) bval = bias[n];
#pragma unroll
      for (int r = 0; r < 4; ++r) {
        const int m = m0 + wm + mt * 16 + lq * 4 + r;
        float v = acc[mt][nt][r];
        if (EPI == 4) {
          ((unsigned short*)Cp)[(size_t)m * N + n] = f2bf(v);
        } else if (EPI == 2) {
          ((unsigned short*)C0)[(size_t)m * N + n] = f2bf(fast_gelu(v + bval));
        } else {  // EPI == 5
          if (region == 0) {
            ((unsigned short*)C0)[(size_t)m * 1024 + n] = f2bf(v * QSCALE2);
          } else if (region == 1) {
            ((unsigned short*)C1)[(size_t)m * 1024 + (n - 1024)] = f2bf(v);
          } else {
            const int nn = n - 2048;
            const int bidx = m >> 11, s = m & 2047;
            // key permutation within 32-group: p = (u&3)|(bit4<<2)|((u>>2&3)<<3)
            const int u = s & 31;
            const int sp = (s & ~31) | (u & 3) | (((u >> 4) & 1) << 2) | (((u >> 2) & 3) << 3);
            const int hh = nn >> 6, d = nn & 63;
            const float vv = ((mbits >> (mt * 4 + r)) & 1u) ? v : 0.f;
            ((unsigned short*)C2)[((size_t)((bidx * 16 + hh) * 64 + d)) * 2048 + sp] = f2bf(vv);
          }
        }
      }
    }
  }
}

// ---------------------------------------------------------------------------
// Flash attention: S=2048, Dk=64. Q PRE-SCALED by 0.125*log2e (exp2 domain).
// FIXED-SHIFT softmax + TRANSPOSED-SCORE register pipeline (S^T = K·Q^T;
// C/D fragment is directly the PV A-operand under phi; V pre-permuted so the
// V B-fragment is one ds_read_b128).
// Q-TILE = 128 rows/block (R13): R12 counters showed flash is LDS-read-BW
// bound (each wave re-reads the whole 16KB K-tile + 16KB V-tile per iter;
// 128KB/block/iter ≈ 1540cyc vs 175cyc MFMA). Each wave now serves TWO
// 16-row q-groups, hoisting K/V fragment reads across them -> LDS traffic
// per q-row halves. 512 blocks; XCD head-grouping: xcd owns 4 heads.
// LDS 32 KB (Ks 16K + VTs 16K). 256 thr, wave w -> q rows w*32..w*32+31.
__global__ __launch_bounds__(256, 2) void flash_kernel(
    const unsigned short* __restrict__ Q, const unsigned short* __restrict__ Kg,
    const unsigned short* __restrict__ VT, const unsigned short* __restrict__ MB,
    unsigned short* __restrict__ ctx) {
  __shared__ __align__(16) unsigned short Ks[128 * 64];    // [key][d] / Q stage, swizzled
  __shared__ __align__(16) unsigned short VTs[64 * 128];   // [d][key'], swizzled

  const int tid = threadIdx.x, w = tid >> 6, l = tid & 63;
  const int lq = l >> 4, lr = l & 15;
  const int lin = blockIdx.x;
  const int xcd = lin & 7, slot = lin >> 3;     // 64 slots per XCD
  const int bh = xcd * 4 + (slot >> 4);         // 4 heads per XCD
  const int b = bh >> 4, h = bh & 15;
  const int q0 = (slot & 15) * 128;

  const unsigned short* Qp = Q + (size_t)(b * 2048 + q0) * 1024 + h * 64;
  const unsigned short* Kp = Kg + (size_t)(b * 2048) * 1024 + h * 64;
  const unsigned short* VTp = VT + (size_t)bh * 64 * 2048;
  const unsigned short* mbp = MB + b * 2048;

  {  // stage Q [128][64] once through Ks (16KB: 16 chunks, 4 per wave)
    const int rq = l >> 3, cs = l & 7;
#pragma unroll
    for (int i = 0; i < 4; ++i) {
      const int c = w * 4 + i;
      load_lds_128(Qp + (size_t)(c * 8 + rq) * 1024 + cs * 8, (char*)Ks + c * 1024);
    }
  }
  __syncthreads();
  short8 qf[2][2];  // [qg][kstep]; lane holds Q[q0+w*32+qg*16+lr][d=lq*8+..]
#pragma unroll
  for (int qg = 0; qg < 2; ++qg) {
    qf[qg][0] = *(const short8*)((const char*)Ks + (w * 32 + qg * 16 + lr) * 128 + lq * 16);
    qf[qg][1] = *(const short8*)((const char*)Ks + (w * 32 + qg * 16 + lr) * 128 + 64 + lq * 16);
  }
  __syncthreads();  // Q consumed; Ks reused for K tiles

  const floatx4 fz = {0.f, 0.f, 0.f, 0.f};
  floatx4 o[2][4];
#pragma unroll
  for (int qg = 0; qg < 2; ++qg)
#pragma unroll
    for (int nt = 0; nt < 4; ++nt) o[qg][nt] = fz;
  floatx4 l_acc[2] = {fz, fz};

  const int krow = l >> 3, kslot = l & 7;   // Ks staging: 8 rows / 1KB chunk
  const int vrow = l >> 4, vslot = l & 15;  // VTs staging: 4 rows / 1KB chunk

  for (int kb = 0; kb < 2048; kb += 128) {
    if (kb) __syncthreads();
#pragma unroll
    for (int i = 0; i < 4; ++i) {
      const int c4 = w * 4 + i;
      {  // Ks rows c4*8..+7; slot kslot holds logical chunk kslot^(row&7)
        const int row = c4 * 8 + krow;
        const int cc = kslot ^ (row & 7);
        load_lds_128(Kp + (size_t)(kb + row) * 1024 + cc * 8, (char*)Ks + c4 * 1024);
      }
      {  // VTs rows c4*4..+3; slot vslot holds logical chunk vslot^(row&15)
        const int row = c4 * 4 + vrow;
        const int cc = vslot ^ (row & 15);
        load_lds_128(VTp + (size_t)row * 2048 + kb + cc * 8, (char*)VTs + c4 * 1024);
      }
    }
    // mask fragments for the 4 PV windows (already in phi key order)
    short8 mf[4];
#pragma unroll
    for (int t = 0; t < 4; ++t) {
      const short4v ma = *(const short4v*)(mbp + kb + t * 32 + lq * 4);
      const short4v mb2 = *(const short4v*)(mbp + kb + t * 32 + 16 + lq * 4);
      mf[t] = short8{ma[0], ma[1], ma[2], ma[3], mb2[0], mb2[1], mb2[2], mb2[3]};
    }
    __syncthreads();

    // two halves of 64 keys each: 4 score-groups -> 2 PV windows
#pragma unroll
    for (int h2 = 0; h2 < 2; ++h2) {
      // S^T for both q-groups; K fragment reads SHARED across qg
      floatx4 s[2][4];
#pragma unroll
      for (int gg = 0; gg < 4; ++gg) {
        const int g = h2 * 4 + gg;
        const char* rowp = (const char*)Ks + (g * 16 + lr) * 128;
        short8 k0 = *(const short8*)(rowp + ((lq) ^ (lr & 7)) * 16);
        short8 k1 = *(const short8*)(rowp + ((4 + lq) ^ (lr & 7)) * 16);
#pragma unroll
        for (int qg = 0; qg < 2; ++qg) {
          floatx4 t = MFMA16(k0, qf[qg][0], fz);
          s[qg][gg] = MFMA16(k1, qf[qg][1], t);
        }
      }
      // p = exp2(score), hw-packed to bf16 A-fragments (phi key order)
      short8 pf[2][2];  // [qg][tt]
#pragma unroll
      for (int qg = 0; qg < 2; ++qg)
#pragma unroll
        for (int tt = 0; tt < 2; ++tt) {
          const floatx4 sL = s[qg][tt * 2], sH = s[qg][tt * 2 + 1];
          union { uint32_t u[4]; short8 s8; } pk;
          pk.u[0] = pkbf(EXP2(sL[0]), EXP2(sL[1]));
          pk.u[1] = pkbf(EXP2(sL[2]), EXP2(sL[3]));
          pk.u[2] = pkbf(EXP2(sH[0]), EXP2(sH[1]));
          pk.u[3] = pkbf(EXP2(sH[2]), EXP2(sH[3]));
          pf[qg][tt] = pk.s8;
        }
      // PV: windows t = h2*2 + tt; V fragment reads SHARED across qg
#pragma unroll
      for (int tt = 0; tt < 2; ++tt) {
        const int t = h2 * 2 + tt;
        l_acc[0] = MFMA16(pf[0][tt], mf[t], l_acc[0]);
        l_acc[1] = MFMA16(pf[1][tt], mf[t], l_acc[1]);
#pragma unroll
        for (int nt = 0; nt < 4; ++nt) {
          const int d = nt * 16 + lr;
          short8 vf = *(const short8*)((const char*)VTs + d * 256 +
                                       (((t * 4 + lq) ^ (d & 15)) * 16));
          o[0][nt] = MFMA16(pf[0][tt], vf, o[0][nt]);
          o[1][nt] = MFMA16(pf[1][tt], vf, o[1][nt]);
        }
      }
    }
  }

  // epilogue: q = q0 + w*32 + qg*16 + lq*4 + r, d = nt*16 + lr
#pragma unroll
  for (int qg = 0; qg < 2; ++qg)
#pragma unroll
    for (int r = 0; r < 4; ++r) {
      const float inv = 1.0f / l_acc[qg][r];
      const int q = q0 + w * 32 + qg * 16 + lq * 4 + r;
#pragma unroll
      for (int nt = 0; nt < 4; ++nt)
        ctx[(size_t)(b * 2048 + q) * 1024 + h * 64 + nt * 16 + lr] = f2bf(o[qg][nt][r] * inv);
    }
}

// ---------------------------------------------------------------------------
// fused residual + dual bf16-partial sum + bias + LayerNorm over rows of 1024.
// v = res + y0 + y1 + bias; out = LN(v)*gamma + beta.
template <int RESBF, int OUTBF>
__global__ __launch_bounds__(256) void ln2_kernel(
    const void* __restrict__ res, const unsigned short* __restrict__ y0,
    const unsigned short* __restrict__ y1, const float* __restrict__ bias,
    const float* __restrict__ gamma, const float* __restrict__ beta,
    void* __restrict__ outp) {
  const int row = blockIdx.x, t = threadIdx.x;
  const size_t base = (size_t)row * 1024 + t * 4;
  float v[4];
  if (RESBF) {
    ushort4v r4 = *(const ushort4v*)((const unsigned short*)res + base);
#pragma unroll
    for (int j = 0; j < 4; ++j) v[j] = bf2f(r4[j]);
  } else {
    floatx4 r4 = *(const floatx4*)((const float*)res + base);
#pragma unroll
    for (int j = 0; j < 4; ++j) v[j] = r4[j];
  }
  const ushort4v a4 = *(const ushort4v*)(y0 + base);
  const ushort4v b4v = *(const ushort4v*)(y1 + base);
  const floatx4 bi4 = *(const floatx4*)(bias + t * 4);
  float s = 0.f, ss = 0.f;
#pragma unroll
  for (int j = 0; j < 4; ++j) {
    v[j] += bf2f(a4[j]) + bf2f(b4v[j]) + bi4[j];
    s += v[j];
    ss += v[j] * v[j];
  }
#pragma unroll
  for (int off = 1; off < 64; off <<= 1) {
    s += __shfl_xor(s, off);
    ss += __shfl_xor(ss, off);
  }
  __shared__ float red[8];
  const int w = t >> 6;
  if ((t & 63) == 0) { red[w] = s; red[4 + w] = ss; }
  __syncthreads();
  s = red[0] + red[1] + red[2] + red[3];
  ss = red[4] + red[5] + red[6] + red[7];
  const float mean = s * (1.0f / 1024.0f);
  const float var = ss * (1.0f / 1024.0f) - mean * mean;
  const float rstd = rsqrtf(var + 1e-6f);
  const floatx4 g4 = *(const floatx4*)(gamma + t * 4);
  const floatx4 be4 = *(const floatx4*)(beta + t * 4);
  if (OUTBF) {
    union { uint32_t u[2]; ushort4v v4; } o;
    o.u[0] = pkbf((v[0] - mean) * rstd * g4[0] + be4[0],
                  (v[1] - mean) * rstd * g4[1] + be4[1]);
    o.u[1] = pkbf((v[2] - mean) * rstd * g4[2] + be4[2],
                  (v[3] - mean) * rstd * g4[3] + be4[3]);
    *(ushort4v*)((unsigned short*)outp + base) = o.v4;
  } else {
    floatx4 o;
#pragma unroll
    for (int j = 0; j < 4; ++j) o[j] = (v[j] - mean) * rstd * g4[j] + be4[j];
    *(floatx4*)((float*)outp + base) = o;
  }
}

// ---------------------------------------------------------------------------
extern "C" void kernel_launch(void* const* d_in, const int* in_sizes, int n_in,
                              void* d_out, int out_size, void* d_ws, size_t ws_size,
                              hipStream_t stream) {
  (void)in_sizes; (void)n_in; (void)out_size; (void)ws_size;
  const float* x    = (const float*)d_in[0];
  const int*   mask = (const int*)d_in[1];
  const float* wq   = (const float*)d_in[2];
  const float* wk   = (const float*)d_in[3];
  const float* wv   = (const float*)d_in[4];
  const float* wo   = (const float*)d_in[5];
  const float* wo_b = (const float*)d_in[6];
  const float* w1   = (const float*)d_in[7];
  const float* b1   = (const float*)d_in[8];
  const float* w2   = (const float*)d_in[9];
  const float* b2   = (const float*)d_in[10];
  const float* g1   = (const float*)d_in[11];
  const float* be1  = (const float*)d_in[12];
  const float* g2   = (const float*)d_in[13];
  const float* be2  = (const float*)d_in[14];
  float* out = (float*)d_out;

  char* ws = (char*)d_ws;
  const size_t MBy = 1024ull * 1024ull;
  // phase-aliased workspace (80 MB):
  unsigned short* WQKV = (unsigned short*)(ws + 0 * MBy);   // 6MB  (dead after QKV gemm)
  unsigned short* WOT  = (unsigned short*)(ws + 6 * MBy);   // 2MB  (dead after WO gemm)
  unsigned short* W1T  = (unsigned short*)(ws + 8 * MBy);   // 8MB  (dead after FF1)
  unsigned short* W2T  = (unsigned short*)(ws + 16 * MBy);  // 8MB  (dead after FF2)
  unsigned short* XB   = (unsigned short*)(ws + 24 * MBy);  // 8MB  (dead after QKV)
  unsigned short* Qb   = (unsigned short*)(ws + 32 * MBy);  // 8MB  (dead after flash)
  unsigned short* Kb   = (unsigned short*)(ws + 40 * MBy);  // 8MB  (dead after flash)
  unsigned short* VTb  = (unsigned short*)(ws + 48 * MBy);  // 8MB  (dead after flash)
  unsigned short* CTX  = (unsigned short*)(ws + 56 * MBy);  // 8MB  (dead after WO gemm)
  unsigned short* ATT0 = (unsigned short*)(ws + 32 * MBy);  // 8MB bf16, over Qb
  unsigned short* ATT1 = (unsigned short*)(ws + 40 * MBy);  // 8MB bf16, over Kb
  unsigned short* Hb   = (unsigned short*)(ws + 24 * MBy);  // 8MB  over XB
  unsigned short* G1   = (unsigned short*)(ws + 32 * MBy);  // 32MB over ATT0/ATT1/VTb/CTX
  unsigned short* FF20 = (unsigned short*)(ws + 64 * MBy);  // 8MB bf16
  unsigned short* FF21 = (unsigned short*)(ws + 72 * MBy);  // 8MB bf16
  unsigned short* MB   = (unsigned short*)(ws + 78 * MBy);  // 8KB bf16 mask (inside FF21
                                                            // region; FF21 written after flash)

  // 1. prep: cast x + all 6 weight transposes + bf16 mask in one launch
  prep_kernel<<<16385, 256, 0, stream>>>(x, XB, wq, wk, wv, wo, WQKV, WOT,
                                         w1, W1T, w2, W2T, mask, MB);
  // 2. fused QKV projection: N=3072 -> 768 blocks; Q pre-scaled, V masked+permuted
  gemm_bt_kernel<5, 1><<<dim3(24, 32), 256, 0, stream>>>(
      XB, WQKV, nullptr, Qb, Kb, VTb, 4096, 3072, 1024, mask);
  // 3. attention (512 blocks, q-tile 128, XCD head-grouped)
  flash_kernel<<<512, 256, 0, stream>>>(Qb, Kb, VTb, MB, CTX);
  // 4. output projection, split-K=2 bf16 partials (bias folded into LN1)
  gemm_bt_kernel<4, 2><<<dim3(8, 32, 2), 256, 0, stream>>>(
      CTX, WOT, nullptr, ATT0, ATT1, nullptr, 4096, 1024, 1024, nullptr);
  // 5. LN1: h = LN(x + att0 + att1 + wo_b) -> bf16
  ln2_kernel<0, 1><<<4096, 256, 0, stream>>>(x, ATT0, ATT1, wo_b, g1, be1, Hb);
  // 6. FF1 + bias + fast GELU -> bf16
  gemm_bt_kernel<2, 1><<<dim3(32, 32), 256, 0, stream>>>(
      Hb, W1T, b1, G1, nullptr, nullptr, 4096, 4096, 1024, nullptr);
  // 7. FF2, split-K=2 bf16 partials (bias folded into LN2)
  gemm_bt_kernel<4, 2><<<dim3(8, 32, 2), 256, 0, stream>>>(
      G1, W2T, nullptr, FF20, FF21, nullptr, 4096, 1024, 4096, nullptr);
  // 8. LN2: out = LN(h + ff0 + ff1 + b2) -> fp32
  ln2_kernel<1, 0><<<4096, 256, 0, stream>>>(Hb, FF20, FF21, b2, g2, be2, out);
}

// Round 14
// 324.733 us; speedup vs baseline: 1.1451x; 1.0138x over previous
//
#include <hip/hip_runtime.h>
#include <cstdint>

#define DEVINL __device__ __forceinline__

typedef __attribute__((ext_vector_type(8))) short short8;       // 8 x bf16 (4 VGPRs)
typedef __attribute__((ext_vector_type(4))) short short4v;      // 4 x bf16 (2 VGPRs)
typedef __attribute__((ext_vector_type(4))) float floatx4;
typedef __attribute__((ext_vector_type(4))) unsigned short ushort4v;

// hardware packed cvt: D = {bf16(a), bf16(b)} (RNE) — use ONLY for true pair
// packs (scalar use regressed R7: asm blocks CSE, +20 VGPR in GEMM epilogue).
DEVINL uint32_t pkbf(float a, float b) {
  uint32_t d;
  asm("v_cvt_pk_bf16_f32 %0, %1, %2" : "=v"(d) : "v"(a), "v"(b));
  return d;
}
// software RNE fp32->bf16 for scalar stores (compiler-schedulable)
DEVINL unsigned short f2bf(float f) {
  union { float f; uint32_t u; } v; v.f = f;
  return (unsigned short)((v.u + 0x7fffu + ((v.u >> 16) & 1u)) >> 16);
}
DEVINL float bf2f(unsigned short h) {
  union { uint32_t u; float f; } v; v.u = ((uint32_t)h) << 16;
  return v.f;
}

#if defined(__has_builtin) && __has_builtin(__builtin_amdgcn_exp2f)
#define EXP2(x) __builtin_amdgcn_exp2f(x)
#else
#define EXP2(x) exp2f(x)
#endif

// fast GELU (tanh form, exp2-based): max |err| ~3e-4 vs exact erf GELU.
DEVINL float fast_gelu(float v) {
  const float z = -2.30220795f * v * (1.0f + 0.044715f * v * v);
  return v * __builtin_amdgcn_rcpf(1.0f + EXP2(z));
}

typedef __attribute__((address_space(3))) unsigned char* lds_ptr_t;
typedef const __attribute__((address_space(1))) unsigned char* gbl_ptr_t;
// async global->LDS, 16B per lane; LDS dest = wave-uniform base + lane*16
DEVINL void load_lds_128(const void* g, void* l) {
  __builtin_amdgcn_global_load_lds((gbl_ptr_t)g, (lds_ptr_t)l, 16, 0, 0);
}

#define MFMA16(a, b, c) __builtin_amdgcn_mfma_f32_16x16x32_bf16((a), (b), (c), 0, 0, 0)

// 0.125 (1/sqrt(Dk)) * log2(e): folds attention scale AND base-2 softmax into Q
#define QSCALE2 0.18033688011112042f

// ---------------------------------------------------------------------------
// prep: blocks 0..4095 cast x->bf16; 4096..8191 four 1024^2 transposes;
// 8192..12287 w1; 12288..16383 w2; 16384 converts mask(int)->bf16 0/1.
__global__ __launch_bounds__(256) void prep_kernel(
    const float* __restrict__ x, unsigned short* __restrict__ XB,
    const float* __restrict__ wq, const float* __restrict__ wk,
    const float* __restrict__ wv, const float* __restrict__ wo,
    unsigned short* __restrict__ WQKV, unsigned short* __restrict__ WOT,
    const float* __restrict__ w1, unsigned short* __restrict__ W1T,
    const float* __restrict__ w2, unsigned short* __restrict__ W2T,
    const int* __restrict__ mask, unsigned short* __restrict__ MB) {
  const int bid = blockIdx.x;
  if (bid >= 16384) {  // mask -> bf16 0/1
    const int i0 = threadIdx.x * 16;
#pragma unroll
    for (int j = 0; j < 16; ++j) MB[i0 + j] = mask[i0 + j] ? 0x3F80 : 0;
    return;
  }
  if (bid < 4096) {  // cast x (pair-packed hw cvt)
    const int i = (bid * 256 + threadIdx.x) * 4;
    floatx4 v = *(const floatx4*)(x + i);
    union { uint32_t u[2]; ushort4v v4; } o;
    o.u[0] = pkbf(v[0], v[1]);
    o.u[1] = pkbf(v[2], v[3]);
    *(ushort4v*)(XB + i) = o.v4;
    return;
  }
  const float* in;
  unsigned short* out;
  int K, N, bx, by;
  if (bid < 8192) {
    const int b2 = bid - 4096, z = b2 >> 10;
    in = (z == 0) ? wq : (z == 1) ? wk : (z == 2) ? wv : wo;
    out = (z == 3) ? WOT : WQKV + (size_t)z * 1024 * 1024;
    K = 1024; N = 1024; bx = b2 & 31; by = (b2 >> 5) & 31;
  } else if (bid < 12288) {
    const int b3 = bid - 8192;
    in = w1; out = W1T; K = 1024; N = 4096; bx = b3 & 127; by = b3 >> 7;
  } else {
    const int b4 = bid - 12288;
    in = w2; out = W2T; K = 4096; N = 1024; bx = b4 & 31; by = b4 >> 5;
  }
  __shared__ float tile[32][33];
  const int n0 = bx * 32, k0 = by * 32;
  const int tx = threadIdx.x & 31, ty = threadIdx.x >> 5;  // 32 x 8
#pragma unroll
  for (int i = 0; i < 4; ++i)
    tile[ty + 8 * i][tx] = in[(size_t)(k0 + ty + 8 * i) * N + n0 + tx];
  __syncthreads();
#pragma unroll
  for (int i = 0; i < 4; ++i)
    out[(size_t)(n0 + ty + 8 * i) * K + k0 + tx] = f2bf(tile[tx][ty + 8 * i]);
}

// ---------------------------------------------------------------------------
// GEMM: C = A[M,K] @ BT[N,K]^T (bf16 in, fp32 acc), BM=BN=128, BK=64, 256 thr.
// 16x16x32 MFMA, 4x4 acc/wave; __launch_bounds__(256,3) -> 3 blocks/CU.
// XCD RECTANGLE SWIZZLE (R14): hardware assigns xcd = dispatch_id & 7; with
// nx % 8 == 0 the natural mapping gives each XCD one COLUMN STRIP (all of A
// streamed through its 4MB L2 — R13 showed FF2 FETCH 135MB vs 40MB
// footprint). Remap so the 8 XCDs tile the grid 2x4: each owns nx/2 cols x
// ny/4 rows -> per-XCD footprint ~5-6MB instead of 16+MB. (R8's failed
// swizzle was strips, which REPRODUCE the disease; rectangles minimize it.)
// LDS A/B each stored as TWO stacked 32-K panels of 64-B rows.
// SK: split-K (blockIdx.z; slice0->C0, slice1->C1).
// EPI: 2 = bias + fast GELU -> bf16
//      4 = bf16 partial store (split-K; bias added downstream in LN)
//      5 = fused QKV epilogue: region 0 -> Q*QSCALE2 (C0); 1 -> K (C1);
//          2 -> V * mask, per-head-transposed [bh][64][2048] with keys
//          permuted within 32-groups (flash phi order) (C2)
template <int EPI, int SK>
__global__ __launch_bounds__(256, 3) void gemm_bt_kernel(
    const unsigned short* __restrict__ A, const unsigned short* __restrict__ BT,
    const float* __restrict__ bias, void* __restrict__ C0, void* __restrict__ C1,
    void* __restrict__ C2, int M, int N, int K, const int* __restrict__ msk) {
  __shared__ __align__(16) unsigned short As[128 * 64];   // 2 panels x 8KB
  __shared__ __align__(16) unsigned short Bs[128 * 64];
  const int tid = threadIdx.x;
  const int w = tid >> 6, l = tid & 63;
  const int lq = l >> 4, lr = l & 15;

  int bxs, bys;
  {  // 2x4 XCD rectangle swizzle (perf-only; any mapping is correct)
    const int nx = gridDim.x, ny = gridDim.y;
    const int f = blockIdx.y * nx + blockIdx.x;
    const int xcd = f & 7, s = f >> 3;
    const int q = nx >> 1, p = ny >> 2;     // rect = q cols x p rows
    bxs = (xcd & 1) * q + (s % q);
    bys = (xcd >> 1) * p + (s / q);
  }
  const int m0 = bys * 128, n0 = bxs * 128;
  const int wm = (w >> 1) * 64, wn = (w & 1) * 64;
  const int r_a = l >> 2;            // row within 16-row chunk
  const int colb = (l & 3) * 8;      // col (8 bf16 = 16B)
  const int kslice = K / SK;
  const int kbeg = kslice * blockIdx.z;
  const int region = (EPI == 5) ? (n0 >> 10) : 0;  // block-uniform

  // V-row mask, 16 packed bits (loads overlap the K-loop staging)
  uint32_t mbits = 0xFFFFu;
  if (EPI == 5 && region == 2) {
    mbits = 0;
#pragma unroll
    for (int mt = 0; mt < 4; ++mt) {
      const int4 m4 = *(const int4*)(msk + m0 + wm + mt * 16 + lq * 4);
      mbits |= (m4.x ? 1u : 0u) << (mt * 4);
      mbits |= (m4.y ? 1u : 0u) << (mt * 4 + 1);
      mbits |= (m4.z ? 1u : 0u) << (mt * 4 + 2);
      mbits |= (m4.w ? 1u : 0u) << (mt * 4 + 3);
    }
  }

  floatx4 acc[4][4];
  const floatx4 fz = {0.f, 0.f, 0.f, 0.f};
#pragma unroll
  for (int mt = 0; mt < 4; ++mt)
#pragma unroll
    for (int nt = 0; nt < 4; ++nt) acc[mt][nt] = fz;

  for (int k0 = kbeg; k0 < kbeg + kslice; k0 += 64) {
    __syncthreads();
#pragma unroll
    for (int p = 0; p < 2; ++p) {
#pragma unroll
      for (int i = 0; i < 2; ++i) {
        const int c = w * 2 + i;
        load_lds_128(A + (size_t)(m0 + c * 16 + r_a) * K + k0 + p * 32 + colb,
                     (char*)As + p * 8192 + c * 1024);
        load_lds_128(BT + (size_t)(n0 + c * 16 + r_a) * K + k0 + p * 32 + colb,
                     (char*)Bs + p * 8192 + c * 1024);
      }
    }
    __syncthreads();
#pragma unroll
    for (int p = 0; p < 2; ++p) {
      short8 af[4], bf[4];
#pragma unroll
      for (int mt = 0; mt < 4; ++mt)
        af[mt] = *(const short8*)((const char*)As + p * 8192 + (wm + mt * 16 + lr) * 64 + lq * 16);
#pragma unroll
      for (int nt = 0; nt < 4; ++nt)
        bf[nt] = *(const short8*)((const char*)Bs + p * 8192 + (wn + nt * 16 + lr) * 64 + lq * 16);
#pragma unroll
      for (int mt = 0; mt < 4; ++mt)
#pragma unroll
        for (int nt = 0; nt < 4; ++nt)
          acc[mt][nt] = MFMA16(af[mt], bf[nt], acc[mt][nt]);
    }
  }

  void* Cp = (SK > 1 && blockIdx.z) ? C1 : C0;
  // epilogue: C row = quad*4+reg, col = lane&15
#pragma unroll
  for (int mt = 0; mt < 4; ++mt) {
#pragma unroll
    for (int nt = 0; nt < 4; ++nt) {
      const int n = n0 + wn + nt * 16 + lr;
      float bval = 0.f;
      if (EPI == 2) bval = bias[n];
#pragma unroll
      for (int r = 0; r < 4; ++r) {
        const int m = m0 + wm + mt * 16 + lq * 4 + r;
        float v = acc[mt][nt][r];
        if (EPI == 4) {
          ((unsigned short*)Cp)[(size_t)m * N + n] = f2bf(v);
        } else if (EPI == 2) {
          ((unsigned short*)C0)[(size_t)m * N + n] = f2bf(fast_gelu(v + bval));
        } else {  // EPI == 5
          if (region == 0) {
            ((unsigned short*)C0)[(size_t)m * 1024 + n] = f2bf(v * QSCALE2);
          } else if (region == 1) {
            ((unsigned short*)C1)[(size_t)m * 1024 + (n - 1024)] = f2bf(v);
          } else {
            const int nn = n - 2048;
            const int bidx = m >> 11, s = m & 2047;
            // key permutation within 32-group: p = (u&3)|(bit4<<2)|((u>>2&3)<<3)
            const int u = s & 31;
            const int sp = (s & ~31) | (u & 3) | (((u >> 4) & 1) << 2) | (((u >> 2) & 3) << 3);
            const int hh = nn >> 6, d = nn & 63;
            const float vv = ((mbits >> (mt * 4 + r)) & 1u) ? v : 0.f;
            ((unsigned short*)C2)[((size_t)((bidx * 16 + hh) * 64 + d)) * 2048 + sp] = f2bf(vv);
          }
        }
      }
    }
  }
}

// ---------------------------------------------------------------------------
// Flash attention: S=2048, Dk=64. Q PRE-SCALED by 0.125*log2e (exp2 domain).
// FIXED-SHIFT softmax + TRANSPOSED-SCORE register pipeline (S^T = K·Q^T;
// C/D fragment is directly the PV A-operand under phi; V pre-permuted so the
// V B-fragment is one ds_read_b128). Q-tile 128 rows/block: K/V fragment
// reads shared across two q-groups per wave (halves LDS read traffic).
// XCD head-grouping: xcd owns 4 heads. LDS 32 KB. 512 blocks.
__global__ __launch_bounds__(256, 2) void flash_kernel(
    const unsigned short* __restrict__ Q, const unsigned short* __restrict__ Kg,
    const unsigned short* __restrict__ VT, const unsigned short* __restrict__ MB,
    unsigned short* __restrict__ ctx) {
  __shared__ __align__(16) unsigned short Ks[128 * 64];    // [key][d] / Q stage, swizzled
  __shared__ __align__(16) unsigned short VTs[64 * 128];   // [d][key'], swizzled

  const int tid = threadIdx.x, w = tid >> 6, l = tid & 63;
  const int lq = l >> 4, lr = l & 15;
  const int lin = blockIdx.x;
  const int xcd = lin & 7, slot = lin >> 3;     // 64 slots per XCD
  const int bh = xcd * 4 + (slot >> 4);         // 4 heads per XCD
  const int b = bh >> 4, h = bh & 15;
  const int q0 = (slot & 15) * 128;

  const unsigned short* Qp = Q + (size_t)(b * 2048 + q0) * 1024 + h * 64;
  const unsigned short* Kp = Kg + (size_t)(b * 2048) * 1024 + h * 64;
  const unsigned short* VTp = VT + (size_t)bh * 64 * 2048;
  const unsigned short* mbp = MB + b * 2048;

  {  // stage Q [128][64] once through Ks (16KB: 16 chunks, 4 per wave)
    const int rq = l >> 3, cs = l & 7;
#pragma unroll
    for (int i = 0; i < 4; ++i) {
      const int c = w * 4 + i;
      load_lds_128(Qp + (size_t)(c * 8 + rq) * 1024 + cs * 8, (char*)Ks + c * 1024);
    }
  }
  __syncthreads();
  short8 qf[2][2];  // [qg][kstep]; lane holds Q[q0+w*32+qg*16+lr][d=lq*8+..]
#pragma unroll
  for (int qg = 0; qg < 2; ++qg) {
    qf[qg][0] = *(const short8*)((const char*)Ks + (w * 32 + qg * 16 + lr) * 128 + lq * 16);
    qf[qg][1] = *(const short8*)((const char*)Ks + (w * 32 + qg * 16 + lr) * 128 + 64 + lq * 16);
  }
  __syncthreads();  // Q consumed; Ks reused for K tiles

  const floatx4 fz = {0.f, 0.f, 0.f, 0.f};
  floatx4 o[2][4];
#pragma unroll
  for (int qg = 0; qg < 2; ++qg)
#pragma unroll
    for (int nt = 0; nt < 4; ++nt) o[qg][nt] = fz;
  floatx4 l_acc[2] = {fz, fz};

  const int krow = l >> 3, kslot = l & 7;   // Ks staging: 8 rows / 1KB chunk
  const int vrow = l >> 4, vslot = l & 15;  // VTs staging: 4 rows / 1KB chunk

  for (int kb = 0; kb < 2048; kb += 128) {
    if (kb) __syncthreads();
#pragma unroll
    for (int i = 0; i < 4; ++i) {
      const int c4 = w * 4 + i;
      {  // Ks rows c4*8..+7; slot kslot holds logical chunk kslot^(row&7)
        const int row = c4 * 8 + krow;
        const int cc = kslot ^ (row & 7);
        load_lds_128(Kp + (size_t)(kb + row) * 1024 + cc * 8, (char*)Ks + c4 * 1024);
      }
      {  // VTs rows c4*4..+3; slot vslot holds logical chunk vslot^(row&15)
        const int row = c4 * 4 + vrow;
        const int cc = vslot ^ (row & 15);
        load_lds_128(VTp + (size_t)row * 2048 + kb + cc * 8, (char*)VTs + c4 * 1024);
      }
    }
    // mask fragments for the 4 PV windows (already in phi key order)
    short8 mf[4];
#pragma unroll
    for (int t = 0; t < 4; ++t) {
      const short4v ma = *(const short4v*)(mbp + kb + t * 32 + lq * 4);
      const short4v mb2 = *(const short4v*)(mbp + kb + t * 32 + 16 + lq * 4);
      mf[t] = short8{ma[0], ma[1], ma[2], ma[3], mb2[0], mb2[1], mb2[2], mb2[3]};
    }
    __syncthreads();

    // two halves of 64 keys each: 4 score-groups -> 2 PV windows
#pragma unroll
    for (int h2 = 0; h2 < 2; ++h2) {
      // S^T for both q-groups; K fragment reads SHARED across qg
      floatx4 s[2][4];
#pragma unroll
      for (int gg = 0; gg < 4; ++gg) {
        const int g = h2 * 4 + gg;
        const char* rowp = (const char*)Ks + (g * 16 + lr) * 128;
        short8 k0 = *(const short8*)(rowp + ((lq) ^ (lr & 7)) * 16);
        short8 k1 = *(const short8*)(rowp + ((4 + lq) ^ (lr & 7)) * 16);
#pragma unroll
        for (int qg = 0; qg < 2; ++qg) {
          floatx4 t = MFMA16(k0, qf[qg][0], fz);
          s[qg][gg] = MFMA16(k1, qf[qg][1], t);
        }
      }
      // p = exp2(score), hw-packed to bf16 A-fragments (phi key order)
      short8 pf[2][2];  // [qg][tt]
#pragma unroll
      for (int qg = 0; qg < 2; ++qg)
#pragma unroll
        for (int tt = 0; tt < 2; ++tt) {
          const floatx4 sL = s[qg][tt * 2], sH = s[qg][tt * 2 + 1];
          union { uint32_t u[4]; short8 s8; } pk;
          pk.u[0] = pkbf(EXP2(sL[0]), EXP2(sL[1]));
          pk.u[1] = pkbf(EXP2(sL[2]), EXP2(sL[3]));
          pk.u[2] = pkbf(EXP2(sH[0]), EXP2(sH[1]));
          pk.u[3] = pkbf(EXP2(sH[2]), EXP2(sH[3]));
          pf[qg][tt] = pk.s8;
        }
      // PV: windows t = h2*2 + tt; V fragment reads SHARED across qg
#pragma unroll
      for (int tt = 0; tt < 2; ++tt) {
        const int t = h2 * 2 + tt;
        l_acc[0] = MFMA16(pf[0][tt], mf[t], l_acc[0]);
        l_acc[1] = MFMA16(pf[1][tt], mf[t], l_acc[1]);
#pragma unroll
        for (int nt = 0; nt < 4; ++nt) {
          const int d = nt * 16 + lr;
          short8 vf = *(const short8*)((const char*)VTs + d * 256 +
                                       (((t * 4 + lq) ^ (d & 15)) * 16));
          o[0][nt] = MFMA16(pf[0][tt], vf, o[0][nt]);
          o[1][nt] = MFMA16(pf[1][tt], vf, o[1][nt]);
        }
      }
    }
  }

  // epilogue: q = q0 + w*32 + qg*16 + lq*4 + r, d = nt*16 + lr
#pragma unroll
  for (int qg = 0; qg < 2; ++qg)
#pragma unroll
    for (int r = 0; r < 4; ++r) {
      const float inv = 1.0f / l_acc[qg][r];
      const int q = q0 + w * 32 + qg * 16 + lq * 4 + r;
#pragma unroll
      for (int nt = 0; nt < 4; ++nt)
        ctx[(size_t)(b * 2048 + q) * 1024 + h * 64 + nt * 16 + lr] = f2bf(o[qg][nt][r] * inv);
    }
}

// ---------------------------------------------------------------------------
// fused residual + dual bf16-partial sum + bias + LayerNorm over rows of 1024.
// v = res + y0 + y1 + bias; out = LN(v)*gamma + beta.
template <int RESBF, int OUTBF>
__global__ __launch_bounds__(256) void ln2_kernel(
    const void* __restrict__ res, const unsigned short* __restrict__ y0,
    const unsigned short* __restrict__ y1, const float* __restrict__ bias,
    const float* __restrict__ gamma, const float* __restrict__ beta,
    void* __restrict__ outp) {
  const int row = blockIdx.x, t = threadIdx.x;
  const size_t base = (size_t)row * 1024 + t * 4;
  float v[4];
  if (RESBF) {
    ushort4v r4 = *(const ushort4v*)((const unsigned short*)res + base);
#pragma unroll
    for (int j = 0; j < 4; ++j) v[j] = bf2f(r4[j]);
  } else {
    floatx4 r4 = *(const floatx4*)((const float*)res + base);
#pragma unroll
    for (int j = 0; j < 4; ++j) v[j] = r4[j];
  }
  const ushort4v a4 = *(const ushort4v*)(y0 + base);
  const ushort4v b4v = *(const ushort4v*)(y1 + base);
  const floatx4 bi4 = *(const floatx4*)(bias + t * 4);
  float s = 0.f, ss = 0.f;
#pragma unroll
  for (int j = 0; j < 4; ++j) {
    v[j] += bf2f(a4[j]) + bf2f(b4v[j]) + bi4[j];
    s += v[j];
    ss += v[j] * v[j];
  }
#pragma unroll
  for (int off = 1; off < 64; off <<= 1) {
    s += __shfl_xor(s, off);
    ss += __shfl_xor(ss, off);
  }
  __shared__ float red[8];
  const int w = t >> 6;
  if ((t & 63) == 0) { red[w] = s; red[4 + w] = ss; }
  __syncthreads();
  s = red[0] + red[1] + red[2] + red[3];
  ss = red[4] + red[5] + red[6] + red[7];
  const float mean = s * (1.0f / 1024.0f);
  const float var = ss * (1.0f / 1024.0f) - mean * mean;
  const float rstd = rsqrtf(var + 1e-6f);
  const floatx4 g4 = *(const floatx4*)(gamma + t * 4);
  const floatx4 be4 = *(const floatx4*)(beta + t * 4);
  if (OUTBF) {
    union { uint32_t u[2]; ushort4v v4; } o;
    o.u[0] = pkbf((v[0] - mean) * rstd * g4[0] + be4[0],
                  (v[1] - mean) * rstd * g4[1] + be4[1]);
    o.u[1] = pkbf((v[2] - mean) * rstd * g4[2] + be4[2],
                  (v[3] - mean) * rstd * g4[3] + be4[3]);
    *(ushort4v*)((unsigned short*)outp + base) = o.v4;
  } else {
    floatx4 o;
#pragma unroll
    for (int j = 0; j < 4; ++j) o[j] = (v[j] - mean) * rstd * g4[j] + be4[j];
    *(floatx4*)((float*)outp + base) = o;
  }
}

// ---------------------------------------------------------------------------
extern "C" void kernel_launch(void* const* d_in, const int* in_sizes, int n_in,
                              void* d_out, int out_size, void* d_ws, size_t ws_size,
                              hipStream_t stream) {
  (void)in_sizes; (void)n_in; (void)out_size; (void)ws_size;
  const float* x    = (const float*)d_in[0];
  const int*   mask = (const int*)d_in[1];
  const float* wq   = (const float*)d_in[2];
  const float* wk   = (const float*)d_in[3];
  const float* wv   = (const float*)d_in[4];
  const float* wo   = (const float*)d_in[5];
  const float* wo_b = (const float*)d_in[6];
  const float* w1   = (const float*)d_in[7];
  const float* b1   = (const float*)d_in[8];
  const float* w2   = (const float*)d_in[9];
  const float* b2   = (const float*)d_in[10];
  const float* g1   = (const float*)d_in[11];
  const float* be1  = (const float*)d_in[12];
  const float* g2   = (const float*)d_in[13];
  const float* be2  = (const float*)d_in[14];
  float* out = (float*)d_out;

  char* ws = (char*)d_ws;
  const size_t MBy = 1024ull * 1024ull;
  // phase-aliased workspace (80 MB):
  unsigned short* WQKV = (unsigned short*)(ws + 0 * MBy);   // 6MB  (dead after QKV gemm)
  unsigned short* WOT  = (unsigned short*)(ws + 6 * MBy);   // 2MB  (dead after WO gemm)
  unsigned short* W1T  = (unsigned short*)(ws + 8 * MBy);   // 8MB  (dead after FF1)
  unsigned short* W2T  = (unsigned short*)(ws + 16 * MBy);  // 8MB  (dead after FF2)
  unsigned short* XB   = (unsigned short*)(ws + 24 * MBy);  // 8MB  (dead after QKV)
  unsigned short* Qb   = (unsigned short*)(ws + 32 * MBy);  // 8MB  (dead after flash)
  unsigned short* Kb   = (unsigned short*)(ws + 40 * MBy);  // 8MB  (dead after flash)
  unsigned short* VTb  = (unsigned short*)(ws + 48 * MBy);  // 8MB  (dead after flash)
  unsigned short* CTX  = (unsigned short*)(ws + 56 * MBy);  // 8MB  (dead after WO gemm)
  unsigned short* ATT0 = (unsigned short*)(ws + 32 * MBy);  // 8MB bf16, over Qb
  unsigned short* ATT1 = (unsigned short*)(ws + 40 * MBy);  // 8MB bf16, over Kb
  unsigned short* Hb   = (unsigned short*)(ws + 24 * MBy);  // 8MB  over XB
  unsigned short* G1   = (unsigned short*)(ws + 32 * MBy);  // 32MB over ATT0/ATT1/VTb/CTX
  unsigned short* FF20 = (unsigned short*)(ws + 64 * MBy);  // 8MB bf16
  unsigned short* FF21 = (unsigned short*)(ws + 72 * MBy);  // 8MB bf16
  unsigned short* MB   = (unsigned short*)(ws + 78 * MBy);  // 8KB bf16 mask (inside FF21
                                                            // region; FF21 written after flash)

  // 1. prep: cast x + all 6 weight transposes + bf16 mask in one launch
  prep_kernel<<<16385, 256, 0, stream>>>(x, XB, wq, wk, wv, wo, WQKV, WOT,
                                         w1, W1T, w2, W2T, mask, MB);
  // 2. fused QKV projection: N=3072 -> 768 blocks; Q pre-scaled, V masked+permuted
  gemm_bt_kernel<5, 1><<<dim3(24, 32), 256, 0, stream>>>(
      XB, WQKV, nullptr, Qb, Kb, VTb, 4096, 3072, 1024, mask);
  // 3. attention (512 blocks, q-tile 128, XCD head-grouped)
  flash_kernel<<<512, 256, 0, stream>>>(Qb, Kb, VTb, MB, CTX);
  // 4. output projection, split-K=2 bf16 partials (bias folded into LN1)
  gemm_bt_kernel<4, 2><<<dim3(8, 32, 2), 256, 0, stream>>>(
      CTX, WOT, nullptr, ATT0, ATT1, nullptr, 4096, 1024, 1024, nullptr);
  // 5. LN1: h = LN(x + att0 + att1 + wo_b) -> bf16
  ln2_kernel<0, 1><<<4096, 256, 0, stream>>>(x, ATT0, ATT1, wo_b, g1, be1, Hb);
  // 6. FF1 + bias + fast GELU -> bf16
  gemm_bt_kernel<2, 1><<<dim3(32, 32), 256, 0, stream>>>(
      Hb, W1T, b1, G1, nullptr, nullptr, 4096, 4096, 1024, nullptr);
  // 7. FF2, split-K=2 bf16 partials (bias folded into LN2)
  gemm_bt_kernel<4, 2><<<dim3(8, 32, 2), 256, 0, stream>>>(
      G1, W2T, nullptr, FF20, FF21, nullptr, 4096, 1024, 4096, nullptr);
  // 8. LN2: out = LN(h + ff0 + ff1 + b2) -> fp32
  ln2_kernel<1, 0><<<4096, 256, 0, stream>>>(Hb, FF20, FF21, b2, g2, be2, out);
}